// Round 3
// baseline (1043.954 us; speedup 1.0000x reference)
//
#include <hip/hip_runtime.h>
#include <stdint.h>

#define N_NODES 50000
#define N_EDGES 800000

// flag indices: 0:x 1:ea 2:Wl1 3:bl1 4:Wr1 5:br1 6:We1 7:att1 8:bias1
//               9:Wl2 10:bl2 11:Wr2 12:br2 13:We2 14:att2 15:bias2
struct Ptrs { const void* p[16]; int n[16]; };

typedef __attribute__((ext_vector_type(8))) short bf16x8;
typedef __attribute__((ext_vector_type(4))) float f32x4;

__device__ __forceinline__ float bf2f(unsigned short u){
  union { unsigned int i; float f; } v; v.i = ((unsigned int)u) << 16; return v.f;
}
__device__ __forceinline__ float lo16(unsigned int u){ union { unsigned int i; float f; } v; v.i = u << 16; return v.f; }
__device__ __forceinline__ float hi16(unsigned int u){ union { unsigned int i; float f; } v; v.i = u & 0xffff0000u; return v.f; }
__device__ __forceinline__ unsigned short f2bf(float f){
  if (!(f == f)) return 0;
  unsigned int x = __float_as_uint(f);
  unsigned int r = (x + 0x7fffu + ((x >> 16) & 1u)) >> 16;
  return (unsigned short)r;
}
__device__ __forceinline__ float fin(float v){
  if (!(v == v)) return 0.f;
  return fminf(fmaxf(v, -1e30f), 1e30f);
}
__device__ __forceinline__ float loadF(const void* p, int f32, size_t idx){
  return f32 ? ((const float*)p)[idx] : bf2f(((const unsigned short*)p)[idx]);
}

// stage n bf16 elems of W (bf16 or f32 source) into LDS; n multiple of 2048
__device__ __forceinline__ void stageW(unsigned short* dst, const void* src, int n, int f32, int tid){
  if (f32) {
    for (int i = tid * 8; i < n; i += 2048) {
      float4 a = *(const float4*)((const float*)src + i);
      float4 b = *(const float4*)((const float*)src + i + 4);
      uint4 u;
      u.x = (unsigned)f2bf(a.x) | ((unsigned)f2bf(a.y) << 16);
      u.y = (unsigned)f2bf(a.z) | ((unsigned)f2bf(a.w) << 16);
      u.z = (unsigned)f2bf(b.x) | ((unsigned)f2bf(b.y) << 16);
      u.w = (unsigned)f2bf(b.z) | ((unsigned)f2bf(b.w) << 16);
      *(uint4*)(dst + i) = u;
    }
  } else {
    for (int i = tid * 8; i < n; i += 2048)
      *(uint4*)(dst + i) = *(const uint4*)((const unsigned short*)src + i);
  }
}

// ---------- dtype detect ----------
__global__ __launch_bounds__(256) void k_detect(Ptrs tl, int* __restrict__ flags)
{
  __shared__ int red[256];
  int b = blockIdx.x, t = threadIdx.x;
  const unsigned short* p = (const unsigned short*)tl.p[b];
  int n = tl.n[b]; if (n > 16384) n = 16384;
  int crazy = 0;
  for (int i = t; i < n; i += 256) {
    unsigned short u = p[i];
    if (u) {
      int ex = (u >> 7) & 0xFF;
      if (ex == 0xFF || ex < 0x60) crazy++;
    }
  }
  red[t] = crazy; __syncthreads();
  for (int off = 128; off; off >>= 1) { if (t < off) red[t] += red[t + off]; __syncthreads(); }
  if (t == 0) flags[b] = (red[0] * 10 > n) ? 1 : 0;
}

__global__ __launch_bounds__(256) void k_zero(int* __restrict__ p, int n)
{
  int i = blockIdx.x * 256 + threadIdx.x;
  if (i < n) p[i] = 0;
}

// ---------- layer-1 GEMM: xl1p / xr1p, packed bf16 [N,64] uints in FRAGMENT order ----------
// fragment order: natural uint u = t*8 + quad*2 + b  ->  u' = quad*16 + t*2 + b
// so lane 'quad' of the fuse kernels reads its 32 channels as 64 contiguous bytes.
__global__ __launch_bounds__(256) void k_gemm1(
    const void* __restrict__ x,
    const void* __restrict__ Wl, const void* __restrict__ bl,
    const void* __restrict__ Wr, const void* __restrict__ br,
    const int* __restrict__ flags,
    unsigned int* __restrict__ xlp, unsigned int* __restrict__ xrp)
{
  __shared__ float xs[32 * 132];
  __shared__ unsigned short ws[128 * 128];
  const void* W  = blockIdx.y ? Wr : Wl;
  const void* bb = blockIdx.y ? br : bl;
  int fW = blockIdx.y ? flags[4] : flags[2];
  int fB = blockIdx.y ? flags[5] : flags[3];
  int fX = flags[0];
  unsigned int* outp = blockIdx.y ? xrp : xlp;
  int tid = threadIdx.x;
  int row0 = blockIdx.x * 32;
  stageW(ws, W, 128 * 128, fW, tid);
  for (int i = tid * 4; i < 32 * 128; i += 1024) {
    int r = i >> 7, k = i & 127;
    int row = row0 + r;
    float4 v = make_float4(0.f, 0.f, 0.f, 0.f);
    if (row < N_NODES) {
      if (fX) v = *(const float4*)((const float*)x + (size_t)row * 128 + k);
      else {
        uint2 u = *(const uint2*)((const unsigned short*)x + (size_t)row * 128 + k);
        v.x = lo16(u.x); v.y = hi16(u.x); v.z = lo16(u.y); v.w = hi16(u.y);
      }
    }
    *(float4*)(xs + r * 132 + k) = v;
  }
  __syncthreads();
  int r = tid >> 3, cg = tid & 7;
  float acc[16];
#pragma unroll
  for (int j = 0; j < 16; j++) acc[j] = 0.f;
#pragma unroll 4
  for (int k = 0; k < 128; k++) {
    float xv = xs[r * 132 + k];
    uint4 p0 = *(const uint4*)(ws + k * 128 + cg * 8);
    uint4 p1 = *(const uint4*)(ws + k * 128 + 64 + cg * 8);
    acc[0]  = fmaf(xv, lo16(p0.x), acc[0]);  acc[1]  = fmaf(xv, hi16(p0.x), acc[1]);
    acc[2]  = fmaf(xv, lo16(p0.y), acc[2]);  acc[3]  = fmaf(xv, hi16(p0.y), acc[3]);
    acc[4]  = fmaf(xv, lo16(p0.z), acc[4]);  acc[5]  = fmaf(xv, hi16(p0.z), acc[5]);
    acc[6]  = fmaf(xv, lo16(p0.w), acc[6]);  acc[7]  = fmaf(xv, hi16(p0.w), acc[7]);
    acc[8]  = fmaf(xv, lo16(p1.x), acc[8]);  acc[9]  = fmaf(xv, hi16(p1.x), acc[9]);
    acc[10] = fmaf(xv, lo16(p1.y), acc[10]); acc[11] = fmaf(xv, hi16(p1.y), acc[11]);
    acc[12] = fmaf(xv, lo16(p1.z), acc[12]); acc[13] = fmaf(xv, hi16(p1.z), acc[13]);
    acc[14] = fmaf(xv, lo16(p1.w), acc[14]); acc[15] = fmaf(xv, hi16(p1.w), acc[15]);
  }
  int row = row0 + r;
  if (row < N_NODES) {
    unsigned int* op = outp + (size_t)row * 64;
    int tt = cg >> 1, qb = (cg & 1) * 2;
    unsigned int ou[4];
#pragma unroll
    for (int t = 0; t < 4; t++) {
      float f0 = fin(acc[2 * t]     + loadF(bb, fB, cg * 8 + 2 * t));
      float f1 = fin(acc[2 * t + 1] + loadF(bb, fB, cg * 8 + 2 * t + 1));
      ou[t] = (unsigned)f2bf(f0) | ((unsigned)f2bf(f1) << 16);
    }
    *(uint2*)(op + qb * 16 + tt * 2)       = make_uint2(ou[0], ou[1]);
    *(uint2*)(op + (qb + 1) * 16 + tt * 2) = make_uint2(ou[2], ou[3]);
#pragma unroll
    for (int t = 0; t < 4; t++) {
      float f0 = fin(acc[8 + 2 * t]     + loadF(bb, fB, 64 + cg * 8 + 2 * t));
      float f1 = fin(acc[8 + 2 * t + 1] + loadF(bb, fB, 64 + cg * 8 + 2 * t + 1));
      ou[t] = (unsigned)f2bf(f0) | ((unsigned)f2bf(f1) << 16);
    }
    *(uint2*)(op + qb * 16 + 8 + tt * 2)       = make_uint2(ou[0], ou[1]);
    *(uint2*)(op + (qb + 1) * 16 + 8 + tt * 2) = make_uint2(ou[2], ou[3]);
  }
}

// ---------- layer-2 GEMM: xl2p / xr2p, packed bf16 [N,32] uints in FRAGMENT order ----------
// natural uint u = t*8 + quad*2 + b (t=0..3) -> u' = quad*8 + t*2 + b
__global__ __launch_bounds__(256) void k_gemm2(
    const float* __restrict__ h,
    const void* __restrict__ Wl, const void* __restrict__ bl,
    const void* __restrict__ Wr, const void* __restrict__ br,
    const int* __restrict__ flags,
    unsigned int* __restrict__ xlp, unsigned int* __restrict__ xrp)
{
  __shared__ float hs[32 * 132];
  __shared__ unsigned short ws[128 * 64];
  const void* W  = blockIdx.y ? Wr : Wl;
  const void* bb = blockIdx.y ? br : bl;
  int fW = blockIdx.y ? flags[11] : flags[9];
  int fB = blockIdx.y ? flags[12] : flags[10];
  unsigned int* outp = blockIdx.y ? xrp : xlp;
  int tid = threadIdx.x;
  int row0 = blockIdx.x * 32;
  stageW(ws, W, 128 * 64, fW, tid);
  for (int i = tid * 4; i < 32 * 128; i += 1024) {
    int r = i >> 7, k = i & 127;
    int row = row0 + r;
    float4 v = make_float4(0.f, 0.f, 0.f, 0.f);
    if (row < N_NODES) v = *(const float4*)(h + (size_t)row * 128 + k);
    *(float4*)(hs + r * 132 + k) = v;
  }
  __syncthreads();
  int r = tid >> 3, cg = tid & 7;
  float acc[8];
#pragma unroll
  for (int j = 0; j < 8; j++) acc[j] = 0.f;
#pragma unroll 4
  for (int k = 0; k < 128; k++) {
    float hv = hs[r * 132 + k];
    uint4 p = *(const uint4*)(ws + k * 64 + cg * 8);
    acc[0] = fmaf(hv, lo16(p.x), acc[0]); acc[1] = fmaf(hv, hi16(p.x), acc[1]);
    acc[2] = fmaf(hv, lo16(p.y), acc[2]); acc[3] = fmaf(hv, hi16(p.y), acc[3]);
    acc[4] = fmaf(hv, lo16(p.z), acc[4]); acc[5] = fmaf(hv, hi16(p.z), acc[5]);
    acc[6] = fmaf(hv, lo16(p.w), acc[6]); acc[7] = fmaf(hv, hi16(p.w), acc[7]);
  }
  int row = row0 + r;
  if (row < N_NODES) {
    unsigned int* op = outp + (size_t)row * 32;
    int tt = cg >> 1, qb = (cg & 1) * 2;
    unsigned int ou[4];
#pragma unroll
    for (int t = 0; t < 4; t++) {
      float f0 = fin(acc[2 * t]     + loadF(bb, fB, cg * 8 + 2 * t));
      float f1 = fin(acc[2 * t + 1] + loadF(bb, fB, cg * 8 + 2 * t + 1));
      ou[t] = (unsigned)f2bf(f0) | ((unsigned)f2bf(f1) << 16);
    }
    *(uint2*)(op + qb * 8 + tt * 2)       = make_uint2(ou[0], ou[1]);
    *(uint2*)(op + (qb + 1) * 8 + tt * 2) = make_uint2(ou[2], ou[3]);
  }
}

// ---------- CSR build ----------
__global__ __launch_bounds__(256) void k_hist(const int* __restrict__ ei, int* __restrict__ counts)
{
  int e = blockIdx.x * 256 + threadIdx.x;
  if (e < N_EDGES) {
    int d = ei[N_EDGES + e]; if ((unsigned)d >= N_NODES) d = 0;
    atomicAdd(&counts[d], 1);
  }
}

__global__ __launch_bounds__(256) void k_scan1(const int* __restrict__ counts,
                                               int* __restrict__ row_ptr, int* __restrict__ bsum)
{
  __shared__ int lds[256];
  int t = threadIdx.x;
  int base = blockIdx.x * 1024 + t * 4;
  int c0 = (base + 0) < N_NODES ? counts[base + 0] : 0;
  int c1 = (base + 1) < N_NODES ? counts[base + 1] : 0;
  int c2 = (base + 2) < N_NODES ? counts[base + 2] : 0;
  int c3 = (base + 3) < N_NODES ? counts[base + 3] : 0;
  int s = c0 + c1 + c2 + c3;
  lds[t] = s; __syncthreads();
  for (int off = 1; off < 256; off <<= 1) {
    int v = (t >= off) ? lds[t - off] : 0;
    __syncthreads();
    lds[t] += v;
    __syncthreads();
  }
  int incl = lds[t];
  int excl = incl - s;
  if (base + 0 < N_NODES) row_ptr[base + 0] = excl;
  if (base + 1 < N_NODES) row_ptr[base + 1] = excl + c0;
  if (base + 2 < N_NODES) row_ptr[base + 2] = excl + c0 + c1;
  if (base + 3 < N_NODES) row_ptr[base + 3] = excl + c0 + c1 + c2;
  if (t == 255) bsum[blockIdx.x] = incl;
}

__global__ __launch_bounds__(64) void k_scan2(int* __restrict__ bsum, int nb)
{
  __shared__ int l[64];
  int t = threadIdx.x;
  if (t < nb) l[t] = bsum[t];
  __syncthreads();
  if (t == 0) { int run = 0; for (int i = 0; i < nb; i++) { int v = l[i]; l[i] = run; run += v; } }
  __syncthreads();
  if (t < nb) bsum[t] = l[t];
}

__global__ __launch_bounds__(256) void k_scan3(int* __restrict__ row_ptr, int* __restrict__ cursor,
                                               const int* __restrict__ bsum)
{
  int t = threadIdx.x;
  int base = blockIdx.x * 1024 + t * 4;
  int add = bsum[blockIdx.x];
#pragma unroll
  for (int j = 0; j < 4; j++) {
    int i = base + j;
    if (i < N_NODES) { int v = row_ptr[i] + add; row_ptr[i] = v; cursor[i] = v; }
  }
  if (blockIdx.x == 0 && t == 0) row_ptr[N_NODES] = N_EDGES;
}

// ---------- scatter: CSR perm + pack edge_attr to bf16 CSR order ----------
__global__ __launch_bounds__(256) void k_scatter(const int* __restrict__ ei,
                                                 int* __restrict__ cursor,
                                                 int* __restrict__ srcs,
                                                 const void* __restrict__ ea,
                                                 const int* __restrict__ flags,
                                                 unsigned short* __restrict__ eap)
{
  int e = blockIdx.x * 256 + threadIdx.x;
  if (e >= N_EDGES) return;
  int d = ei[N_EDGES + e]; if ((unsigned)d >= N_NODES) d = 0;
  int s = ei[e];           if ((unsigned)s >= N_NODES) s = 0;
  int p = atomicAdd(&cursor[d], 1);
  if ((unsigned)p >= N_EDGES) return;
  srcs[p] = s;
  unsigned short* op = eap + (size_t)p * 32;
  if (flags[1]) {
    const float* ip = (const float*)ea + (size_t)e * 32;
#pragma unroll
    for (int q = 0; q < 2; q++) {
      float4 a = *(const float4*)(ip + q * 16);
      float4 b = *(const float4*)(ip + q * 16 + 4);
      float4 c = *(const float4*)(ip + q * 16 + 8);
      float4 dd = *(const float4*)(ip + q * 16 + 12);
      uint4 u0, u1;
      u0.x = (unsigned)f2bf(a.x) | ((unsigned)f2bf(a.y) << 16);
      u0.y = (unsigned)f2bf(a.z) | ((unsigned)f2bf(a.w) << 16);
      u0.z = (unsigned)f2bf(b.x) | ((unsigned)f2bf(b.y) << 16);
      u0.w = (unsigned)f2bf(b.z) | ((unsigned)f2bf(b.w) << 16);
      u1.x = (unsigned)f2bf(c.x) | ((unsigned)f2bf(c.y) << 16);
      u1.y = (unsigned)f2bf(c.z) | ((unsigned)f2bf(c.w) << 16);
      u1.z = (unsigned)f2bf(dd.x) | ((unsigned)f2bf(dd.y) << 16);
      u1.w = (unsigned)f2bf(dd.z) | ((unsigned)f2bf(dd.w) << 16);
      *(uint4*)(op + q * 16) = u0;
      *(uint4*)(op + q * 16 + 8) = u1;
    }
  } else {
    const uint4* ip = (const uint4*)((const unsigned short*)ea + (size_t)e * 32);
#pragma unroll
    for (int q = 0; q < 4; q++) *(uint4*)(op + q * 8) = ip[q];
  }
}

// ---------- layer-1 fused score+aggregate, 2-tile (32 edges/iter), dwordx4 gathers ----------
// wave per node, 8 nodes/block (2 reps of 4). xlp/xrp are fragment-ordered:
// lane quad's 32 channels = 64 contiguous bytes -> 4 dwordx4 per edge.
__global__ __launch_bounds__(256, 3) void k_fuse1(
    const unsigned short* __restrict__ eap, const int* __restrict__ srcs,
    const int* __restrict__ row_ptr,
    const unsigned int* __restrict__ xlp, const unsigned int* __restrict__ xrp,
    const void* __restrict__ We, const void* __restrict__ att,
    const void* __restrict__ bias, const int* __restrict__ flags,
    float* __restrict__ hout)
{
  __shared__ unsigned short wt[128 * 34];   // WeT[ch][k], stride 34
  __shared__ float at[128];
  int tid = threadIdx.x;
  {
    int f = flags[6];
    for (int i2 = tid; i2 < 4096; i2 += 256) {   // We[k][c] -> wt[c*34+k]
      int k = i2 >> 7, c = i2 & 127;
      wt[c * 34 + k] = f ? f2bf(((const float*)We)[i2]) : ((const unsigned short*)We)[i2];
    }
  }
  if (tid < 128) at[tid] = loadF(att, flags[7], tid);
  __syncthreads();
  int lane = tid & 63;
  int idx16 = lane & 15, quad = lane >> 4;
  bf16x8 af[8];
#pragma unroll
  for (int t = 0; t < 8; t++)
    af[t] = *(const bf16x8*)(wt + (t * 16 + idx16) * 34 + quad * 8);
  int wv = tid >> 6;
#pragma unroll 1
  for (int rep = 0; rep < 2; rep++) {
    int i = blockIdx.x * 8 + rep * 4 + wv;
    int p0 = row_ptr[i], p1 = row_ptr[i + 1];
    uint2 rv[8];
#pragma unroll
    for (int t4 = 0; t4 < 4; t4++) {
      uint4 u = *(const uint4*)(xrp + (size_t)i * 64 + quad * 16 + t4 * 4);
      rv[2 * t4]     = make_uint2(u.x, u.y);
      rv[2 * t4 + 1] = make_uint2(u.z, u.w);
    }
    float acc[32];
#pragma unroll
    for (int k = 0; k < 32; k++) acc[k] = 0.f;
    float den0 = 0.f, den1 = 0.f, den2 = 0.f, den3 = 0.f;
    for (int jb = p0; jb < p1; jb += 32) {
      int jA = jb + idx16, jB = jA + 16;
      int aA = jA < p1, aB = jB < p1;
      int jcA = aA ? jA : p0, jcB = aB ? jB : p0;
      int sA = srcs[jcA], sB = srcs[jcB];
      bf16x8 bfA = *(const bf16x8*)(eap + (size_t)jcA * 32 + quad * 8);
      bf16x8 bfB = *(const bf16x8*)(eap + (size_t)jcB * 32 + quad * 8);
      uint2 xvA[8], xvB[8];
#pragma unroll
      for (int t4 = 0; t4 < 4; t4++) {
        uint4 u = *(const uint4*)(xlp + (size_t)sA * 64 + quad * 16 + t4 * 4);
        xvA[2 * t4]     = make_uint2(u.x, u.y);
        xvA[2 * t4 + 1] = make_uint2(u.z, u.w);
      }
#pragma unroll
      for (int t4 = 0; t4 < 4; t4++) {
        uint4 u = *(const uint4*)(xlp + (size_t)sB * 64 + quad * 16 + t4 * 4);
        xvB[2 * t4]     = make_uint2(u.x, u.y);
        xvB[2 * t4 + 1] = make_uint2(u.z, u.w);
      }
      float pA0 = 0.f, pA1 = 0.f, pA2 = 0.f, pA3 = 0.f;
      float pB0 = 0.f, pB1 = 0.f, pB2 = 0.f, pB3 = 0.f;
#pragma unroll
      for (int t = 0; t < 8; t++) {
        float4 av = *(const float4*)(at + t * 16 + quad * 4);
        uint2 r = rv[t];
        f32x4 cA = {0.f, 0.f, 0.f, 0.f};
        cA = __builtin_amdgcn_mfma_f32_16x16x32_bf16(af[t], bfA, cA, 0, 0, 0);
        float zA0 = cA[0] + lo16(xvA[t].x) + lo16(r.x);
        float zA1 = cA[1] + hi16(xvA[t].x) + hi16(r.x);
        float zA2 = cA[2] + lo16(xvA[t].y) + lo16(r.y);
        float zA3 = cA[3] + hi16(xvA[t].y) + hi16(r.y);
        zA0 = zA0 > 0.f ? zA0 : 0.2f * zA0;
        zA1 = zA1 > 0.f ? zA1 : 0.2f * zA1;
        zA2 = zA2 > 0.f ? zA2 : 0.2f * zA2;
        zA3 = zA3 > 0.f ? zA3 : 0.2f * zA3;
        float ppA = fmaf(av.x, zA0, fmaf(av.y, zA1, fmaf(av.z, zA2, av.w * zA3)));
        f32x4 cB = {0.f, 0.f, 0.f, 0.f};
        cB = __builtin_amdgcn_mfma_f32_16x16x32_bf16(af[t], bfB, cB, 0, 0, 0);
        float zB0 = cB[0] + lo16(xvB[t].x) + lo16(r.x);
        float zB1 = cB[1] + hi16(xvB[t].x) + hi16(r.x);
        float zB2 = cB[2] + lo16(xvB[t].y) + lo16(r.y);
        float zB3 = cB[3] + hi16(xvB[t].y) + hi16(r.y);
        zB0 = zB0 > 0.f ? zB0 : 0.2f * zB0;
        zB1 = zB1 > 0.f ? zB1 : 0.2f * zB1;
        zB2 = zB2 > 0.f ? zB2 : 0.2f * zB2;
        zB3 = zB3 > 0.f ? zB3 : 0.2f * zB3;
        float ppB = fmaf(av.x, zB0, fmaf(av.y, zB1, fmaf(av.z, zB2, av.w * zB3)));
        if (t < 2)      { pA0 += ppA; pB0 += ppB; }
        else if (t < 4) { pA1 += ppA; pB1 += ppB; }
        else if (t < 6) { pA2 += ppA; pB2 += ppB; }
        else            { pA3 += ppA; pB3 += ppB; }
      }
      pA0 += __shfl_xor(pA0, 16, 64); pA0 += __shfl_xor(pA0, 32, 64);
      pA1 += __shfl_xor(pA1, 16, 64); pA1 += __shfl_xor(pA1, 32, 64);
      pA2 += __shfl_xor(pA2, 16, 64); pA2 += __shfl_xor(pA2, 32, 64);
      pA3 += __shfl_xor(pA3, 16, 64); pA3 += __shfl_xor(pA3, 32, 64);
      pB0 += __shfl_xor(pB0, 16, 64); pB0 += __shfl_xor(pB0, 32, 64);
      pB1 += __shfl_xor(pB1, 16, 64); pB1 += __shfl_xor(pB1, 32, 64);
      pB2 += __shfl_xor(pB2, 16, 64); pB2 += __shfl_xor(pB2, 32, 64);
      pB3 += __shfl_xor(pB3, 16, 64); pB3 += __shfl_xor(pB3, 32, 64);
      float wA0 = aA ? __expf(fminf(fin(pA0), 25.f)) : 0.f;
      float wA1 = aA ? __expf(fminf(fin(pA1), 25.f)) : 0.f;
      float wA2 = aA ? __expf(fminf(fin(pA2), 25.f)) : 0.f;
      float wA3 = aA ? __expf(fminf(fin(pA3), 25.f)) : 0.f;
      float wB0 = aB ? __expf(fminf(fin(pB0), 25.f)) : 0.f;
      float wB1 = aB ? __expf(fminf(fin(pB1), 25.f)) : 0.f;
      float wB2 = aB ? __expf(fminf(fin(pB2), 25.f)) : 0.f;
      float wB3 = aB ? __expf(fminf(fin(pB3), 25.f)) : 0.f;
      den0 += wA0 + wB0; den1 += wA1 + wB1;
      den2 += wA2 + wB2; den3 += wA3 + wB3;
#pragma unroll
      for (int t = 0; t < 8; t++) {
        float whA = (t < 2) ? wA0 : (t < 4) ? wA1 : (t < 6) ? wA2 : wA3;
        float whB = (t < 2) ? wB0 : (t < 4) ? wB1 : (t < 6) ? wB2 : wB3;
        acc[t * 4 + 0] = fmaf(whA, lo16(xvA[t].x), fmaf(whB, lo16(xvB[t].x), acc[t * 4 + 0]));
        acc[t * 4 + 1] = fmaf(whA, hi16(xvA[t].x), fmaf(whB, hi16(xvB[t].x), acc[t * 4 + 1]));
        acc[t * 4 + 2] = fmaf(whA, lo16(xvA[t].y), fmaf(whB, lo16(xvB[t].y), acc[t * 4 + 2]));
        acc[t * 4 + 3] = fmaf(whA, hi16(xvA[t].y), fmaf(whB, hi16(xvB[t].y), acc[t * 4 + 3]));
      }
    }
    // edge-dim reduce over idx16 lanes
#pragma unroll
    for (int k = 0; k < 32; k++) {
      acc[k] += __shfl_xor(acc[k], 1, 64); acc[k] += __shfl_xor(acc[k], 2, 64);
      acc[k] += __shfl_xor(acc[k], 4, 64); acc[k] += __shfl_xor(acc[k], 8, 64);
    }
    den0 += __shfl_xor(den0, 1, 64); den0 += __shfl_xor(den0, 2, 64);
    den0 += __shfl_xor(den0, 4, 64); den0 += __shfl_xor(den0, 8, 64);
    den1 += __shfl_xor(den1, 1, 64); den1 += __shfl_xor(den1, 2, 64);
    den1 += __shfl_xor(den1, 4, 64); den1 += __shfl_xor(den1, 8, 64);
    den2 += __shfl_xor(den2, 1, 64); den2 += __shfl_xor(den2, 2, 64);
    den2 += __shfl_xor(den2, 4, 64); den2 += __shfl_xor(den2, 8, 64);
    den3 += __shfl_xor(den3, 1, 64); den3 += __shfl_xor(den3, 2, 64);
    den3 += __shfl_xor(den3, 4, 64); den3 += __shfl_xor(den3, 8, 64);
    if (idx16 == 0) {
      float inv0 = 1.f / (den0 + 1e-16f);
      float inv1 = 1.f / (den1 + 1e-16f);
      float inv2 = 1.f / (den2 + 1e-16f);
      float inv3 = 1.f / (den3 + 1e-16f);
      int fB = flags[8];
#pragma unroll
      for (int t = 0; t < 8; t++) {
        float invh = (t < 2) ? inv0 : (t < 4) ? inv1 : (t < 6) ? inv2 : inv3;
        int ch = t * 16 + quad * 4;
        float4 o;
        o.x = fin(fmaf(acc[t * 4 + 0], invh, loadF(bias, fB, ch + 0)));
        o.y = fin(fmaf(acc[t * 4 + 1], invh, loadF(bias, fB, ch + 1)));
        o.z = fin(fmaf(acc[t * 4 + 2], invh, loadF(bias, fB, ch + 2)));
        o.w = fin(fmaf(acc[t * 4 + 3], invh, loadF(bias, fB, ch + 3)));
        o.x = o.x > 0.f ? o.x : __expf(o.x) - 1.f;
        o.y = o.y > 0.f ? o.y : __expf(o.y) - 1.f;
        o.z = o.z > 0.f ? o.z : __expf(o.z) - 1.f;
        o.w = o.w > 0.f ? o.w : __expf(o.w) - 1.f;
        *(float4*)(hout + (size_t)i * 128 + ch) = o;
      }
    }
  }
}

// ---------- layer-2 fused score+aggregate (H=1, C=64), 2-tile ----------
__global__ __launch_bounds__(256, 4) void k_fuse2(
    const unsigned short* __restrict__ eap, const int* __restrict__ srcs,
    const int* __restrict__ row_ptr,
    const unsigned int* __restrict__ xlp, const unsigned int* __restrict__ xrp,
    const void* __restrict__ We, const void* __restrict__ att,
    const void* __restrict__ bias, const int* __restrict__ flags,
    void* __restrict__ out)
{
  __shared__ unsigned short wt[64 * 34];
  __shared__ float at[64];
  int tid = threadIdx.x;
  {
    int f = flags[13];
    for (int i2 = tid; i2 < 2048; i2 += 256) {   // We[k][c] -> wt[c*34+k]
      int k = i2 >> 6, c = i2 & 63;
      wt[c * 34 + k] = f ? f2bf(((const float*)We)[i2]) : ((const unsigned short*)We)[i2];
    }
  }
  if (tid < 64) at[tid] = loadF(att, flags[14], tid);
  __syncthreads();
  int lane = tid & 63;
  int idx16 = lane & 15, quad = lane >> 4;
  bf16x8 af[4];
#pragma unroll
  for (int t = 0; t < 4; t++)
    af[t] = *(const bf16x8*)(wt + (t * 16 + idx16) * 34 + quad * 8);
  int wv = tid >> 6;
#pragma unroll 1
  for (int rep = 0; rep < 2; rep++) {
    int i = blockIdx.x * 8 + rep * 4 + wv;
    int p0 = row_ptr[i], p1 = row_ptr[i + 1];
    uint2 rv[4];
#pragma unroll
    for (int k = 0; k < 2; k++) {
      uint4 u = *(const uint4*)(xrp + (size_t)i * 32 + quad * 8 + k * 4);
      rv[2 * k]     = make_uint2(u.x, u.y);
      rv[2 * k + 1] = make_uint2(u.z, u.w);
    }
    float acc[16];
#pragma unroll
    for (int k = 0; k < 16; k++) acc[k] = 0.f;
    float den = 0.f;
    for (int jb = p0; jb < p1; jb += 32) {
      int jA = jb + idx16, jB = jA + 16;
      int aA = jA < p1, aB = jB < p1;
      int jcA = aA ? jA : p0, jcB = aB ? jB : p0;
      int sA = srcs[jcA], sB = srcs[jcB];
      bf16x8 bfA = *(const bf16x8*)(eap + (size_t)jcA * 32 + quad * 8);
      bf16x8 bfB = *(const bf16x8*)(eap + (size_t)jcB * 32 + quad * 8);
      uint2 xvA[4], xvB[4];
#pragma unroll
      for (int k = 0; k < 2; k++) {
        uint4 u = *(const uint4*)(xlp + (size_t)sA * 32 + quad * 8 + k * 4);
        xvA[2 * k]     = make_uint2(u.x, u.y);
        xvA[2 * k + 1] = make_uint2(u.z, u.w);
      }
#pragma unroll
      for (int k = 0; k < 2; k++) {
        uint4 u = *(const uint4*)(xlp + (size_t)sB * 32 + quad * 8 + k * 4);
        xvB[2 * k]     = make_uint2(u.x, u.y);
        xvB[2 * k + 1] = make_uint2(u.z, u.w);
      }
      float phA = 0.f, phB = 0.f;
#pragma unroll
      for (int t = 0; t < 4; t++) {
        float4 av = *(const float4*)(at + t * 16 + quad * 4);
        uint2 r = rv[t];
        f32x4 cA = {0.f, 0.f, 0.f, 0.f};
        cA = __builtin_amdgcn_mfma_f32_16x16x32_bf16(af[t], bfA, cA, 0, 0, 0);
        float zA0 = cA[0] + lo16(xvA[t].x) + lo16(r.x);
        float zA1 = cA[1] + hi16(xvA[t].x) + hi16(r.x);
        float zA2 = cA[2] + lo16(xvA[t].y) + lo16(r.y);
        float zA3 = cA[3] + hi16(xvA[t].y) + hi16(r.y);
        zA0 = zA0 > 0.f ? zA0 : 0.2f * zA0;
        zA1 = zA1 > 0.f ? zA1 : 0.2f * zA1;
        zA2 = zA2 > 0.f ? zA2 : 0.2f * zA2;
        zA3 = zA3 > 0.f ? zA3 : 0.2f * zA3;
        phA += fmaf(av.x, zA0, fmaf(av.y, zA1, fmaf(av.z, zA2, av.w * zA3)));
        f32x4 cB = {0.f, 0.f, 0.f, 0.f};
        cB = __builtin_amdgcn_mfma_f32_16x16x32_bf16(af[t], bfB, cB, 0, 0, 0);
        float zB0 = cB[0] + lo16(xvB[t].x) + lo16(r.x);
        float zB1 = cB[1] + hi16(xvB[t].x) + hi16(r.x);
        float zB2 = cB[2] + lo16(xvB[t].y) + lo16(r.y);
        float zB3 = cB[3] + hi16(xvB[t].y) + hi16(r.y);
        zB0 = zB0 > 0.f ? zB0 : 0.2f * zB0;
        zB1 = zB1 > 0.f ? zB1 : 0.2f * zB1;
        zB2 = zB2 > 0.f ? zB2 : 0.2f * zB2;
        zB3 = zB3 > 0.f ? zB3 : 0.2f * zB3;
        phB += fmaf(av.x, zB0, fmaf(av.y, zB1, fmaf(av.z, zB2, av.w * zB3)));
      }
      phA += __shfl_xor(phA, 16, 64); phA += __shfl_xor(phA, 32, 64);
      phB += __shfl_xor(phB, 16, 64); phB += __shfl_xor(phB, 32, 64);
      float wA = aA ? __expf(fminf(fin(phA), 25.f)) : 0.f;
      float wB = aB ? __expf(fminf(fin(phB), 25.f)) : 0.f;
      den += wA + wB;
#pragma unroll
      for (int t = 0; t < 4; t++) {
        acc[t * 4 + 0] = fmaf(wA, lo16(xvA[t].x), fmaf(wB, lo16(xvB[t].x), acc[t * 4 + 0]));
        acc[t * 4 + 1] = fmaf(wA, hi16(xvA[t].x), fmaf(wB, hi16(xvB[t].x), acc[t * 4 + 1]));
        acc[t * 4 + 2] = fmaf(wA, lo16(xvA[t].y), fmaf(wB, lo16(xvB[t].y), acc[t * 4 + 2]));
        acc[t * 4 + 3] = fmaf(wA, hi16(xvA[t].y), fmaf(wB, hi16(xvB[t].y), acc[t * 4 + 3]));
      }
    }
#pragma unroll
    for (int k = 0; k < 16; k++) {
      acc[k] += __shfl_xor(acc[k], 1, 64); acc[k] += __shfl_xor(acc[k], 2, 64);
      acc[k] += __shfl_xor(acc[k], 4, 64); acc[k] += __shfl_xor(acc[k], 8, 64);
    }
    den += __shfl_xor(den, 1, 64); den += __shfl_xor(den, 2, 64);
    den += __shfl_xor(den, 4, 64); den += __shfl_xor(den, 8, 64);
    if (idx16 == 0) {
      float inv = 1.f / (den + 1e-16f);
      int fB = flags[15];
#pragma unroll
      for (int t = 0; t < 4; t++) {
        int ch = t * 16 + quad * 4;
        float o0 = fin(fmaf(acc[t * 4 + 0], inv, loadF(bias, fB, ch + 0)));
        float o1 = fin(fmaf(acc[t * 4 + 1], inv, loadF(bias, fB, ch + 1)));
        float o2 = fin(fmaf(acc[t * 4 + 2], inv, loadF(bias, fB, ch + 2)));
        float o3 = fin(fmaf(acc[t * 4 + 3], inv, loadF(bias, fB, ch + 3)));
        if (flags[0]) {
          *(float4*)((float*)out + (size_t)i * 64 + ch) = make_float4(o0, o1, o2, o3);
        } else {
          uint2 u;
          u.x = (unsigned)f2bf(o0) | ((unsigned)f2bf(o1) << 16);
          u.y = (unsigned)f2bf(o2) | ((unsigned)f2bf(o3) << 16);
          *(uint2*)((unsigned short*)out + (size_t)i * 64 + ch) = u;
        }
      }
    }
  }
}

extern "C" void kernel_launch(void* const* d_in, const int* in_sizes, int n_in,
                              void* d_out, int out_size, void* d_ws, size_t ws_size,
                              hipStream_t stream)
{
  (void)n_in; (void)out_size; (void)ws_size;
  const void* x    = d_in[0];
  const int*  ei   = (const int*)d_in[1];
  const void* ea   = d_in[2];
  const void* Wl1  = d_in[3];
  const void* bl1  = d_in[4];
  const void* Wr1  = d_in[5];
  const void* br1  = d_in[6];
  const void* We1  = d_in[7];
  const void* att1 = d_in[8];
  const void* bias1= d_in[9];
  const void* Wl2  = d_in[10];
  const void* bl2  = d_in[11];
  const void* Wr2  = d_in[12];
  const void* br2  = d_in[13];
  const void* We2  = d_in[14];
  const void* att2 = d_in[15];
  const void* bias2= d_in[16];

  char* ws = (char*)d_ws;
  size_t off = 0;
  auto take = [&](size_t bytes) -> char* {
    char* p = ws + off;
    off += (bytes + 255) & ~(size_t)255;
    return p;
  };
  unsigned int* xl1p = (unsigned int*)take((size_t)N_NODES * 64 * 4);   // 12.8 MB
  unsigned int* xr1p = (unsigned int*)take((size_t)N_NODES * 64 * 4);   // 12.8 MB
  float* hbuf   = (float*)take((size_t)N_NODES * 128 * 4);              // 25.6 MB
  unsigned short* eap = (unsigned short*)take((size_t)(N_EDGES + 16) * 32 * 2); // 51.2 MB
  int*   counts = (int*)  take((size_t)N_NODES * 4);
  int*   row_ptr= (int*)  take((size_t)(N_NODES + 1) * 4);
  int*   cursor = (int*)  take((size_t)N_NODES * 4);
  int*   srcs   = (int*)  take((size_t)N_EDGES * 4);
  int*   bsum   = (int*)  take(64 * 4);
  int*   flags  = (int*)  take(64 * 4);
  unsigned int* xl2p = xl1p;      // layer-2 reuses ([N,32] <= [N,64])
  unsigned int* xr2p = xr1p;

  Ptrs tl;
  const int map[16] = {0, 2, 3, 4, 5, 6, 7, 8, 9, 10, 11, 12, 13, 14, 15, 16};
  for (int j = 0; j < 16; j++) { tl.p[j] = d_in[map[j]]; tl.n[j] = in_sizes[map[j]]; }

  int nb = (N_NODES + 1023) / 1024;
  k_detect<<<16, 256, 0, stream>>>(tl, flags);
  k_zero<<<(N_NODES + 255) / 256, 256, 0, stream>>>(counts, N_NODES);
  k_gemm1<<<dim3((N_NODES + 31) / 32, 2), 256, 0, stream>>>(x, Wl1, bl1, Wr1, br1, flags, xl1p, xr1p);
  k_hist<<<(N_EDGES + 255) / 256, 256, 0, stream>>>(ei, counts);
  k_scan1<<<nb, 256, 0, stream>>>(counts, row_ptr, bsum);
  k_scan2<<<1, 64, 0, stream>>>(bsum, nb);
  k_scan3<<<nb, 256, 0, stream>>>(row_ptr, cursor, bsum);
  k_scatter<<<(N_EDGES + 255) / 256, 256, 0, stream>>>(ei, cursor, srcs, ea, flags, eap);
  k_fuse1<<<N_NODES / 8, 256, 0, stream>>>(eap, srcs, row_ptr, xl1p, xr1p, We1, att1, bias1, flags, hbuf);
  k_gemm2<<<dim3((N_NODES + 31) / 32, 2), 256, 0, stream>>>(hbuf, Wl2, bl2, Wr2, br2, flags, xl2p, xr2p);
  k_fuse2<<<N_NODES / 8, 256, 0, stream>>>(eap, srcs, row_ptr, xl2p, xr2p, We2, att2, bias2, flags, d_out);
}

// Round 5
// 867.218 us; speedup vs baseline: 1.2038x; 1.2038x over previous
//
#include <hip/hip_runtime.h>
#include <stdint.h>

#define N_NODES 50000
#define N_EDGES 800000

// flag indices: 0:x 1:ea 2:Wl1 3:bl1 4:Wr1 5:br1 6:We1 7:att1 8:bias1
//               9:Wl2 10:bl2 11:Wr2 12:br2 13:We2 14:att2 15:bias2
struct Ptrs { const void* p[16]; int n[16]; };

typedef __attribute__((ext_vector_type(8))) short bf16x8;
typedef __attribute__((ext_vector_type(4))) float f32x4;

__device__ __forceinline__ float bf2f(unsigned short u){
  union { unsigned int i; float f; } v; v.i = ((unsigned int)u) << 16; return v.f;
}
__device__ __forceinline__ float lo16(unsigned int u){ union { unsigned int i; float f; } v; v.i = u << 16; return v.f; }
__device__ __forceinline__ float hi16(unsigned int u){ union { unsigned int i; float f; } v; v.i = u & 0xffff0000u; return v.f; }
__device__ __forceinline__ unsigned short f2bf(float f){
  if (!(f == f)) return 0;
  unsigned int x = __float_as_uint(f);
  unsigned int r = (x + 0x7fffu + ((x >> 16) & 1u)) >> 16;
  return (unsigned short)r;
}
__device__ __forceinline__ float fin(float v){
  if (!(v == v)) return 0.f;
  return fminf(fmaxf(v, -1e30f), 1e30f);
}
__device__ __forceinline__ float loadF(const void* p, int f32, size_t idx){
  return f32 ? ((const float*)p)[idx] : bf2f(((const unsigned short*)p)[idx]);
}

// stage n bf16 elems of W (bf16 or f32 source) into LDS; n multiple of 2048
__device__ __forceinline__ void stageW(unsigned short* dst, const void* src, int n, int f32, int tid){
  if (f32) {
    for (int i = tid * 8; i < n; i += 2048) {
      float4 a = *(const float4*)((const float*)src + i);
      float4 b = *(const float4*)((const float*)src + i + 4);
      uint4 u;
      u.x = (unsigned)f2bf(a.x) | ((unsigned)f2bf(a.y) << 16);
      u.y = (unsigned)f2bf(a.z) | ((unsigned)f2bf(a.w) << 16);
      u.z = (unsigned)f2bf(b.x) | ((unsigned)f2bf(b.y) << 16);
      u.w = (unsigned)f2bf(b.z) | ((unsigned)f2bf(b.w) << 16);
      *(uint4*)(dst + i) = u;
    }
  } else {
    for (int i = tid * 8; i < n; i += 2048)
      *(uint4*)(dst + i) = *(const uint4*)((const unsigned short*)src + i);
  }
}

// ---------- dtype detect ----------
__global__ __launch_bounds__(256) void k_detect(Ptrs tl, int* __restrict__ flags)
{
  __shared__ int red[256];
  int b = blockIdx.x, t = threadIdx.x;
  const unsigned short* p = (const unsigned short*)tl.p[b];
  int n = tl.n[b]; if (n > 16384) n = 16384;
  int crazy = 0;
  for (int i = t; i < n; i += 256) {
    unsigned short u = p[i];
    if (u) {
      int ex = (u >> 7) & 0xFF;
      if (ex == 0xFF || ex < 0x60) crazy++;
    }
  }
  red[t] = crazy; __syncthreads();
  for (int off = 128; off; off >>= 1) { if (t < off) red[t] += red[t + off]; __syncthreads(); }
  if (t == 0) flags[b] = (red[0] * 10 > n) ? 1 : 0;
}

__global__ __launch_bounds__(256) void k_zero(int* __restrict__ p, int n)
{
  int i = blockIdx.x * 256 + threadIdx.x;
  if (i < n) p[i] = 0;
}

// ---------- layer-1 GEMM: xl1p / xr1p, packed bf16 [N,64] uints in FRAGMENT order ----------
// fragment order: natural uint u = t*8 + quad*2 + b  ->  u' = quad*16 + t*2 + b
// so lane 'quad' of the fuse kernels reads its 32 channels as 64 contiguous bytes.
__global__ __launch_bounds__(256) void k_gemm1(
    const void* __restrict__ x,
    const void* __restrict__ Wl, const void* __restrict__ bl,
    const void* __restrict__ Wr, const void* __restrict__ br,
    const int* __restrict__ flags,
    unsigned int* __restrict__ xlp, unsigned int* __restrict__ xrp)
{
  __shared__ float xs[32 * 132];
  __shared__ unsigned short ws[128 * 128];
  const void* W  = blockIdx.y ? Wr : Wl;
  const void* bb = blockIdx.y ? br : bl;
  int fW = blockIdx.y ? flags[4] : flags[2];
  int fB = blockIdx.y ? flags[5] : flags[3];
  int fX = flags[0];
  unsigned int* outp = blockIdx.y ? xrp : xlp;
  int tid = threadIdx.x;
  int row0 = blockIdx.x * 32;
  stageW(ws, W, 128 * 128, fW, tid);
  for (int i = tid * 4; i < 32 * 128; i += 1024) {
    int r = i >> 7, k = i & 127;
    int row = row0 + r;
    float4 v = make_float4(0.f, 0.f, 0.f, 0.f);
    if (row < N_NODES) {
      if (fX) v = *(const float4*)((const float*)x + (size_t)row * 128 + k);
      else {
        uint2 u = *(const uint2*)((const unsigned short*)x + (size_t)row * 128 + k);
        v.x = lo16(u.x); v.y = hi16(u.x); v.z = lo16(u.y); v.w = hi16(u.y);
      }
    }
    *(float4*)(xs + r * 132 + k) = v;
  }
  __syncthreads();
  int r = tid >> 3, cg = tid & 7;
  float acc[16];
#pragma unroll
  for (int j = 0; j < 16; j++) acc[j] = 0.f;
#pragma unroll 4
  for (int k = 0; k < 128; k++) {
    float xv = xs[r * 132 + k];
    uint4 p0 = *(const uint4*)(ws + k * 128 + cg * 8);
    uint4 p1 = *(const uint4*)(ws + k * 128 + 64 + cg * 8);
    acc[0]  = fmaf(xv, lo16(p0.x), acc[0]);  acc[1]  = fmaf(xv, hi16(p0.x), acc[1]);
    acc[2]  = fmaf(xv, lo16(p0.y), acc[2]);  acc[3]  = fmaf(xv, hi16(p0.y), acc[3]);
    acc[4]  = fmaf(xv, lo16(p0.z), acc[4]);  acc[5]  = fmaf(xv, hi16(p0.z), acc[5]);
    acc[6]  = fmaf(xv, lo16(p0.w), acc[6]);  acc[7]  = fmaf(xv, hi16(p0.w), acc[7]);
    acc[8]  = fmaf(xv, lo16(p1.x), acc[8]);  acc[9]  = fmaf(xv, hi16(p1.x), acc[9]);
    acc[10] = fmaf(xv, lo16(p1.y), acc[10]); acc[11] = fmaf(xv, hi16(p1.y), acc[11]);
    acc[12] = fmaf(xv, lo16(p1.z), acc[12]); acc[13] = fmaf(xv, hi16(p1.z), acc[13]);
    acc[14] = fmaf(xv, lo16(p1.w), acc[14]); acc[15] = fmaf(xv, hi16(p1.w), acc[15]);
  }
  int row = row0 + r;
  if (row < N_NODES) {
    unsigned int* op = outp + (size_t)row * 64;
    int tt = cg >> 1, qb = (cg & 1) * 2;
    unsigned int ou[4];
#pragma unroll
    for (int t = 0; t < 4; t++) {
      float f0 = fin(acc[2 * t]     + loadF(bb, fB, cg * 8 + 2 * t));
      float f1 = fin(acc[2 * t + 1] + loadF(bb, fB, cg * 8 + 2 * t + 1));
      ou[t] = (unsigned)f2bf(f0) | ((unsigned)f2bf(f1) << 16);
    }
    *(uint2*)(op + qb * 16 + tt * 2)       = make_uint2(ou[0], ou[1]);
    *(uint2*)(op + (qb + 1) * 16 + tt * 2) = make_uint2(ou[2], ou[3]);
#pragma unroll
    for (int t = 0; t < 4; t++) {
      float f0 = fin(acc[8 + 2 * t]     + loadF(bb, fB, 64 + cg * 8 + 2 * t));
      float f1 = fin(acc[8 + 2 * t + 1] + loadF(bb, fB, 64 + cg * 8 + 2 * t + 1));
      ou[t] = (unsigned)f2bf(f0) | ((unsigned)f2bf(f1) << 16);
    }
    *(uint2*)(op + qb * 16 + 8 + tt * 2)       = make_uint2(ou[0], ou[1]);
    *(uint2*)(op + (qb + 1) * 16 + 8 + tt * 2) = make_uint2(ou[2], ou[3]);
  }
}

// ---------- layer-2 GEMM: xl2p / xr2p, packed bf16 [N,32] uints in FRAGMENT order ----------
// natural uint u = t*8 + quad*2 + b (t=0..3) -> u' = quad*8 + t*2 + b
__global__ __launch_bounds__(256) void k_gemm2(
    const float* __restrict__ h,
    const void* __restrict__ Wl, const void* __restrict__ bl,
    const void* __restrict__ Wr, const void* __restrict__ br,
    const int* __restrict__ flags,
    unsigned int* __restrict__ xlp, unsigned int* __restrict__ xrp)
{
  __shared__ float hs[32 * 132];
  __shared__ unsigned short ws[128 * 64];
  const void* W  = blockIdx.y ? Wr : Wl;
  const void* bb = blockIdx.y ? br : bl;
  int fW = blockIdx.y ? flags[11] : flags[9];
  int fB = blockIdx.y ? flags[12] : flags[10];
  unsigned int* outp = blockIdx.y ? xrp : xlp;
  int tid = threadIdx.x;
  int row0 = blockIdx.x * 32;
  stageW(ws, W, 128 * 64, fW, tid);
  for (int i = tid * 4; i < 32 * 128; i += 1024) {
    int r = i >> 7, k = i & 127;
    int row = row0 + r;
    float4 v = make_float4(0.f, 0.f, 0.f, 0.f);
    if (row < N_NODES) v = *(const float4*)(h + (size_t)row * 128 + k);
    *(float4*)(hs + r * 132 + k) = v;
  }
  __syncthreads();
  int r = tid >> 3, cg = tid & 7;
  float acc[8];
#pragma unroll
  for (int j = 0; j < 8; j++) acc[j] = 0.f;
#pragma unroll 4
  for (int k = 0; k < 128; k++) {
    float hv = hs[r * 132 + k];
    uint4 p = *(const uint4*)(ws + k * 64 + cg * 8);
    acc[0] = fmaf(hv, lo16(p.x), acc[0]); acc[1] = fmaf(hv, hi16(p.x), acc[1]);
    acc[2] = fmaf(hv, lo16(p.y), acc[2]); acc[3] = fmaf(hv, hi16(p.y), acc[3]);
    acc[4] = fmaf(hv, lo16(p.z), acc[4]); acc[5] = fmaf(hv, hi16(p.z), acc[5]);
    acc[6] = fmaf(hv, lo16(p.w), acc[6]); acc[7] = fmaf(hv, hi16(p.w), acc[7]);
  }
  int row = row0 + r;
  if (row < N_NODES) {
    unsigned int* op = outp + (size_t)row * 32;
    int tt = cg >> 1, qb = (cg & 1) * 2;
    unsigned int ou[4];
#pragma unroll
    for (int t = 0; t < 4; t++) {
      float f0 = fin(acc[2 * t]     + loadF(bb, fB, cg * 8 + 2 * t));
      float f1 = fin(acc[2 * t + 1] + loadF(bb, fB, cg * 8 + 2 * t + 1));
      ou[t] = (unsigned)f2bf(f0) | ((unsigned)f2bf(f1) << 16);
    }
    *(uint2*)(op + qb * 8 + tt * 2)       = make_uint2(ou[0], ou[1]);
    *(uint2*)(op + (qb + 1) * 8 + tt * 2) = make_uint2(ou[2], ou[3]);
  }
}

// ---------- CSR build ----------
__global__ __launch_bounds__(256) void k_hist(const int* __restrict__ ei, int* __restrict__ counts)
{
  int e = blockIdx.x * 256 + threadIdx.x;
  if (e < N_EDGES) {
    int d = ei[N_EDGES + e]; if ((unsigned)d >= N_NODES) d = 0;
    atomicAdd(&counts[d], 1);
  }
}

__global__ __launch_bounds__(256) void k_scan1(const int* __restrict__ counts,
                                               int* __restrict__ row_ptr, int* __restrict__ bsum)
{
  __shared__ int lds[256];
  int t = threadIdx.x;
  int base = blockIdx.x * 1024 + t * 4;
  int c0 = (base + 0) < N_NODES ? counts[base + 0] : 0;
  int c1 = (base + 1) < N_NODES ? counts[base + 1] : 0;
  int c2 = (base + 2) < N_NODES ? counts[base + 2] : 0;
  int c3 = (base + 3) < N_NODES ? counts[base + 3] : 0;
  int s = c0 + c1 + c2 + c3;
  lds[t] = s; __syncthreads();
  for (int off = 1; off < 256; off <<= 1) {
    int v = (t >= off) ? lds[t - off] : 0;
    __syncthreads();
    lds[t] += v;
    __syncthreads();
  }
  int incl = lds[t];
  int excl = incl - s;
  if (base + 0 < N_NODES) row_ptr[base + 0] = excl;
  if (base + 1 < N_NODES) row_ptr[base + 1] = excl + c0;
  if (base + 2 < N_NODES) row_ptr[base + 2] = excl + c0 + c1;
  if (base + 3 < N_NODES) row_ptr[base + 3] = excl + c0 + c1 + c2;
  if (t == 255) bsum[blockIdx.x] = incl;
}

__global__ __launch_bounds__(64) void k_scan2(int* __restrict__ bsum, int nb)
{
  __shared__ int l[64];
  int t = threadIdx.x;
  if (t < nb) l[t] = bsum[t];
  __syncthreads();
  if (t == 0) { int run = 0; for (int i = 0; i < nb; i++) { int v = l[i]; l[i] = run; run += v; } }
  __syncthreads();
  if (t < nb) bsum[t] = l[t];
}

__global__ __launch_bounds__(256) void k_scan3(int* __restrict__ row_ptr, int* __restrict__ cursor,
                                               const int* __restrict__ bsum)
{
  int t = threadIdx.x;
  int base = blockIdx.x * 1024 + t * 4;
  int add = bsum[blockIdx.x];
#pragma unroll
  for (int j = 0; j < 4; j++) {
    int i = base + j;
    if (i < N_NODES) { int v = row_ptr[i] + add; row_ptr[i] = v; cursor[i] = v; }
  }
  if (blockIdx.x == 0 && t == 0) row_ptr[N_NODES] = N_EDGES;
}

// ---------- scatter: CSR perm + pack edge_attr to bf16 CSR order ----------
__global__ __launch_bounds__(256) void k_scatter(const int* __restrict__ ei,
                                                 int* __restrict__ cursor,
                                                 int* __restrict__ srcs,
                                                 const void* __restrict__ ea,
                                                 const int* __restrict__ flags,
                                                 unsigned short* __restrict__ eap)
{
  int e = blockIdx.x * 256 + threadIdx.x;
  if (e >= N_EDGES) return;
  int d = ei[N_EDGES + e]; if ((unsigned)d >= N_NODES) d = 0;
  int s = ei[e];           if ((unsigned)s >= N_NODES) s = 0;
  int p = atomicAdd(&cursor[d], 1);
  if ((unsigned)p >= N_EDGES) return;
  srcs[p] = s;
  unsigned short* op = eap + (size_t)p * 32;
  if (flags[1]) {
    const float* ip = (const float*)ea + (size_t)e * 32;
#pragma unroll
    for (int q = 0; q < 2; q++) {
      float4 a = *(const float4*)(ip + q * 16);
      float4 b = *(const float4*)(ip + q * 16 + 4);
      float4 c = *(const float4*)(ip + q * 16 + 8);
      float4 dd = *(const float4*)(ip + q * 16 + 12);
      uint4 u0, u1;
      u0.x = (unsigned)f2bf(a.x) | ((unsigned)f2bf(a.y) << 16);
      u0.y = (unsigned)f2bf(a.z) | ((unsigned)f2bf(a.w) << 16);
      u0.z = (unsigned)f2bf(b.x) | ((unsigned)f2bf(b.y) << 16);
      u0.w = (unsigned)f2bf(b.z) | ((unsigned)f2bf(b.w) << 16);
      u1.x = (unsigned)f2bf(c.x) | ((unsigned)f2bf(c.y) << 16);
      u1.y = (unsigned)f2bf(c.z) | ((unsigned)f2bf(c.w) << 16);
      u1.z = (unsigned)f2bf(dd.x) | ((unsigned)f2bf(dd.y) << 16);
      u1.w = (unsigned)f2bf(dd.z) | ((unsigned)f2bf(dd.w) << 16);
      *(uint4*)(op + q * 16) = u0;
      *(uint4*)(op + q * 16 + 8) = u1;
    }
  } else {
    const uint4* ip = (const uint4*)((const unsigned short*)ea + (size_t)e * 32);
#pragma unroll
    for (int q = 0; q < 4; q++) *(uint4*)(op + q * 8) = ip[q];
  }
}

// ---------- layer-1 fused score+aggregate, 2-tile (32 edges/iter), dwordx4 gathers ----------
// wave per node, 8 nodes/block (2 reps of 4). xlp/xrp are fragment-ordered:
// lane quad's 32 channels = 64 contiguous bytes -> 4 dwordx4 per edge.
// NOTE: no min-occupancy launch bound — the body needs ~150 VGPRs; forcing
// 3 waves/EU (85 VGPR cap) spills acc to scratch (660 MB of HBM writes, r3).
__global__ __launch_bounds__(256) void k_fuse1(
    const unsigned short* __restrict__ eap, const int* __restrict__ srcs,
    const int* __restrict__ row_ptr,
    const unsigned int* __restrict__ xlp, const unsigned int* __restrict__ xrp,
    const void* __restrict__ We, const void* __restrict__ att,
    const void* __restrict__ bias, const int* __restrict__ flags,
    float* __restrict__ hout)
{
  __shared__ unsigned short wt[128 * 34];   // WeT[ch][k], stride 34
  __shared__ float at[128];
  int tid = threadIdx.x;
  {
    int f = flags[6];
    for (int i2 = tid; i2 < 4096; i2 += 256) {   // We[k][c] -> wt[c*34+k]
      int k = i2 >> 7, c = i2 & 127;
      wt[c * 34 + k] = f ? f2bf(((const float*)We)[i2]) : ((const unsigned short*)We)[i2];
    }
  }
  if (tid < 128) at[tid] = loadF(att, flags[7], tid);
  __syncthreads();
  int lane = tid & 63;
  int idx16 = lane & 15, quad = lane >> 4;
  bf16x8 af[8];
#pragma unroll
  for (int t = 0; t < 8; t++)
    af[t] = *(const bf16x8*)(wt + (t * 16 + idx16) * 34 + quad * 8);
  int wv = tid >> 6;
#pragma unroll 1
  for (int rep = 0; rep < 2; rep++) {
    int i = blockIdx.x * 8 + rep * 4 + wv;
    int p0 = row_ptr[i], p1 = row_ptr[i + 1];
    uint2 rv[8];
#pragma unroll
    for (int t4 = 0; t4 < 4; t4++) {
      uint4 u = *(const uint4*)(xrp + (size_t)i * 64 + quad * 16 + t4 * 4);
      rv[2 * t4]     = make_uint2(u.x, u.y);
      rv[2 * t4 + 1] = make_uint2(u.z, u.w);
    }
    float acc[32];
#pragma unroll
    for (int k = 0; k < 32; k++) acc[k] = 0.f;
    float den0 = 0.f, den1 = 0.f, den2 = 0.f, den3 = 0.f;
    for (int jb = p0; jb < p1; jb += 32) {
      int jA = jb + idx16, jB = jA + 16;
      int aA = jA < p1, aB = jB < p1;
      int jcA = aA ? jA : p0, jcB = aB ? jB : p0;
      int sA = srcs[jcA], sB = srcs[jcB];
      bf16x8 bfA = *(const bf16x8*)(eap + (size_t)jcA * 32 + quad * 8);
      bf16x8 bfB = *(const bf16x8*)(eap + (size_t)jcB * 32 + quad * 8);
      uint2 xvA[8], xvB[8];
#pragma unroll
      for (int t4 = 0; t4 < 4; t4++) {
        uint4 u = *(const uint4*)(xlp + (size_t)sA * 64 + quad * 16 + t4 * 4);
        xvA[2 * t4]     = make_uint2(u.x, u.y);
        xvA[2 * t4 + 1] = make_uint2(u.z, u.w);
      }
#pragma unroll
      for (int t4 = 0; t4 < 4; t4++) {
        uint4 u = *(const uint4*)(xlp + (size_t)sB * 64 + quad * 16 + t4 * 4);
        xvB[2 * t4]     = make_uint2(u.x, u.y);
        xvB[2 * t4 + 1] = make_uint2(u.z, u.w);
      }
      float pA0 = 0.f, pA1 = 0.f, pA2 = 0.f, pA3 = 0.f;
      float pB0 = 0.f, pB1 = 0.f, pB2 = 0.f, pB3 = 0.f;
#pragma unroll
      for (int t = 0; t < 8; t++) {
        float4 av = *(const float4*)(at + t * 16 + quad * 4);
        uint2 r = rv[t];
        f32x4 cA = {0.f, 0.f, 0.f, 0.f};
        cA = __builtin_amdgcn_mfma_f32_16x16x32_bf16(af[t], bfA, cA, 0, 0, 0);
        float zA0 = cA[0] + lo16(xvA[t].x) + lo16(r.x);
        float zA1 = cA[1] + hi16(xvA[t].x) + hi16(r.x);
        float zA2 = cA[2] + lo16(xvA[t].y) + lo16(r.y);
        float zA3 = cA[3] + hi16(xvA[t].y) + hi16(r.y);
        zA0 = zA0 > 0.f ? zA0 : 0.2f * zA0;
        zA1 = zA1 > 0.f ? zA1 : 0.2f * zA1;
        zA2 = zA2 > 0.f ? zA2 : 0.2f * zA2;
        zA3 = zA3 > 0.f ? zA3 : 0.2f * zA3;
        float ppA = fmaf(av.x, zA0, fmaf(av.y, zA1, fmaf(av.z, zA2, av.w * zA3)));
        f32x4 cB = {0.f, 0.f, 0.f, 0.f};
        cB = __builtin_amdgcn_mfma_f32_16x16x32_bf16(af[t], bfB, cB, 0, 0, 0);
        float zB0 = cB[0] + lo16(xvB[t].x) + lo16(r.x);
        float zB1 = cB[1] + hi16(xvB[t].x) + hi16(r.x);
        float zB2 = cB[2] + lo16(xvB[t].y) + lo16(r.y);
        float zB3 = cB[3] + hi16(xvB[t].y) + hi16(r.y);
        zB0 = zB0 > 0.f ? zB0 : 0.2f * zB0;
        zB1 = zB1 > 0.f ? zB1 : 0.2f * zB1;
        zB2 = zB2 > 0.f ? zB2 : 0.2f * zB2;
        zB3 = zB3 > 0.f ? zB3 : 0.2f * zB3;
        float ppB = fmaf(av.x, zB0, fmaf(av.y, zB1, fmaf(av.z, zB2, av.w * zB3)));
        if (t < 2)      { pA0 += ppA; pB0 += ppB; }
        else if (t < 4) { pA1 += ppA; pB1 += ppB; }
        else if (t < 6) { pA2 += ppA; pB2 += ppB; }
        else            { pA3 += ppA; pB3 += ppB; }
      }
      pA0 += __shfl_xor(pA0, 16, 64); pA0 += __shfl_xor(pA0, 32, 64);
      pA1 += __shfl_xor(pA1, 16, 64); pA1 += __shfl_xor(pA1, 32, 64);
      pA2 += __shfl_xor(pA2, 16, 64); pA2 += __shfl_xor(pA2, 32, 64);
      pA3 += __shfl_xor(pA3, 16, 64); pA3 += __shfl_xor(pA3, 32, 64);
      pB0 += __shfl_xor(pB0, 16, 64); pB0 += __shfl_xor(pB0, 32, 64);
      pB1 += __shfl_xor(pB1, 16, 64); pB1 += __shfl_xor(pB1, 32, 64);
      pB2 += __shfl_xor(pB2, 16, 64); pB2 += __shfl_xor(pB2, 32, 64);
      pB3 += __shfl_xor(pB3, 16, 64); pB3 += __shfl_xor(pB3, 32, 64);
      float wA0 = aA ? __expf(fminf(fin(pA0), 25.f)) : 0.f;
      float wA1 = aA ? __expf(fminf(fin(pA1), 25.f)) : 0.f;
      float wA2 = aA ? __expf(fminf(fin(pA2), 25.f)) : 0.f;
      float wA3 = aA ? __expf(fminf(fin(pA3), 25.f)) : 0.f;
      float wB0 = aB ? __expf(fminf(fin(pB0), 25.f)) : 0.f;
      float wB1 = aB ? __expf(fminf(fin(pB1), 25.f)) : 0.f;
      float wB2 = aB ? __expf(fminf(fin(pB2), 25.f)) : 0.f;
      float wB3 = aB ? __expf(fminf(fin(pB3), 25.f)) : 0.f;
      den0 += wA0 + wB0; den1 += wA1 + wB1;
      den2 += wA2 + wB2; den3 += wA3 + wB3;
#pragma unroll
      for (int t = 0; t < 8; t++) {
        float whA = (t < 2) ? wA0 : (t < 4) ? wA1 : (t < 6) ? wA2 : wA3;
        float whB = (t < 2) ? wB0 : (t < 4) ? wB1 : (t < 6) ? wB2 : wB3;
        acc[t * 4 + 0] = fmaf(whA, lo16(xvA[t].x), fmaf(whB, lo16(xvB[t].x), acc[t * 4 + 0]));
        acc[t * 4 + 1] = fmaf(whA, hi16(xvA[t].x), fmaf(whB, hi16(xvB[t].x), acc[t * 4 + 1]));
        acc[t * 4 + 2] = fmaf(whA, lo16(xvA[t].y), fmaf(whB, lo16(xvB[t].y), acc[t * 4 + 2]));
        acc[t * 4 + 3] = fmaf(whA, hi16(xvA[t].y), fmaf(whB, hi16(xvB[t].y), acc[t * 4 + 3]));
      }
    }
    // edge-dim reduce over idx16 lanes
#pragma unroll
    for (int k = 0; k < 32; k++) {
      acc[k] += __shfl_xor(acc[k], 1, 64); acc[k] += __shfl_xor(acc[k], 2, 64);
      acc[k] += __shfl_xor(acc[k], 4, 64); acc[k] += __shfl_xor(acc[k], 8, 64);
    }
    den0 += __shfl_xor(den0, 1, 64); den0 += __shfl_xor(den0, 2, 64);
    den0 += __shfl_xor(den0, 4, 64); den0 += __shfl_xor(den0, 8, 64);
    den1 += __shfl_xor(den1, 1, 64); den1 += __shfl_xor(den1, 2, 64);
    den1 += __shfl_xor(den1, 4, 64); den1 += __shfl_xor(den1, 8, 64);
    den2 += __shfl_xor(den2, 1, 64); den2 += __shfl_xor(den2, 2, 64);
    den2 += __shfl_xor(den2, 4, 64); den2 += __shfl_xor(den2, 8, 64);
    den3 += __shfl_xor(den3, 1, 64); den3 += __shfl_xor(den3, 2, 64);
    den3 += __shfl_xor(den3, 4, 64); den3 += __shfl_xor(den3, 8, 64);
    if (idx16 == 0) {
      float inv0 = 1.f / (den0 + 1e-16f);
      float inv1 = 1.f / (den1 + 1e-16f);
      float inv2 = 1.f / (den2 + 1e-16f);
      float inv3 = 1.f / (den3 + 1e-16f);
      int fB = flags[8];
#pragma unroll
      for (int t = 0; t < 8; t++) {
        float invh = (t < 2) ? inv0 : (t < 4) ? inv1 : (t < 6) ? inv2 : inv3;
        int ch = t * 16 + quad * 4;
        float4 o;
        o.x = fin(fmaf(acc[t * 4 + 0], invh, loadF(bias, fB, ch + 0)));
        o.y = fin(fmaf(acc[t * 4 + 1], invh, loadF(bias, fB, ch + 1)));
        o.z = fin(fmaf(acc[t * 4 + 2], invh, loadF(bias, fB, ch + 2)));
        o.w = fin(fmaf(acc[t * 4 + 3], invh, loadF(bias, fB, ch + 3)));
        o.x = o.x > 0.f ? o.x : __expf(o.x) - 1.f;
        o.y = o.y > 0.f ? o.y : __expf(o.y) - 1.f;
        o.z = o.z > 0.f ? o.z : __expf(o.z) - 1.f;
        o.w = o.w > 0.f ? o.w : __expf(o.w) - 1.f;
        *(float4*)(hout + (size_t)i * 128 + ch) = o;
      }
    }
  }
}

// ---------- layer-2 fused score+aggregate (H=1, C=64), 2-tile ----------
__global__ __launch_bounds__(256) void k_fuse2(
    const unsigned short* __restrict__ eap, const int* __restrict__ srcs,
    const int* __restrict__ row_ptr,
    const unsigned int* __restrict__ xlp, const unsigned int* __restrict__ xrp,
    const void* __restrict__ We, const void* __restrict__ att,
    const void* __restrict__ bias, const int* __restrict__ flags,
    void* __restrict__ out)
{
  __shared__ unsigned short wt[64 * 34];
  __shared__ float at[64];
  int tid = threadIdx.x;
  {
    int f = flags[13];
    for (int i2 = tid; i2 < 2048; i2 += 256) {   // We[k][c] -> wt[c*34+k]
      int k = i2 >> 6, c = i2 & 63;
      wt[c * 34 + k] = f ? f2bf(((const float*)We)[i2]) : ((const unsigned short*)We)[i2];
    }
  }
  if (tid < 64) at[tid] = loadF(att, flags[14], tid);
  __syncthreads();
  int lane = tid & 63;
  int idx16 = lane & 15, quad = lane >> 4;
  bf16x8 af[4];
#pragma unroll
  for (int t = 0; t < 4; t++)
    af[t] = *(const bf16x8*)(wt + (t * 16 + idx16) * 34 + quad * 8);
  int wv = tid >> 6;
#pragma unroll 1
  for (int rep = 0; rep < 2; rep++) {
    int i = blockIdx.x * 8 + rep * 4 + wv;
    int p0 = row_ptr[i], p1 = row_ptr[i + 1];
    uint2 rv[4];
#pragma unroll
    for (int k = 0; k < 2; k++) {
      uint4 u = *(const uint4*)(xrp + (size_t)i * 32 + quad * 8 + k * 4);
      rv[2 * k]     = make_uint2(u.x, u.y);
      rv[2 * k + 1] = make_uint2(u.z, u.w);
    }
    float acc[16];
#pragma unroll
    for (int k = 0; k < 16; k++) acc[k] = 0.f;
    float den = 0.f;
    for (int jb = p0; jb < p1; jb += 32) {
      int jA = jb + idx16, jB = jA + 16;
      int aA = jA < p1, aB = jB < p1;
      int jcA = aA ? jA : p0, jcB = aB ? jB : p0;
      int sA = srcs[jcA], sB = srcs[jcB];
      bf16x8 bfA = *(const bf16x8*)(eap + (size_t)jcA * 32 + quad * 8);
      bf16x8 bfB = *(const bf16x8*)(eap + (size_t)jcB * 32 + quad * 8);
      uint2 xvA[4], xvB[4];
#pragma unroll
      for (int k = 0; k < 2; k++) {
        uint4 u = *(const uint4*)(xlp + (size_t)sA * 32 + quad * 8 + k * 4);
        xvA[2 * k]     = make_uint2(u.x, u.y);
        xvA[2 * k + 1] = make_uint2(u.z, u.w);
      }
#pragma unroll
      for (int k = 0; k < 2; k++) {
        uint4 u = *(const uint4*)(xlp + (size_t)sB * 32 + quad * 8 + k * 4);
        xvB[2 * k]     = make_uint2(u.x, u.y);
        xvB[2 * k + 1] = make_uint2(u.z, u.w);
      }
      float phA = 0.f, phB = 0.f;
#pragma unroll
      for (int t = 0; t < 4; t++) {
        float4 av = *(const float4*)(at + t * 16 + quad * 4);
        uint2 r = rv[t];
        f32x4 cA = {0.f, 0.f, 0.f, 0.f};
        cA = __builtin_amdgcn_mfma_f32_16x16x32_bf16(af[t], bfA, cA, 0, 0, 0);
        float zA0 = cA[0] + lo16(xvA[t].x) + lo16(r.x);
        float zA1 = cA[1] + hi16(xvA[t].x) + hi16(r.x);
        float zA2 = cA[2] + lo16(xvA[t].y) + lo16(r.y);
        float zA3 = cA[3] + hi16(xvA[t].y) + hi16(r.y);
        zA0 = zA0 > 0.f ? zA0 : 0.2f * zA0;
        zA1 = zA1 > 0.f ? zA1 : 0.2f * zA1;
        zA2 = zA2 > 0.f ? zA2 : 0.2f * zA2;
        zA3 = zA3 > 0.f ? zA3 : 0.2f * zA3;
        phA += fmaf(av.x, zA0, fmaf(av.y, zA1, fmaf(av.z, zA2, av.w * zA3)));
        f32x4 cB = {0.f, 0.f, 0.f, 0.f};
        cB = __builtin_amdgcn_mfma_f32_16x16x32_bf16(af[t], bfB, cB, 0, 0, 0);
        float zB0 = cB[0] + lo16(xvB[t].x) + lo16(r.x);
        float zB1 = cB[1] + hi16(xvB[t].x) + hi16(r.x);
        float zB2 = cB[2] + lo16(xvB[t].y) + lo16(r.y);
        float zB3 = cB[3] + hi16(xvB[t].y) + hi16(r.y);
        zB0 = zB0 > 0.f ? zB0 : 0.2f * zB0;
        zB1 = zB1 > 0.f ? zB1 : 0.2f * zB1;
        zB2 = zB2 > 0.f ? zB2 : 0.2f * zB2;
        zB3 = zB3 > 0.f ? zB3 : 0.2f * zB3;
        phB += fmaf(av.x, zB0, fmaf(av.y, zB1, fmaf(av.z, zB2, av.w * zB3)));
      }
      phA += __shfl_xor(phA, 16, 64); phA += __shfl_xor(phA, 32, 64);
      phB += __shfl_xor(phB, 16, 64); phB += __shfl_xor(phB, 32, 64);
      float wA = aA ? __expf(fminf(fin(phA), 25.f)) : 0.f;
      float wB = aB ? __expf(fminf(fin(phB), 25.f)) : 0.f;
      den += wA + wB;
#pragma unroll
      for (int t = 0; t < 4; t++) {
        acc[t * 4 + 0] = fmaf(wA, lo16(xvA[t].x), fmaf(wB, lo16(xvB[t].x), acc[t * 4 + 0]));
        acc[t * 4 + 1] = fmaf(wA, hi16(xvA[t].x), fmaf(wB, hi16(xvB[t].x), acc[t * 4 + 1]));
        acc[t * 4 + 2] = fmaf(wA, lo16(xvA[t].y), fmaf(wB, lo16(xvB[t].y), acc[t * 4 + 2]));
        acc[t * 4 + 3] = fmaf(wA, hi16(xvA[t].y), fmaf(wB, hi16(xvB[t].y), acc[t * 4 + 3]));
      }
    }
#pragma unroll
    for (int k = 0; k < 16; k++) {
      acc[k] += __shfl_xor(acc[k], 1, 64); acc[k] += __shfl_xor(acc[k], 2, 64);
      acc[k] += __shfl_xor(acc[k], 4, 64); acc[k] += __shfl_xor(acc[k], 8, 64);
    }
    den += __shfl_xor(den, 1, 64); den += __shfl_xor(den, 2, 64);
    den += __shfl_xor(den, 4, 64); den += __shfl_xor(den, 8, 64);
    if (idx16 == 0) {
      float inv = 1.f / (den + 1e-16f);
      int fB = flags[15];
#pragma unroll
      for (int t = 0; t < 4; t++) {
        int ch = t * 16 + quad * 4;
        float o0 = fin(fmaf(acc[t * 4 + 0], inv, loadF(bias, fB, ch + 0)));
        float o1 = fin(fmaf(acc[t * 4 + 1], inv, loadF(bias, fB, ch + 1)));
        float o2 = fin(fmaf(acc[t * 4 + 2], inv, loadF(bias, fB, ch + 2)));
        float o3 = fin(fmaf(acc[t * 4 + 3], inv, loadF(bias, fB, ch + 3)));
        if (flags[0]) {
          *(float4*)((float*)out + (size_t)i * 64 + ch) = make_float4(o0, o1, o2, o3);
        } else {
          uint2 u;
          u.x = (unsigned)f2bf(o0) | ((unsigned)f2bf(o1) << 16);
          u.y = (unsigned)f2bf(o2) | ((unsigned)f2bf(o3) << 16);
          *(uint2*)((unsigned short*)out + (size_t)i * 64 + ch) = u;
        }
      }
    }
  }
}

extern "C" void kernel_launch(void* const* d_in, const int* in_sizes, int n_in,
                              void* d_out, int out_size, void* d_ws, size_t ws_size,
                              hipStream_t stream)
{
  (void)n_in; (void)out_size; (void)ws_size;
  const void* x    = d_in[0];
  const int*  ei   = (const int*)d_in[1];
  const void* ea   = d_in[2];
  const void* Wl1  = d_in[3];
  const void* bl1  = d_in[4];
  const void* Wr1  = d_in[5];
  const void* br1  = d_in[6];
  const void* We1  = d_in[7];
  const void* att1 = d_in[8];
  const void* bias1= d_in[9];
  const void* Wl2  = d_in[10];
  const void* bl2  = d_in[11];
  const void* Wr2  = d_in[12];
  const void* br2  = d_in[13];
  const void* We2  = d_in[14];
  const void* att2 = d_in[15];
  const void* bias2= d_in[16];

  char* ws = (char*)d_ws;
  size_t off = 0;
  auto take = [&](size_t bytes) -> char* {
    char* p = ws + off;
    off += (bytes + 255) & ~(size_t)255;
    return p;
  };
  unsigned int* xl1p = (unsigned int*)take((size_t)N_NODES * 64 * 4);   // 12.8 MB
  unsigned int* xr1p = (unsigned int*)take((size_t)N_NODES * 64 * 4);   // 12.8 MB
  float* hbuf   = (float*)take((size_t)N_NODES * 128 * 4);              // 25.6 MB
  unsigned short* eap = (unsigned short*)take((size_t)(N_EDGES + 16) * 32 * 2); // 51.2 MB
  int*   counts = (int*)  take((size_t)N_NODES * 4);
  int*   row_ptr= (int*)  take((size_t)(N_NODES + 1) * 4);
  int*   cursor = (int*)  take((size_t)N_NODES * 4);
  int*   srcs   = (int*)  take((size_t)N_EDGES * 4);
  int*   bsum   = (int*)  take(64 * 4);
  int*   flags  = (int*)  take(64 * 4);
  unsigned int* xl2p = xl1p;      // layer-2 reuses ([N,32] <= [N,64])
  unsigned int* xr2p = xr1p;

  Ptrs tl;
  const int map[16] = {0, 2, 3, 4, 5, 6, 7, 8, 9, 10, 11, 12, 13, 14, 15, 16};
  for (int j = 0; j < 16; j++) { tl.p[j] = d_in[map[j]]; tl.n[j] = in_sizes[map[j]]; }

  int nb = (N_NODES + 1023) / 1024;
  k_detect<<<16, 256, 0, stream>>>(tl, flags);
  k_zero<<<(N_NODES + 255) / 256, 256, 0, stream>>>(counts, N_NODES);
  k_gemm1<<<dim3((N_NODES + 31) / 32, 2), 256, 0, stream>>>(x, Wl1, bl1, Wr1, br1, flags, xl1p, xr1p);
  k_hist<<<(N_EDGES + 255) / 256, 256, 0, stream>>>(ei, counts);
  k_scan1<<<nb, 256, 0, stream>>>(counts, row_ptr, bsum);
  k_scan2<<<1, 64, 0, stream>>>(bsum, nb);
  k_scan3<<<nb, 256, 0, stream>>>(row_ptr, cursor, bsum);
  k_scatter<<<(N_EDGES + 255) / 256, 256, 0, stream>>>(ei, cursor, srcs, ea, flags, eap);
  k_fuse1<<<N_NODES / 8, 256, 0, stream>>>(eap, srcs, row_ptr, xl1p, xr1p, We1, att1, bias1, flags, hbuf);
  k_gemm2<<<dim3((N_NODES + 31) / 32, 2), 256, 0, stream>>>(hbuf, Wl2, bl2, Wr2, br2, flags, xl2p, xr2p);
  k_fuse2<<<N_NODES / 8, 256, 0, stream>>>(eap, srcs, row_ptr, xl2p, xr2p, We2, att2, bias2, flags, d_out);
}

// Round 6
// 705.190 us; speedup vs baseline: 1.4804x; 1.2298x over previous
//
#include <hip/hip_runtime.h>
#include <stdint.h>

#define N_NODES 50000
#define N_EDGES 800000

// flag indices: 0:x 1:ea 2:Wl1 3:bl1 4:Wr1 5:br1 6:We1 7:att1 8:bias1
//               9:Wl2 10:bl2 11:Wr2 12:br2 13:We2 14:att2 15:bias2
struct Ptrs { const void* p[16]; int n[16]; };

typedef __attribute__((ext_vector_type(8))) short bf16x8;
typedef __attribute__((ext_vector_type(4))) float f32x4;

__device__ __forceinline__ float bf2f(unsigned short u){
  union { unsigned int i; float f; } v; v.i = ((unsigned int)u) << 16; return v.f;
}
__device__ __forceinline__ float lo16(unsigned int u){ union { unsigned int i; float f; } v; v.i = u << 16; return v.f; }
__device__ __forceinline__ float hi16(unsigned int u){ union { unsigned int i; float f; } v; v.i = u & 0xffff0000u; return v.f; }
__device__ __forceinline__ unsigned short f2bf(float f){
  if (!(f == f)) return 0;
  unsigned int x = __float_as_uint(f);
  unsigned int r = (x + 0x7fffu + ((x >> 16) & 1u)) >> 16;
  return (unsigned short)r;
}
__device__ __forceinline__ float fin(float v){
  if (!(v == v)) return 0.f;
  return fminf(fmaxf(v, -1e30f), 1e30f);
}
__device__ __forceinline__ float loadF(const void* p, int f32, size_t idx){
  return f32 ? ((const float*)p)[idx] : bf2f(((const unsigned short*)p)[idx]);
}

// stage n bf16 elems of W (bf16 or f32 source) into LDS; n multiple of 2048
__device__ __forceinline__ void stageW(unsigned short* dst, const void* src, int n, int f32, int tid){
  if (f32) {
    for (int i = tid * 8; i < n; i += 2048) {
      float4 a = *(const float4*)((const float*)src + i);
      float4 b = *(const float4*)((const float*)src + i + 4);
      uint4 u;
      u.x = (unsigned)f2bf(a.x) | ((unsigned)f2bf(a.y) << 16);
      u.y = (unsigned)f2bf(a.z) | ((unsigned)f2bf(a.w) << 16);
      u.z = (unsigned)f2bf(b.x) | ((unsigned)f2bf(b.y) << 16);
      u.w = (unsigned)f2bf(b.z) | ((unsigned)f2bf(b.w) << 16);
      *(uint4*)(dst + i) = u;
    }
  } else {
    for (int i = tid * 8; i < n; i += 2048)
      *(uint4*)(dst + i) = *(const uint4*)((const unsigned short*)src + i);
  }
}

// ---------- dtype detect ----------
__global__ __launch_bounds__(256) void k_detect(Ptrs tl, int* __restrict__ flags)
{
  __shared__ int red[256];
  int b = blockIdx.x, t = threadIdx.x;
  const unsigned short* p = (const unsigned short*)tl.p[b];
  int n = tl.n[b]; if (n > 16384) n = 16384;
  int crazy = 0;
  for (int i = t; i < n; i += 256) {
    unsigned short u = p[i];
    if (u) {
      int ex = (u >> 7) & 0xFF;
      if (ex == 0xFF || ex < 0x60) crazy++;
    }
  }
  red[t] = crazy; __syncthreads();
  for (int off = 128; off; off >>= 1) { if (t < off) red[t] += red[t + off]; __syncthreads(); }
  if (t == 0) flags[b] = (red[0] * 10 > n) ? 1 : 0;
}

__global__ __launch_bounds__(256) void k_zero(int* __restrict__ p, int n)
{
  int i = blockIdx.x * 256 + threadIdx.x;
  if (i < n) p[i] = 0;
}

// ---------- layer-1 GEMM: xl1p / xr1p, packed bf16 [N,64] uints in FRAGMENT order ----------
// fragment order: natural uint u = t*8 + quad*2 + b  ->  u' = quad*16 + t*2 + b
// so lane 'quad' of the fuse kernels reads its 32 channels as 64 contiguous bytes.
__global__ __launch_bounds__(256) void k_gemm1(
    const void* __restrict__ x,
    const void* __restrict__ Wl, const void* __restrict__ bl,
    const void* __restrict__ Wr, const void* __restrict__ br,
    const int* __restrict__ flags,
    unsigned int* __restrict__ xlp, unsigned int* __restrict__ xrp)
{
  __shared__ float xs[32 * 132];
  __shared__ unsigned short ws[128 * 128];
  const void* W  = blockIdx.y ? Wr : Wl;
  const void* bb = blockIdx.y ? br : bl;
  int fW = blockIdx.y ? flags[4] : flags[2];
  int fB = blockIdx.y ? flags[5] : flags[3];
  int fX = flags[0];
  unsigned int* outp = blockIdx.y ? xrp : xlp;
  int tid = threadIdx.x;
  int row0 = blockIdx.x * 32;
  stageW(ws, W, 128 * 128, fW, tid);
  for (int i = tid * 4; i < 32 * 128; i += 1024) {
    int r = i >> 7, k = i & 127;
    int row = row0 + r;
    float4 v = make_float4(0.f, 0.f, 0.f, 0.f);
    if (row < N_NODES) {
      if (fX) v = *(const float4*)((const float*)x + (size_t)row * 128 + k);
      else {
        uint2 u = *(const uint2*)((const unsigned short*)x + (size_t)row * 128 + k);
        v.x = lo16(u.x); v.y = hi16(u.x); v.z = lo16(u.y); v.w = hi16(u.y);
      }
    }
    *(float4*)(xs + r * 132 + k) = v;
  }
  __syncthreads();
  int r = tid >> 3, cg = tid & 7;
  float acc[16];
#pragma unroll
  for (int j = 0; j < 16; j++) acc[j] = 0.f;
#pragma unroll 4
  for (int k = 0; k < 128; k++) {
    float xv = xs[r * 132 + k];
    uint4 p0 = *(const uint4*)(ws + k * 128 + cg * 8);
    uint4 p1 = *(const uint4*)(ws + k * 128 + 64 + cg * 8);
    acc[0]  = fmaf(xv, lo16(p0.x), acc[0]);  acc[1]  = fmaf(xv, hi16(p0.x), acc[1]);
    acc[2]  = fmaf(xv, lo16(p0.y), acc[2]);  acc[3]  = fmaf(xv, hi16(p0.y), acc[3]);
    acc[4]  = fmaf(xv, lo16(p0.z), acc[4]);  acc[5]  = fmaf(xv, hi16(p0.z), acc[5]);
    acc[6]  = fmaf(xv, lo16(p0.w), acc[6]);  acc[7]  = fmaf(xv, hi16(p0.w), acc[7]);
    acc[8]  = fmaf(xv, lo16(p1.x), acc[8]);  acc[9]  = fmaf(xv, hi16(p1.x), acc[9]);
    acc[10] = fmaf(xv, lo16(p1.y), acc[10]); acc[11] = fmaf(xv, hi16(p1.y), acc[11]);
    acc[12] = fmaf(xv, lo16(p1.z), acc[12]); acc[13] = fmaf(xv, hi16(p1.z), acc[13]);
    acc[14] = fmaf(xv, lo16(p1.w), acc[14]); acc[15] = fmaf(xv, hi16(p1.w), acc[15]);
  }
  int row = row0 + r;
  if (row < N_NODES) {
    unsigned int* op = outp + (size_t)row * 64;
    int tt = cg >> 1, qb = (cg & 1) * 2;
    unsigned int ou[4];
#pragma unroll
    for (int t = 0; t < 4; t++) {
      float f0 = fin(acc[2 * t]     + loadF(bb, fB, cg * 8 + 2 * t));
      float f1 = fin(acc[2 * t + 1] + loadF(bb, fB, cg * 8 + 2 * t + 1));
      ou[t] = (unsigned)f2bf(f0) | ((unsigned)f2bf(f1) << 16);
    }
    *(uint2*)(op + qb * 16 + tt * 2)       = make_uint2(ou[0], ou[1]);
    *(uint2*)(op + (qb + 1) * 16 + tt * 2) = make_uint2(ou[2], ou[3]);
#pragma unroll
    for (int t = 0; t < 4; t++) {
      float f0 = fin(acc[8 + 2 * t]     + loadF(bb, fB, 64 + cg * 8 + 2 * t));
      float f1 = fin(acc[8 + 2 * t + 1] + loadF(bb, fB, 64 + cg * 8 + 2 * t + 1));
      ou[t] = (unsigned)f2bf(f0) | ((unsigned)f2bf(f1) << 16);
    }
    *(uint2*)(op + qb * 16 + 8 + tt * 2)       = make_uint2(ou[0], ou[1]);
    *(uint2*)(op + (qb + 1) * 16 + 8 + tt * 2) = make_uint2(ou[2], ou[3]);
  }
}

// ---------- layer-2 GEMM: xl2p / xr2p, packed bf16 [N,32] uints in FRAGMENT order ----------
// natural uint u = t*8 + quad*2 + b (t=0..3) -> u' = quad*8 + t*2 + b
__global__ __launch_bounds__(256) void k_gemm2(
    const float* __restrict__ h,
    const void* __restrict__ Wl, const void* __restrict__ bl,
    const void* __restrict__ Wr, const void* __restrict__ br,
    const int* __restrict__ flags,
    unsigned int* __restrict__ xlp, unsigned int* __restrict__ xrp)
{
  __shared__ float hs[32 * 132];
  __shared__ unsigned short ws[128 * 64];
  const void* W  = blockIdx.y ? Wr : Wl;
  const void* bb = blockIdx.y ? br : bl;
  int fW = blockIdx.y ? flags[11] : flags[9];
  int fB = blockIdx.y ? flags[12] : flags[10];
  unsigned int* outp = blockIdx.y ? xrp : xlp;
  int tid = threadIdx.x;
  int row0 = blockIdx.x * 32;
  stageW(ws, W, 128 * 64, fW, tid);
  for (int i = tid * 4; i < 32 * 128; i += 1024) {
    int r = i >> 7, k = i & 127;
    int row = row0 + r;
    float4 v = make_float4(0.f, 0.f, 0.f, 0.f);
    if (row < N_NODES) v = *(const float4*)(h + (size_t)row * 128 + k);
    *(float4*)(hs + r * 132 + k) = v;
  }
  __syncthreads();
  int r = tid >> 3, cg = tid & 7;
  float acc[8];
#pragma unroll
  for (int j = 0; j < 8; j++) acc[j] = 0.f;
#pragma unroll 4
  for (int k = 0; k < 128; k++) {
    float hv = hs[r * 132 + k];
    uint4 p = *(const uint4*)(ws + k * 64 + cg * 8);
    acc[0] = fmaf(hv, lo16(p.x), acc[0]); acc[1] = fmaf(hv, hi16(p.x), acc[1]);
    acc[2] = fmaf(hv, lo16(p.y), acc[2]); acc[3] = fmaf(hv, hi16(p.y), acc[3]);
    acc[4] = fmaf(hv, lo16(p.z), acc[4]); acc[5] = fmaf(hv, hi16(p.z), acc[5]);
    acc[6] = fmaf(hv, lo16(p.w), acc[6]); acc[7] = fmaf(hv, hi16(p.w), acc[7]);
  }
  int row = row0 + r;
  if (row < N_NODES) {
    unsigned int* op = outp + (size_t)row * 32;
    int tt = cg >> 1, qb = (cg & 1) * 2;
    unsigned int ou[4];
#pragma unroll
    for (int t = 0; t < 4; t++) {
      float f0 = fin(acc[2 * t]     + loadF(bb, fB, cg * 8 + 2 * t));
      float f1 = fin(acc[2 * t + 1] + loadF(bb, fB, cg * 8 + 2 * t + 1));
      ou[t] = (unsigned)f2bf(f0) | ((unsigned)f2bf(f1) << 16);
    }
    *(uint2*)(op + qb * 8 + tt * 2)       = make_uint2(ou[0], ou[1]);
    *(uint2*)(op + (qb + 1) * 8 + tt * 2) = make_uint2(ou[2], ou[3]);
  }
}

// ---------- CSR build ----------
__global__ __launch_bounds__(256) void k_hist(const int* __restrict__ ei, int* __restrict__ counts)
{
  int e = blockIdx.x * 256 + threadIdx.x;
  if (e < N_EDGES) {
    int d = ei[N_EDGES + e]; if ((unsigned)d >= N_NODES) d = 0;
    atomicAdd(&counts[d], 1);
  }
}

__global__ __launch_bounds__(256) void k_scan1(const int* __restrict__ counts,
                                               int* __restrict__ row_ptr, int* __restrict__ bsum)
{
  __shared__ int lds[256];
  int t = threadIdx.x;
  int base = blockIdx.x * 1024 + t * 4;
  int c0 = (base + 0) < N_NODES ? counts[base + 0] : 0;
  int c1 = (base + 1) < N_NODES ? counts[base + 1] : 0;
  int c2 = (base + 2) < N_NODES ? counts[base + 2] : 0;
  int c3 = (base + 3) < N_NODES ? counts[base + 3] : 0;
  int s = c0 + c1 + c2 + c3;
  lds[t] = s; __syncthreads();
  for (int off = 1; off < 256; off <<= 1) {
    int v = (t >= off) ? lds[t - off] : 0;
    __syncthreads();
    lds[t] += v;
    __syncthreads();
  }
  int incl = lds[t];
  int excl = incl - s;
  if (base + 0 < N_NODES) row_ptr[base + 0] = excl;
  if (base + 1 < N_NODES) row_ptr[base + 1] = excl + c0;
  if (base + 2 < N_NODES) row_ptr[base + 2] = excl + c0 + c1;
  if (base + 3 < N_NODES) row_ptr[base + 3] = excl + c0 + c1 + c2;
  if (t == 255) bsum[blockIdx.x] = incl;
}

__global__ __launch_bounds__(64) void k_scan2(int* __restrict__ bsum, int nb)
{
  __shared__ int l[64];
  int t = threadIdx.x;
  if (t < nb) l[t] = bsum[t];
  __syncthreads();
  if (t == 0) { int run = 0; for (int i = 0; i < nb; i++) { int v = l[i]; l[i] = run; run += v; } }
  __syncthreads();
  if (t < nb) bsum[t] = l[t];
}

__global__ __launch_bounds__(256) void k_scan3(int* __restrict__ row_ptr, int* __restrict__ cursor,
                                               const int* __restrict__ bsum)
{
  int t = threadIdx.x;
  int base = blockIdx.x * 1024 + t * 4;
  int add = bsum[blockIdx.x];
#pragma unroll
  for (int j = 0; j < 4; j++) {
    int i = base + j;
    if (i < N_NODES) { int v = row_ptr[i] + add; row_ptr[i] = v; cursor[i] = v; }
  }
  if (blockIdx.x == 0 && t == 0) row_ptr[N_NODES] = N_EDGES;
}

// ---------- scatter: CSR perm + pack edge_attr to bf16 CSR order ----------
__global__ __launch_bounds__(256) void k_scatter(const int* __restrict__ ei,
                                                 int* __restrict__ cursor,
                                                 int* __restrict__ srcs,
                                                 const void* __restrict__ ea,
                                                 const int* __restrict__ flags,
                                                 unsigned short* __restrict__ eap)
{
  int e = blockIdx.x * 256 + threadIdx.x;
  if (e >= N_EDGES) return;
  int d = ei[N_EDGES + e]; if ((unsigned)d >= N_NODES) d = 0;
  int s = ei[e];           if ((unsigned)s >= N_NODES) s = 0;
  int p = atomicAdd(&cursor[d], 1);
  if ((unsigned)p >= N_EDGES) return;
  srcs[p] = s;
  unsigned short* op = eap + (size_t)p * 32;
  if (flags[1]) {
    const float* ip = (const float*)ea + (size_t)e * 32;
#pragma unroll
    for (int q = 0; q < 2; q++) {
      float4 a = *(const float4*)(ip + q * 16);
      float4 b = *(const float4*)(ip + q * 16 + 4);
      float4 c = *(const float4*)(ip + q * 16 + 8);
      float4 dd = *(const float4*)(ip + q * 16 + 12);
      uint4 u0, u1;
      u0.x = (unsigned)f2bf(a.x) | ((unsigned)f2bf(a.y) << 16);
      u0.y = (unsigned)f2bf(a.z) | ((unsigned)f2bf(a.w) << 16);
      u0.z = (unsigned)f2bf(b.x) | ((unsigned)f2bf(b.y) << 16);
      u0.w = (unsigned)f2bf(b.z) | ((unsigned)f2bf(b.w) << 16);
      u1.x = (unsigned)f2bf(c.x) | ((unsigned)f2bf(c.y) << 16);
      u1.y = (unsigned)f2bf(c.z) | ((unsigned)f2bf(c.w) << 16);
      u1.z = (unsigned)f2bf(dd.x) | ((unsigned)f2bf(dd.y) << 16);
      u1.w = (unsigned)f2bf(dd.z) | ((unsigned)f2bf(dd.w) << 16);
      *(uint4*)(op + q * 16) = u0;
      *(uint4*)(op + q * 16 + 8) = u1;
    }
  } else {
    const uint4* ip = (const uint4*)((const unsigned short*)ea + (size_t)e * 32);
#pragma unroll
    for (int q = 0; q < 4; q++) *(uint4*)(op + q * 8) = ip[q];
  }
}

// ---------- layer-1 fused score+aggregate, channel-owner epilogue ----------
// wave per node, 16-edge chunks. Score: fragment gathers + MFMA (as before).
// Agg: lane owns 2 output channels (fragment uint 'lane' of a row); per edge,
// broadcast (s_j, w_{j,hd}) with 2 shfls, coalesced L1-hot row read, 2 FMAs.
// No edge-dim butterfly; den accumulates per-lane; all lanes write output.
__global__ __launch_bounds__(256) void k_fuse1(
    const unsigned short* __restrict__ eap, const int* __restrict__ srcs,
    const int* __restrict__ row_ptr,
    const unsigned int* __restrict__ xlp, const unsigned int* __restrict__ xrp,
    const void* __restrict__ We, const void* __restrict__ att,
    const void* __restrict__ bias, const int* __restrict__ flags,
    float* __restrict__ hout)
{
  __shared__ unsigned short wt[128 * 34];   // WeT[ch][k], stride 34
  __shared__ float at[128];
  int tid = threadIdx.x;
  {
    int f = flags[6];
    for (int i2 = tid; i2 < 4096; i2 += 256) {   // We[k][c] -> wt[c*34+k]
      int k = i2 >> 7, c = i2 & 127;
      wt[c * 34 + k] = f ? f2bf(((const float*)We)[i2]) : ((const unsigned short*)We)[i2];
    }
  }
  if (tid < 128) at[tid] = loadF(att, flags[7], tid);
  __syncthreads();
  int lane = tid & 63;
  int idx16 = lane & 15, quad = lane >> 4;
  // agg ownership: lane reads fragment uint u'=lane -> natural uint un
  int t_s = (lane & 15) >> 1, b_s = lane & 1;
  int un = t_s * 8 + quad * 2 + b_s;     // natural uint index in [0,64)
  int hd = un >> 4;                       // head of owned channels
  bf16x8 af[8];
#pragma unroll
  for (int t = 0; t < 8; t++)
    af[t] = *(const bf16x8*)(wt + (t * 16 + idx16) * 34 + quad * 8);
  int wv = tid >> 6;
#pragma unroll 1
  for (int rep = 0; rep < 2; rep++) {
    int i = blockIdx.x * 8 + rep * 4 + wv;
    int p0 = row_ptr[i], p1 = row_ptr[i + 1];
    uint2 rv[8];
#pragma unroll
    for (int t4 = 0; t4 < 4; t4++) {
      uint4 u = *(const uint4*)(xrp + (size_t)i * 64 + quad * 16 + t4 * 4);
      rv[2 * t4]     = make_uint2(u.x, u.y);
      rv[2 * t4 + 1] = make_uint2(u.z, u.w);
    }
    float acc0 = 0.f, acc1 = 0.f, den = 0.f;
    for (int jb = p0; jb < p1; jb += 16) {
      int j = jb + idx16;
      int act = j < p1;
      int jc = act ? j : p0;
      int s = srcs[jc];
      bf16x8 bfrag = *(const bf16x8*)(eap + (size_t)jc * 32 + quad * 8);
      uint2 xv[8];
#pragma unroll
      for (int t4 = 0; t4 < 4; t4++) {
        uint4 u = *(const uint4*)(xlp + (size_t)s * 64 + quad * 16 + t4 * 4);
        xv[2 * t4]     = make_uint2(u.x, u.y);
        xv[2 * t4 + 1] = make_uint2(u.z, u.w);
      }
      float ph0 = 0.f, ph1 = 0.f, ph2 = 0.f, ph3 = 0.f;
#pragma unroll
      for (int t = 0; t < 8; t++) {
        float4 av = *(const float4*)(at + t * 16 + quad * 4);
        uint2 r = rv[t];
        f32x4 c = {0.f, 0.f, 0.f, 0.f};
        c = __builtin_amdgcn_mfma_f32_16x16x32_bf16(af[t], bfrag, c, 0, 0, 0);
        float z0 = c[0] + lo16(xv[t].x) + lo16(r.x);
        float z1 = c[1] + hi16(xv[t].x) + hi16(r.x);
        float z2 = c[2] + lo16(xv[t].y) + lo16(r.y);
        float z3 = c[3] + hi16(xv[t].y) + hi16(r.y);
        z0 = z0 > 0.f ? z0 : 0.2f * z0;
        z1 = z1 > 0.f ? z1 : 0.2f * z1;
        z2 = z2 > 0.f ? z2 : 0.2f * z2;
        z3 = z3 > 0.f ? z3 : 0.2f * z3;
        float pp = fmaf(av.x, z0, fmaf(av.y, z1, fmaf(av.z, z2, av.w * z3)));
        if (t < 2)      ph0 += pp;
        else if (t < 4) ph1 += pp;
        else if (t < 6) ph2 += pp;
        else            ph3 += pp;
      }
      ph0 += __shfl_xor(ph0, 16, 64); ph0 += __shfl_xor(ph0, 32, 64);
      ph1 += __shfl_xor(ph1, 16, 64); ph1 += __shfl_xor(ph1, 32, 64);
      ph2 += __shfl_xor(ph2, 16, 64); ph2 += __shfl_xor(ph2, 32, 64);
      ph3 += __shfl_xor(ph3, 16, 64); ph3 += __shfl_xor(ph3, 32, 64);
      float w0 = act ? __expf(fminf(fin(ph0), 25.f)) : 0.f;
      float w1 = act ? __expf(fminf(fin(ph1), 25.f)) : 0.f;
      float w2 = act ? __expf(fminf(fin(ph2), 25.f)) : 0.f;
      float w3 = act ? __expf(fminf(fin(ph3), 25.f)) : 0.f;
      float wsel = quad == 0 ? w0 : quad == 1 ? w1 : quad == 2 ? w2 : w3;
      int sjl[16];
      float wjv[16];
#pragma unroll
      for (int q = 0; q < 16; q++) sjl[q] = __shfl(s, q, 64);
#pragma unroll
      for (int q = 0; q < 16; q++) wjv[q] = __shfl(wsel, hd * 16 + q, 64);
#pragma unroll
      for (int q = 0; q < 16; q++) {
        unsigned int v = xlp[(size_t)sjl[q] * 64 + lane];   // L1-hot coalesced row
        acc0 = fmaf(wjv[q], lo16(v), acc0);
        acc1 = fmaf(wjv[q], hi16(v), acc1);
        den += wjv[q];
      }
    }
    float inv = 1.f / (den + 1e-16f);
    int fB = flags[8];
    int ch = un * 2;
    float o0 = fin(fmaf(acc0, inv, loadF(bias, fB, ch)));
    float o1 = fin(fmaf(acc1, inv, loadF(bias, fB, ch + 1)));
    o0 = o0 > 0.f ? o0 : __expf(o0) - 1.f;
    o1 = o1 > 0.f ? o1 : __expf(o1) - 1.f;
    *(float2*)(hout + (size_t)i * 128 + ch) = make_float2(o0, o1);
  }
}

// ---------- layer-2 fused score+aggregate (H=1, C=64), channel-owner epilogue ----------
// rows are 32 uints -> half-wave edge split: half h handles edges h,h+2,...;
// one cross-half reduce at the end; lanes 0..31 write 2 channels each.
__global__ __launch_bounds__(256) void k_fuse2(
    const unsigned short* __restrict__ eap, const int* __restrict__ srcs,
    const int* __restrict__ row_ptr,
    const unsigned int* __restrict__ xlp, const unsigned int* __restrict__ xrp,
    const void* __restrict__ We, const void* __restrict__ att,
    const void* __restrict__ bias, const int* __restrict__ flags,
    void* __restrict__ out)
{
  __shared__ unsigned short wt[64 * 34];
  __shared__ float at[64];
  int tid = threadIdx.x;
  {
    int f = flags[13];
    for (int i2 = tid; i2 < 2048; i2 += 256) {   // We[k][c] -> wt[c*34+k]
      int k = i2 >> 6, c = i2 & 63;
      wt[c * 34 + k] = f ? f2bf(((const float*)We)[i2]) : ((const unsigned short*)We)[i2];
    }
  }
  if (tid < 64) at[tid] = loadF(att, flags[14], tid);
  __syncthreads();
  int lane = tid & 63;
  int idx16 = lane & 15, quad = lane >> 4;
  // agg ownership for [N,32] rows: position l5 = lane&31 -> natural uint un
  int l5 = lane & 31;
  int q_s = l5 >> 3, t2 = (l5 & 7) >> 1, b2 = l5 & 1;
  int un = t2 * 8 + q_s * 2 + b2;        // natural uint index in [0,32)
  int halfe = lane >> 5;
  bf16x8 af[4];
#pragma unroll
  for (int t = 0; t < 4; t++)
    af[t] = *(const bf16x8*)(wt + (t * 16 + idx16) * 34 + quad * 8);
  int wv = tid >> 6;
#pragma unroll 1
  for (int rep = 0; rep < 2; rep++) {
    int i = blockIdx.x * 8 + rep * 4 + wv;
    int p0 = row_ptr[i], p1 = row_ptr[i + 1];
    uint2 rv[4];
#pragma unroll
    for (int k = 0; k < 2; k++) {
      uint4 u = *(const uint4*)(xrp + (size_t)i * 32 + quad * 8 + k * 4);
      rv[2 * k]     = make_uint2(u.x, u.y);
      rv[2 * k + 1] = make_uint2(u.z, u.w);
    }
    float acc0 = 0.f, acc1 = 0.f, den = 0.f;
    for (int jb = p0; jb < p1; jb += 16) {
      int j = jb + idx16;
      int act = j < p1;
      int jc = act ? j : p0;
      int s = srcs[jc];
      bf16x8 bfrag = *(const bf16x8*)(eap + (size_t)jc * 32 + quad * 8);
      uint2 xv[4];
#pragma unroll
      for (int k = 0; k < 2; k++) {
        uint4 u = *(const uint4*)(xlp + (size_t)s * 32 + quad * 8 + k * 4);
        xv[2 * k]     = make_uint2(u.x, u.y);
        xv[2 * k + 1] = make_uint2(u.z, u.w);
      }
      float ph = 0.f;
#pragma unroll
      for (int t = 0; t < 4; t++) {
        float4 av = *(const float4*)(at + t * 16 + quad * 4);
        uint2 r = rv[t];
        f32x4 c = {0.f, 0.f, 0.f, 0.f};
        c = __builtin_amdgcn_mfma_f32_16x16x32_bf16(af[t], bfrag, c, 0, 0, 0);
        float z0 = c[0] + lo16(xv[t].x) + lo16(r.x);
        float z1 = c[1] + hi16(xv[t].x) + hi16(r.x);
        float z2 = c[2] + lo16(xv[t].y) + lo16(r.y);
        float z3 = c[3] + hi16(xv[t].y) + hi16(r.y);
        z0 = z0 > 0.f ? z0 : 0.2f * z0;
        z1 = z1 > 0.f ? z1 : 0.2f * z1;
        z2 = z2 > 0.f ? z2 : 0.2f * z2;
        z3 = z3 > 0.f ? z3 : 0.2f * z3;
        ph += fmaf(av.x, z0, fmaf(av.y, z1, fmaf(av.z, z2, av.w * z3)));
      }
      ph += __shfl_xor(ph, 16, 64);
      ph += __shfl_xor(ph, 32, 64);
      float wsel = act ? __expf(fminf(fin(ph), 25.f)) : 0.f;
      int sjl[8];
      float wjv[8];
#pragma unroll
      for (int q = 0; q < 8; q++) {
        int qq = 2 * q + halfe;
        sjl[q] = __shfl(s, qq, 64);
        wjv[q] = __shfl(wsel, qq, 64);
      }
#pragma unroll
      for (int q = 0; q < 8; q++) {
        unsigned int v = xlp[(size_t)sjl[q] * 32 + l5];   // L1-hot coalesced row
        acc0 = fmaf(wjv[q], lo16(v), acc0);
        acc1 = fmaf(wjv[q], hi16(v), acc1);
        den += wjv[q];
      }
    }
    acc0 += __shfl_xor(acc0, 32, 64);
    acc1 += __shfl_xor(acc1, 32, 64);
    den  += __shfl_xor(den, 32, 64);
    if (lane < 32) {
      float inv = 1.f / (den + 1e-16f);
      int fB = flags[15];
      int ch = un * 2;
      float o0 = fin(fmaf(acc0, inv, loadF(bias, fB, ch)));
      float o1 = fin(fmaf(acc1, inv, loadF(bias, fB, ch + 1)));
      if (flags[0]) {
        *(float2*)((float*)out + (size_t)i * 64 + ch) = make_float2(o0, o1);
      } else {
        unsigned int u = (unsigned)f2bf(o0) | ((unsigned)f2bf(o1) << 16);
        *(unsigned int*)((unsigned short*)out + (size_t)i * 64 + ch) = u;
      }
    }
  }
}

extern "C" void kernel_launch(void* const* d_in, const int* in_sizes, int n_in,
                              void* d_out, int out_size, void* d_ws, size_t ws_size,
                              hipStream_t stream)
{
  (void)n_in; (void)out_size; (void)ws_size;
  const void* x    = d_in[0];
  const int*  ei   = (const int*)d_in[1];
  const void* ea   = d_in[2];
  const void* Wl1  = d_in[3];
  const void* bl1  = d_in[4];
  const void* Wr1  = d_in[5];
  const void* br1  = d_in[6];
  const void* We1  = d_in[7];
  const void* att1 = d_in[8];
  const void* bias1= d_in[9];
  const void* Wl2  = d_in[10];
  const void* bl2  = d_in[11];
  const void* Wr2  = d_in[12];
  const void* br2  = d_in[13];
  const void* We2  = d_in[14];
  const void* att2 = d_in[15];
  const void* bias2= d_in[16];

  char* ws = (char*)d_ws;
  size_t off = 0;
  auto take = [&](size_t bytes) -> char* {
    char* p = ws + off;
    off += (bytes + 255) & ~(size_t)255;
    return p;
  };
  unsigned int* xl1p = (unsigned int*)take((size_t)N_NODES * 64 * 4);   // 12.8 MB
  unsigned int* xr1p = (unsigned int*)take((size_t)N_NODES * 64 * 4);   // 12.8 MB
  float* hbuf   = (float*)take((size_t)N_NODES * 128 * 4);              // 25.6 MB
  unsigned short* eap = (unsigned short*)take((size_t)(N_EDGES + 16) * 32 * 2); // 51.2 MB
  int*   counts = (int*)  take((size_t)N_NODES * 4);
  int*   row_ptr= (int*)  take((size_t)(N_NODES + 1) * 4);
  int*   cursor = (int*)  take((size_t)N_NODES * 4);
  int*   srcs   = (int*)  take((size_t)N_EDGES * 4);
  int*   bsum   = (int*)  take(64 * 4);
  int*   flags  = (int*)  take(64 * 4);
  unsigned int* xl2p = xl1p;      // layer-2 reuses ([N,32] <= [N,64])
  unsigned int* xr2p = xr1p;

  Ptrs tl;
  const int map[16] = {0, 2, 3, 4, 5, 6, 7, 8, 9, 10, 11, 12, 13, 14, 15, 16};
  for (int j = 0; j < 16; j++) { tl.p[j] = d_in[map[j]]; tl.n[j] = in_sizes[map[j]]; }

  int nb = (N_NODES + 1023) / 1024;
  k_detect<<<16, 256, 0, stream>>>(tl, flags);
  k_zero<<<(N_NODES + 255) / 256, 256, 0, stream>>>(counts, N_NODES);
  k_gemm1<<<dim3((N_NODES + 31) / 32, 2), 256, 0, stream>>>(x, Wl1, bl1, Wr1, br1, flags, xl1p, xr1p);
  k_hist<<<(N_EDGES + 255) / 256, 256, 0, stream>>>(ei, counts);
  k_scan1<<<nb, 256, 0, stream>>>(counts, row_ptr, bsum);
  k_scan2<<<1, 64, 0, stream>>>(bsum, nb);
  k_scan3<<<nb, 256, 0, stream>>>(row_ptr, cursor, bsum);
  k_scatter<<<(N_EDGES + 255) / 256, 256, 0, stream>>>(ei, cursor, srcs, ea, flags, eap);
  k_fuse1<<<N_NODES / 8, 256, 0, stream>>>(eap, srcs, row_ptr, xl1p, xr1p, We1, att1, bias1, flags, hbuf);
  k_gemm2<<<dim3((N_NODES + 31) / 32, 2), 256, 0, stream>>>(hbuf, Wl2, bl2, Wr2, br2, flags, xl2p, xr2p);
  k_fuse2<<<N_NODES / 8, 256, 0, stream>>>(eap, srcs, row_ptr, xl2p, xr2p, We2, att2, bias2, flags, d_out);
}

// Round 7
// 698.643 us; speedup vs baseline: 1.4943x; 1.0094x over previous
//
#include <hip/hip_runtime.h>
#include <stdint.h>

#define N_NODES 50000
#define N_EDGES 800000

// flag indices: 0:x 1:ea 2:Wl1 3:bl1 4:Wr1 5:br1 6:We1 7:att1 8:bias1
//               9:Wl2 10:bl2 11:Wr2 12:br2 13:We2 14:att2 15:bias2
struct Ptrs { const void* p[16]; int n[16]; };

typedef __attribute__((ext_vector_type(8))) short bf16x8;
typedef __attribute__((ext_vector_type(4))) float f32x4;

__device__ __forceinline__ float bf2f(unsigned short u){
  union { unsigned int i; float f; } v; v.i = ((unsigned int)u) << 16; return v.f;
}
__device__ __forceinline__ float lo16(unsigned int u){ union { unsigned int i; float f; } v; v.i = u << 16; return v.f; }
__device__ __forceinline__ float hi16(unsigned int u){ union { unsigned int i; float f; } v; v.i = u & 0xffff0000u; return v.f; }
__device__ __forceinline__ unsigned short f2bf(float f){
  if (!(f == f)) return 0;
  unsigned int x = __float_as_uint(f);
  unsigned int r = (x + 0x7fffu + ((x >> 16) & 1u)) >> 16;
  return (unsigned short)r;
}
__device__ __forceinline__ float fin(float v){
  if (!(v == v)) return 0.f;
  return fminf(fmaxf(v, -1e30f), 1e30f);
}
__device__ __forceinline__ float loadF(const void* p, int f32, size_t idx){
  return f32 ? ((const float*)p)[idx] : bf2f(((const unsigned short*)p)[idx]);
}

// stage n bf16 elems of W (bf16 or f32 source) into LDS; n multiple of 2048
__device__ __forceinline__ void stageW(unsigned short* dst, const void* src, int n, int f32, int tid){
  if (f32) {
    for (int i = tid * 8; i < n; i += 2048) {
      float4 a = *(const float4*)((const float*)src + i);
      float4 b = *(const float4*)((const float*)src + i + 4);
      uint4 u;
      u.x = (unsigned)f2bf(a.x) | ((unsigned)f2bf(a.y) << 16);
      u.y = (unsigned)f2bf(a.z) | ((unsigned)f2bf(a.w) << 16);
      u.z = (unsigned)f2bf(b.x) | ((unsigned)f2bf(b.y) << 16);
      u.w = (unsigned)f2bf(b.z) | ((unsigned)f2bf(b.w) << 16);
      *(uint4*)(dst + i) = u;
    }
  } else {
    for (int i = tid * 8; i < n; i += 2048)
      *(uint4*)(dst + i) = *(const uint4*)((const unsigned short*)src + i);
  }
}

// ---------- dtype detect ----------
__global__ __launch_bounds__(256) void k_detect(Ptrs tl, int* __restrict__ flags)
{
  __shared__ int red[256];
  int b = blockIdx.x, t = threadIdx.x;
  const unsigned short* p = (const unsigned short*)tl.p[b];
  int n = tl.n[b]; if (n > 16384) n = 16384;
  int crazy = 0;
  for (int i = t; i < n; i += 256) {
    unsigned short u = p[i];
    if (u) {
      int ex = (u >> 7) & 0xFF;
      if (ex == 0xFF || ex < 0x60) crazy++;
    }
  }
  red[t] = crazy; __syncthreads();
  for (int off = 128; off; off >>= 1) { if (t < off) red[t] += red[t + off]; __syncthreads(); }
  if (t == 0) flags[b] = (red[0] * 10 > n) ? 1 : 0;
}

__global__ __launch_bounds__(256) void k_zero(int* __restrict__ p, int n, int* __restrict__ pad16)
{
  int i = blockIdx.x * 256 + threadIdx.x;
  if (i < n) p[i] = 0;
  if (i < 16) pad16[i] = 0;
}

// ---------- layer-1 GEMM: xl1p / xr1p, packed bf16 [N,64] uints in FRAGMENT order ----------
// fragment order: natural uint u = t*8 + quad*2 + b  ->  u' = quad*16 + t*2 + b
// so lane 'quad' of the fuse kernels reads its 32 channels as 64 contiguous bytes.
__global__ __launch_bounds__(256) void k_gemm1(
    const void* __restrict__ x,
    const void* __restrict__ Wl, const void* __restrict__ bl,
    const void* __restrict__ Wr, const void* __restrict__ br,
    const int* __restrict__ flags,
    unsigned int* __restrict__ xlp, unsigned int* __restrict__ xrp)
{
  __shared__ float xs[32 * 132];
  __shared__ unsigned short ws[128 * 128];
  const void* W  = blockIdx.y ? Wr : Wl;
  const void* bb = blockIdx.y ? br : bl;
  int fW = blockIdx.y ? flags[4] : flags[2];
  int fB = blockIdx.y ? flags[5] : flags[3];
  int fX = flags[0];
  unsigned int* outp = blockIdx.y ? xrp : xlp;
  int tid = threadIdx.x;
  int row0 = blockIdx.x * 32;
  stageW(ws, W, 128 * 128, fW, tid);
  for (int i = tid * 4; i < 32 * 128; i += 1024) {
    int r = i >> 7, k = i & 127;
    int row = row0 + r;
    float4 v = make_float4(0.f, 0.f, 0.f, 0.f);
    if (row < N_NODES) {
      if (fX) v = *(const float4*)((const float*)x + (size_t)row * 128 + k);
      else {
        uint2 u = *(const uint2*)((const unsigned short*)x + (size_t)row * 128 + k);
        v.x = lo16(u.x); v.y = hi16(u.x); v.z = lo16(u.y); v.w = hi16(u.y);
      }
    }
    *(float4*)(xs + r * 132 + k) = v;
  }
  __syncthreads();
  int r = tid >> 3, cg = tid & 7;
  float acc[16];
#pragma unroll
  for (int j = 0; j < 16; j++) acc[j] = 0.f;
#pragma unroll 4
  for (int k = 0; k < 128; k++) {
    float xv = xs[r * 132 + k];
    uint4 p0 = *(const uint4*)(ws + k * 128 + cg * 8);
    uint4 p1 = *(const uint4*)(ws + k * 128 + 64 + cg * 8);
    acc[0]  = fmaf(xv, lo16(p0.x), acc[0]);  acc[1]  = fmaf(xv, hi16(p0.x), acc[1]);
    acc[2]  = fmaf(xv, lo16(p0.y), acc[2]);  acc[3]  = fmaf(xv, hi16(p0.y), acc[3]);
    acc[4]  = fmaf(xv, lo16(p0.z), acc[4]);  acc[5]  = fmaf(xv, hi16(p0.z), acc[5]);
    acc[6]  = fmaf(xv, lo16(p0.w), acc[6]);  acc[7]  = fmaf(xv, hi16(p0.w), acc[7]);
    acc[8]  = fmaf(xv, lo16(p1.x), acc[8]);  acc[9]  = fmaf(xv, hi16(p1.x), acc[9]);
    acc[10] = fmaf(xv, lo16(p1.y), acc[10]); acc[11] = fmaf(xv, hi16(p1.y), acc[11]);
    acc[12] = fmaf(xv, lo16(p1.z), acc[12]); acc[13] = fmaf(xv, hi16(p1.z), acc[13]);
    acc[14] = fmaf(xv, lo16(p1.w), acc[14]); acc[15] = fmaf(xv, hi16(p1.w), acc[15]);
  }
  int row = row0 + r;
  if (row < N_NODES) {
    unsigned int* op = outp + (size_t)row * 64;
    int tt = cg >> 1, qb = (cg & 1) * 2;
    unsigned int ou[4];
#pragma unroll
    for (int t = 0; t < 4; t++) {
      float f0 = fin(acc[2 * t]     + loadF(bb, fB, cg * 8 + 2 * t));
      float f1 = fin(acc[2 * t + 1] + loadF(bb, fB, cg * 8 + 2 * t + 1));
      ou[t] = (unsigned)f2bf(f0) | ((unsigned)f2bf(f1) << 16);
    }
    *(uint2*)(op + qb * 16 + tt * 2)       = make_uint2(ou[0], ou[1]);
    *(uint2*)(op + (qb + 1) * 16 + tt * 2) = make_uint2(ou[2], ou[3]);
#pragma unroll
    for (int t = 0; t < 4; t++) {
      float f0 = fin(acc[8 + 2 * t]     + loadF(bb, fB, 64 + cg * 8 + 2 * t));
      float f1 = fin(acc[8 + 2 * t + 1] + loadF(bb, fB, 64 + cg * 8 + 2 * t + 1));
      ou[t] = (unsigned)f2bf(f0) | ((unsigned)f2bf(f1) << 16);
    }
    *(uint2*)(op + qb * 16 + 8 + tt * 2)       = make_uint2(ou[0], ou[1]);
    *(uint2*)(op + (qb + 1) * 16 + 8 + tt * 2) = make_uint2(ou[2], ou[3]);
  }
}

// ---------- layer-2 GEMM: xl2p / xr2p, packed bf16 [N,32] uints in FRAGMENT order ----------
// natural uint u = t*8 + quad*2 + b (t=0..3) -> u' = quad*8 + t*2 + b
__global__ __launch_bounds__(256) void k_gemm2(
    const float* __restrict__ h,
    const void* __restrict__ Wl, const void* __restrict__ bl,
    const void* __restrict__ Wr, const void* __restrict__ br,
    const int* __restrict__ flags,
    unsigned int* __restrict__ xlp, unsigned int* __restrict__ xrp)
{
  __shared__ float hs[32 * 132];
  __shared__ unsigned short ws[128 * 64];
  const void* W  = blockIdx.y ? Wr : Wl;
  const void* bb = blockIdx.y ? br : bl;
  int fW = blockIdx.y ? flags[11] : flags[9];
  int fB = blockIdx.y ? flags[12] : flags[10];
  unsigned int* outp = blockIdx.y ? xrp : xlp;
  int tid = threadIdx.x;
  int row0 = blockIdx.x * 32;
  stageW(ws, W, 128 * 64, fW, tid);
  for (int i = tid * 4; i < 32 * 128; i += 1024) {
    int r = i >> 7, k = i & 127;
    int row = row0 + r;
    float4 v = make_float4(0.f, 0.f, 0.f, 0.f);
    if (row < N_NODES) v = *(const float4*)(h + (size_t)row * 128 + k);
    *(float4*)(hs + r * 132 + k) = v;
  }
  __syncthreads();
  int r = tid >> 3, cg = tid & 7;
  float acc[8];
#pragma unroll
  for (int j = 0; j < 8; j++) acc[j] = 0.f;
#pragma unroll 4
  for (int k = 0; k < 128; k++) {
    float hv = hs[r * 132 + k];
    uint4 p = *(const uint4*)(ws + k * 64 + cg * 8);
    acc[0] = fmaf(hv, lo16(p.x), acc[0]); acc[1] = fmaf(hv, hi16(p.x), acc[1]);
    acc[2] = fmaf(hv, lo16(p.y), acc[2]); acc[3] = fmaf(hv, hi16(p.y), acc[3]);
    acc[4] = fmaf(hv, lo16(p.z), acc[4]); acc[5] = fmaf(hv, hi16(p.z), acc[5]);
    acc[6] = fmaf(hv, lo16(p.w), acc[6]); acc[7] = fmaf(hv, hi16(p.w), acc[7]);
  }
  int row = row0 + r;
  if (row < N_NODES) {
    unsigned int* op = outp + (size_t)row * 32;
    int tt = cg >> 1, qb = (cg & 1) * 2;
    unsigned int ou[4];
#pragma unroll
    for (int t = 0; t < 4; t++) {
      float f0 = fin(acc[2 * t]     + loadF(bb, fB, cg * 8 + 2 * t));
      float f1 = fin(acc[2 * t + 1] + loadF(bb, fB, cg * 8 + 2 * t + 1));
      ou[t] = (unsigned)f2bf(f0) | ((unsigned)f2bf(f1) << 16);
    }
    *(uint2*)(op + qb * 8 + tt * 2)       = make_uint2(ou[0], ou[1]);
    *(uint2*)(op + (qb + 1) * 8 + tt * 2) = make_uint2(ou[2], ou[3]);
  }
}

// ---------- CSR build ----------
__global__ __launch_bounds__(256) void k_hist(const int* __restrict__ ei, int* __restrict__ counts)
{
  int e = blockIdx.x * 256 + threadIdx.x;
  if (e < N_EDGES) {
    int d = ei[N_EDGES + e]; if ((unsigned)d >= N_NODES) d = 0;
    atomicAdd(&counts[d], 1);
  }
}

__global__ __launch_bounds__(256) void k_scan1(const int* __restrict__ counts,
                                               int* __restrict__ row_ptr, int* __restrict__ bsum)
{
  __shared__ int lds[256];
  int t = threadIdx.x;
  int base = blockIdx.x * 1024 + t * 4;
  int c0 = (base + 0) < N_NODES ? counts[base + 0] : 0;
  int c1 = (base + 1) < N_NODES ? counts[base + 1] : 0;
  int c2 = (base + 2) < N_NODES ? counts[base + 2] : 0;
  int c3 = (base + 3) < N_NODES ? counts[base + 3] : 0;
  int s = c0 + c1 + c2 + c3;
  lds[t] = s; __syncthreads();
  for (int off = 1; off < 256; off <<= 1) {
    int v = (t >= off) ? lds[t - off] : 0;
    __syncthreads();
    lds[t] += v;
    __syncthreads();
  }
  int incl = lds[t];
  int excl = incl - s;
  if (base + 0 < N_NODES) row_ptr[base + 0] = excl;
  if (base + 1 < N_NODES) row_ptr[base + 1] = excl + c0;
  if (base + 2 < N_NODES) row_ptr[base + 2] = excl + c0 + c1;
  if (base + 3 < N_NODES) row_ptr[base + 3] = excl + c0 + c1 + c2;
  if (t == 255) bsum[blockIdx.x] = incl;
}

__global__ __launch_bounds__(64) void k_scan2(int* __restrict__ bsum, int nb)
{
  __shared__ int l[64];
  int t = threadIdx.x;
  if (t < nb) l[t] = bsum[t];
  __syncthreads();
  if (t == 0) { int run = 0; for (int i = 0; i < nb; i++) { int v = l[i]; l[i] = run; run += v; } }
  __syncthreads();
  if (t < nb) bsum[t] = l[t];
}

__global__ __launch_bounds__(256) void k_scan3(int* __restrict__ row_ptr, int* __restrict__ cursor,
                                               const int* __restrict__ bsum)
{
  int t = threadIdx.x;
  int base = blockIdx.x * 1024 + t * 4;
  int add = bsum[blockIdx.x];
#pragma unroll
  for (int j = 0; j < 4; j++) {
    int i = base + j;
    if (i < N_NODES) { int v = row_ptr[i] + add; row_ptr[i] = v; cursor[i] = v; }
  }
  if (blockIdx.x == 0 && t == 0) row_ptr[N_NODES] = N_EDGES;
}

// ---------- scatter: CSR perm + pack edge_attr to bf16 CSR order ----------
__global__ __launch_bounds__(256) void k_scatter(const int* __restrict__ ei,
                                                 int* __restrict__ cursor,
                                                 int* __restrict__ srcs,
                                                 const void* __restrict__ ea,
                                                 const int* __restrict__ flags,
                                                 unsigned short* __restrict__ eap)
{
  int e = blockIdx.x * 256 + threadIdx.x;
  if (e >= N_EDGES) return;
  int d = ei[N_EDGES + e]; if ((unsigned)d >= N_NODES) d = 0;
  int s = ei[e];           if ((unsigned)s >= N_NODES) s = 0;
  int p = atomicAdd(&cursor[d], 1);
  if ((unsigned)p >= N_EDGES) return;
  srcs[p] = s;
  unsigned short* op = eap + (size_t)p * 32;
  if (flags[1]) {
    const float* ip = (const float*)ea + (size_t)e * 32;
#pragma unroll
    for (int q = 0; q < 2; q++) {
      float4 a = *(const float4*)(ip + q * 16);
      float4 b = *(const float4*)(ip + q * 16 + 4);
      float4 c = *(const float4*)(ip + q * 16 + 8);
      float4 dd = *(const float4*)(ip + q * 16 + 12);
      uint4 u0, u1;
      u0.x = (unsigned)f2bf(a.x) | ((unsigned)f2bf(a.y) << 16);
      u0.y = (unsigned)f2bf(a.z) | ((unsigned)f2bf(a.w) << 16);
      u0.z = (unsigned)f2bf(b.x) | ((unsigned)f2bf(b.y) << 16);
      u0.w = (unsigned)f2bf(b.z) | ((unsigned)f2bf(b.w) << 16);
      u1.x = (unsigned)f2bf(c.x) | ((unsigned)f2bf(c.y) << 16);
      u1.y = (unsigned)f2bf(c.z) | ((unsigned)f2bf(c.w) << 16);
      u1.z = (unsigned)f2bf(dd.x) | ((unsigned)f2bf(dd.y) << 16);
      u1.w = (unsigned)f2bf(dd.z) | ((unsigned)f2bf(dd.w) << 16);
      *(uint4*)(op + q * 16) = u0;
      *(uint4*)(op + q * 16 + 8) = u1;
    }
  } else {
    const uint4* ip = (const uint4*)((const unsigned short*)ea + (size_t)e * 32);
#pragma unroll
    for (int q = 0; q < 4; q++) *(uint4*)(op + q * 8) = ip[q];
  }
}

// ---------- layer-1 fused score+aggregate: 2 nodes/wave interleaved ----------
// Wave handles nodes i0=blk*8+wv and i1=i0+4 in ONE loop (2x independent
// latency chains). Agg uses channel-owner epilogue; srcs re-read via SCALAR
// loads (jba wave-uniform via readfirstlane -> s_load + saddr gathers),
// replacing 16 of the 32 ds_bpermutes per chunk. srcs has a zeroed +16 pad.
__global__ __launch_bounds__(256) void k_fuse1(
    const unsigned short* __restrict__ eap, const int* __restrict__ srcs,
    const int* __restrict__ row_ptr,
    const unsigned int* __restrict__ xlp, const unsigned int* __restrict__ xrp,
    const void* __restrict__ We, const void* __restrict__ att,
    const void* __restrict__ bias, const int* __restrict__ flags,
    float* __restrict__ hout)
{
  __shared__ unsigned short wt[128 * 34];   // WeT[ch][k], stride 34
  __shared__ float at[128];
  int tid = threadIdx.x;
  {
    int f = flags[6];
    for (int i2 = tid; i2 < 4096; i2 += 256) {   // We[k][c] -> wt[c*34+k]
      int k = i2 >> 7, c = i2 & 127;
      wt[c * 34 + k] = f ? f2bf(((const float*)We)[i2]) : ((const unsigned short*)We)[i2];
    }
  }
  if (tid < 128) at[tid] = loadF(att, flags[7], tid);
  __syncthreads();
  int lane = tid & 63;
  int idx16 = lane & 15, quad = lane >> 4;
  int t_s = (lane & 15) >> 1, b_s = lane & 1;
  int un = t_s * 8 + quad * 2 + b_s;     // owned natural uint index in [0,64)
  int hd = un >> 4;                       // head of owned channels
  bf16x8 af[8];
#pragma unroll
  for (int t = 0; t < 8; t++)
    af[t] = *(const bf16x8*)(wt + (t * 16 + idx16) * 34 + quad * 8);
  int wv = tid >> 6;
  int i0 = blockIdx.x * 8 + wv;
  int i1 = i0 + 4;
  uint2 rv0[8], rv1[8];
#pragma unroll
  for (int t4 = 0; t4 < 4; t4++) {
    uint4 u = *(const uint4*)(xrp + (size_t)i0 * 64 + quad * 16 + t4 * 4);
    rv0[2 * t4]     = make_uint2(u.x, u.y);
    rv0[2 * t4 + 1] = make_uint2(u.z, u.w);
  }
#pragma unroll
  for (int t4 = 0; t4 < 4; t4++) {
    uint4 u = *(const uint4*)(xrp + (size_t)i1 * 64 + quad * 16 + t4 * 4);
    rv1[2 * t4]     = make_uint2(u.x, u.y);
    rv1[2 * t4 + 1] = make_uint2(u.z, u.w);
  }
  int p0a = __builtin_amdgcn_readfirstlane(row_ptr[i0]);
  int p1a = __builtin_amdgcn_readfirstlane(row_ptr[i0 + 1]);
  int p0b = __builtin_amdgcn_readfirstlane(row_ptr[i1]);
  int p1b = __builtin_amdgcn_readfirstlane(row_ptr[i1 + 1]);
  float aA0 = 0.f, aA1 = 0.f, dA = 0.f;
  float aB0 = 0.f, aB1 = 0.f, dB = 0.f;
  for (int jba = p0a, jbb = p0b; jba < p1a || jbb < p1b; jba += 16, jbb += 16) {
    // ---- issue both nodes' gathers up front ----
    int doA = jba < p1a, doB = jbb < p1b;
    int jA = jba + idx16, jB = jbb + idx16;
    int actA = jA < p1a, actB = jB < p1b;
    int jcA = actA ? jA : p0a, jcB = actB ? jB : p0b;
    int sA = srcs[jcA], sB = srcs[jcB];
    bf16x8 bfA, bfB;
    uint2 xvA[8], xvB[8];
    if (doA) {
      bfA = *(const bf16x8*)(eap + (size_t)jcA * 32 + quad * 8);
#pragma unroll
      for (int t4 = 0; t4 < 4; t4++) {
        uint4 u = *(const uint4*)(xlp + (size_t)sA * 64 + quad * 16 + t4 * 4);
        xvA[2 * t4]     = make_uint2(u.x, u.y);
        xvA[2 * t4 + 1] = make_uint2(u.z, u.w);
      }
    }
    if (doB) {
      bfB = *(const bf16x8*)(eap + (size_t)jcB * 32 + quad * 8);
#pragma unroll
      for (int t4 = 0; t4 < 4; t4++) {
        uint4 u = *(const uint4*)(xlp + (size_t)sB * 64 + quad * 16 + t4 * 4);
        xvB[2 * t4]     = make_uint2(u.x, u.y);
        xvB[2 * t4 + 1] = make_uint2(u.z, u.w);
      }
    }
    // ---- node A: logits + agg ----
    if (doA) {
      float ph0 = 0.f, ph1 = 0.f, ph2 = 0.f, ph3 = 0.f;
#pragma unroll
      for (int t = 0; t < 8; t++) {
        float4 av = *(const float4*)(at + t * 16 + quad * 4);
        uint2 r = rv0[t];
        f32x4 c = {0.f, 0.f, 0.f, 0.f};
        c = __builtin_amdgcn_mfma_f32_16x16x32_bf16(af[t], bfA, c, 0, 0, 0);
        float z0 = c[0] + lo16(xvA[t].x) + lo16(r.x);
        float z1 = c[1] + hi16(xvA[t].x) + hi16(r.x);
        float z2 = c[2] + lo16(xvA[t].y) + lo16(r.y);
        float z3 = c[3] + hi16(xvA[t].y) + hi16(r.y);
        z0 = z0 > 0.f ? z0 : 0.2f * z0;
        z1 = z1 > 0.f ? z1 : 0.2f * z1;
        z2 = z2 > 0.f ? z2 : 0.2f * z2;
        z3 = z3 > 0.f ? z3 : 0.2f * z3;
        float pp = fmaf(av.x, z0, fmaf(av.y, z1, fmaf(av.z, z2, av.w * z3)));
        if (t < 2)      ph0 += pp;
        else if (t < 4) ph1 += pp;
        else if (t < 6) ph2 += pp;
        else            ph3 += pp;
      }
      ph0 += __shfl_xor(ph0, 16, 64); ph0 += __shfl_xor(ph0, 32, 64);
      ph1 += __shfl_xor(ph1, 16, 64); ph1 += __shfl_xor(ph1, 32, 64);
      ph2 += __shfl_xor(ph2, 16, 64); ph2 += __shfl_xor(ph2, 32, 64);
      ph3 += __shfl_xor(ph3, 16, 64); ph3 += __shfl_xor(ph3, 32, 64);
      float w0 = actA ? __expf(fminf(fin(ph0), 25.f)) : 0.f;
      float w1 = actA ? __expf(fminf(fin(ph1), 25.f)) : 0.f;
      float w2 = actA ? __expf(fminf(fin(ph2), 25.f)) : 0.f;
      float w3 = actA ? __expf(fminf(fin(ph3), 25.f)) : 0.f;
      float wsel = quad == 0 ? w0 : quad == 1 ? w1 : quad == 2 ? w2 : w3;
#pragma unroll
      for (int q = 0; q < 16; q++) {
        int ej = jba + q;
        ej = (ej < p1a) ? ej : p0a;            // scalar clamp (pad-safe)
        int sq = srcs[ej];                     // s_load
        float wq = __shfl(wsel, hd * 16 + q, 64);
        unsigned int v = xlp[(size_t)sq * 64 + lane];   // L1-hot, saddr
        aA0 = fmaf(wq, lo16(v), aA0);
        aA1 = fmaf(wq, hi16(v), aA1);
        dA += wq;
      }
    }
    // ---- node B: logits + agg ----
    if (doB) {
      float ph0 = 0.f, ph1 = 0.f, ph2 = 0.f, ph3 = 0.f;
#pragma unroll
      for (int t = 0; t < 8; t++) {
        float4 av = *(const float4*)(at + t * 16 + quad * 4);
        uint2 r = rv1[t];
        f32x4 c = {0.f, 0.f, 0.f, 0.f};
        c = __builtin_amdgcn_mfma_f32_16x16x32_bf16(af[t], bfB, c, 0, 0, 0);
        float z0 = c[0] + lo16(xvB[t].x) + lo16(r.x);
        float z1 = c[1] + hi16(xvB[t].x) + hi16(r.x);
        float z2 = c[2] + lo16(xvB[t].y) + lo16(r.y);
        float z3 = c[3] + hi16(xvB[t].y) + hi16(r.y);
        z0 = z0 > 0.f ? z0 : 0.2f * z0;
        z1 = z1 > 0.f ? z1 : 0.2f * z1;
        z2 = z2 > 0.f ? z2 : 0.2f * z2;
        z3 = z3 > 0.f ? z3 : 0.2f * z3;
        float pp = fmaf(av.x, z0, fmaf(av.y, z1, fmaf(av.z, z2, av.w * z3)));
        if (t < 2)      ph0 += pp;
        else if (t < 4) ph1 += pp;
        else if (t < 6) ph2 += pp;
        else            ph3 += pp;
      }
      ph0 += __shfl_xor(ph0, 16, 64); ph0 += __shfl_xor(ph0, 32, 64);
      ph1 += __shfl_xor(ph1, 16, 64); ph1 += __shfl_xor(ph1, 32, 64);
      ph2 += __shfl_xor(ph2, 16, 64); ph2 += __shfl_xor(ph2, 32, 64);
      ph3 += __shfl_xor(ph3, 16, 64); ph3 += __shfl_xor(ph3, 32, 64);
      float w0 = actB ? __expf(fminf(fin(ph0), 25.f)) : 0.f;
      float w1 = actB ? __expf(fminf(fin(ph1), 25.f)) : 0.f;
      float w2 = actB ? __expf(fminf(fin(ph2), 25.f)) : 0.f;
      float w3 = actB ? __expf(fminf(fin(ph3), 25.f)) : 0.f;
      float wsel = quad == 0 ? w0 : quad == 1 ? w1 : quad == 2 ? w2 : w3;
#pragma unroll
      for (int q = 0; q < 16; q++) {
        int ej = jbb + q;
        ej = (ej < p1b) ? ej : p0b;
        int sq = srcs[ej];
        float wq = __shfl(wsel, hd * 16 + q, 64);
        unsigned int v = xlp[(size_t)sq * 64 + lane];
        aB0 = fmaf(wq, lo16(v), aB0);
        aB1 = fmaf(wq, hi16(v), aB1);
        dB += wq;
      }
    }
  }
  int fB = flags[8];
  int ch = un * 2;
  float b0 = loadF(bias, fB, ch), b1 = loadF(bias, fB, ch + 1);
  {
    float inv = 1.f / (dA + 1e-16f);
    float o0 = fin(fmaf(aA0, inv, b0));
    float o1 = fin(fmaf(aA1, inv, b1));
    o0 = o0 > 0.f ? o0 : __expf(o0) - 1.f;
    o1 = o1 > 0.f ? o1 : __expf(o1) - 1.f;
    *(float2*)(hout + (size_t)i0 * 128 + ch) = make_float2(o0, o1);
  }
  {
    float inv = 1.f / (dB + 1e-16f);
    float o0 = fin(fmaf(aB0, inv, b0));
    float o1 = fin(fmaf(aB1, inv, b1));
    o0 = o0 > 0.f ? o0 : __expf(o0) - 1.f;
    o1 = o1 > 0.f ? o1 : __expf(o1) - 1.f;
    *(float2*)(hout + (size_t)i1 * 128 + ch) = make_float2(o0, o1);
  }
}

// ---------- layer-2 fused score+aggregate (H=1, C=64): 2 nodes/wave ----------
// half-wave edge split in agg (shfl-based s/w broadcast, as r6);
// one cross-half reduce per node at the end; lanes 0..31 write.
__global__ __launch_bounds__(256) void k_fuse2(
    const unsigned short* __restrict__ eap, const int* __restrict__ srcs,
    const int* __restrict__ row_ptr,
    const unsigned int* __restrict__ xlp, const unsigned int* __restrict__ xrp,
    const void* __restrict__ We, const void* __restrict__ att,
    const void* __restrict__ bias, const int* __restrict__ flags,
    void* __restrict__ out)
{
  __shared__ unsigned short wt[64 * 34];
  __shared__ float at[64];
  int tid = threadIdx.x;
  {
    int f = flags[13];
    for (int i2 = tid; i2 < 2048; i2 += 256) {   // We[k][c] -> wt[c*34+k]
      int k = i2 >> 6, c = i2 & 63;
      wt[c * 34 + k] = f ? f2bf(((const float*)We)[i2]) : ((const unsigned short*)We)[i2];
    }
  }
  if (tid < 64) at[tid] = loadF(att, flags[14], tid);
  __syncthreads();
  int lane = tid & 63;
  int idx16 = lane & 15, quad = lane >> 4;
  int l5 = lane & 31;
  int q_s = l5 >> 3, t2 = (l5 & 7) >> 1, b2 = l5 & 1;
  int un = t2 * 8 + q_s * 2 + b2;        // owned natural uint index in [0,32)
  int halfe = lane >> 5;
  bf16x8 af[4];
#pragma unroll
  for (int t = 0; t < 4; t++)
    af[t] = *(const bf16x8*)(wt + (t * 16 + idx16) * 34 + quad * 8);
  int wv = tid >> 6;
  int i0 = blockIdx.x * 8 + wv;
  int i1 = i0 + 4;
  uint2 rv0[4], rv1[4];
#pragma unroll
  for (int k = 0; k < 2; k++) {
    uint4 u = *(const uint4*)(xrp + (size_t)i0 * 32 + quad * 8 + k * 4);
    rv0[2 * k]     = make_uint2(u.x, u.y);
    rv0[2 * k + 1] = make_uint2(u.z, u.w);
  }
#pragma unroll
  for (int k = 0; k < 2; k++) {
    uint4 u = *(const uint4*)(xrp + (size_t)i1 * 32 + quad * 8 + k * 4);
    rv1[2 * k]     = make_uint2(u.x, u.y);
    rv1[2 * k + 1] = make_uint2(u.z, u.w);
  }
  int p0a = __builtin_amdgcn_readfirstlane(row_ptr[i0]);
  int p1a = __builtin_amdgcn_readfirstlane(row_ptr[i0 + 1]);
  int p0b = __builtin_amdgcn_readfirstlane(row_ptr[i1]);
  int p1b = __builtin_amdgcn_readfirstlane(row_ptr[i1 + 1]);
  float aA0 = 0.f, aA1 = 0.f, dA = 0.f;
  float aB0 = 0.f, aB1 = 0.f, dB = 0.f;
  for (int jba = p0a, jbb = p0b; jba < p1a || jbb < p1b; jba += 16, jbb += 16) {
    int doA = jba < p1a, doB = jbb < p1b;
    int jA = jba + idx16, jB = jbb + idx16;
    int actA = jA < p1a, actB = jB < p1b;
    int jcA = actA ? jA : p0a, jcB = actB ? jB : p0b;
    int sA = srcs[jcA], sB = srcs[jcB];
    if (doA) {
      bf16x8 bfrag = *(const bf16x8*)(eap + (size_t)jcA * 32 + quad * 8);
      uint2 xv[4];
#pragma unroll
      for (int k = 0; k < 2; k++) {
        uint4 u = *(const uint4*)(xlp + (size_t)sA * 32 + quad * 8 + k * 4);
        xv[2 * k]     = make_uint2(u.x, u.y);
        xv[2 * k + 1] = make_uint2(u.z, u.w);
      }
      float ph = 0.f;
#pragma unroll
      for (int t = 0; t < 4; t++) {
        float4 av = *(const float4*)(at + t * 16 + quad * 4);
        uint2 r = rv0[t];
        f32x4 c = {0.f, 0.f, 0.f, 0.f};
        c = __builtin_amdgcn_mfma_f32_16x16x32_bf16(af[t], bfrag, c, 0, 0, 0);
        float z0 = c[0] + lo16(xv[t].x) + lo16(r.x);
        float z1 = c[1] + hi16(xv[t].x) + hi16(r.x);
        float z2 = c[2] + lo16(xv[t].y) + lo16(r.y);
        float z3 = c[3] + hi16(xv[t].y) + hi16(r.y);
        z0 = z0 > 0.f ? z0 : 0.2f * z0;
        z1 = z1 > 0.f ? z1 : 0.2f * z1;
        z2 = z2 > 0.f ? z2 : 0.2f * z2;
        z3 = z3 > 0.f ? z3 : 0.2f * z3;
        ph += fmaf(av.x, z0, fmaf(av.y, z1, fmaf(av.z, z2, av.w * z3)));
      }
      ph += __shfl_xor(ph, 16, 64);
      ph += __shfl_xor(ph, 32, 64);
      float wsel = actA ? __expf(fminf(fin(ph), 25.f)) : 0.f;
#pragma unroll
      for (int q = 0; q < 8; q++) {
        int qq = 2 * q + halfe;
        int sq = __shfl(sA, qq, 64);
        float wq = __shfl(wsel, qq, 64);
        unsigned int v = xlp[(size_t)sq * 32 + l5];
        aA0 = fmaf(wq, lo16(v), aA0);
        aA1 = fmaf(wq, hi16(v), aA1);
        dA += wq;
      }
    }
    if (doB) {
      bf16x8 bfrag = *(const bf16x8*)(eap + (size_t)jcB * 32 + quad * 8);
      uint2 xv[4];
#pragma unroll
      for (int k = 0; k < 2; k++) {
        uint4 u = *(const uint4*)(xlp + (size_t)sB * 32 + quad * 8 + k * 4);
        xv[2 * k]     = make_uint2(u.x, u.y);
        xv[2 * k + 1] = make_uint2(u.z, u.w);
      }
      float ph = 0.f;
#pragma unroll
      for (int t = 0; t < 4; t++) {
        float4 av = *(const float4*)(at + t * 16 + quad * 4);
        uint2 r = rv1[t];
        f32x4 c = {0.f, 0.f, 0.f, 0.f};
        c = __builtin_amdgcn_mfma_f32_16x16x32_bf16(af[t], bfrag, c, 0, 0, 0);
        float z0 = c[0] + lo16(xv[t].x) + lo16(r.x);
        float z1 = c[1] + hi16(xv[t].x) + hi16(r.x);
        float z2 = c[2] + lo16(xv[t].y) + lo16(r.y);
        float z3 = c[3] + hi16(xv[t].y) + hi16(r.y);
        z0 = z0 > 0.f ? z0 : 0.2f * z0;
        z1 = z1 > 0.f ? z1 : 0.2f * z1;
        z2 = z2 > 0.f ? z2 : 0.2f * z2;
        z3 = z3 > 0.f ? z3 : 0.2f * z3;
        ph += fmaf(av.x, z0, fmaf(av.y, z1, fmaf(av.z, z2, av.w * z3)));
      }
      ph += __shfl_xor(ph, 16, 64);
      ph += __shfl_xor(ph, 32, 64);
      float wsel = actB ? __expf(fminf(fin(ph), 25.f)) : 0.f;
#pragma unroll
      for (int q = 0; q < 8; q++) {
        int qq = 2 * q + halfe;
        int sq = __shfl(sB, qq, 64);
        float wq = __shfl(wsel, qq, 64);
        unsigned int v = xlp[(size_t)sq * 32 + l5];
        aB0 = fmaf(wq, lo16(v), aB0);
        aB1 = fmaf(wq, hi16(v), aB1);
        dB += wq;
      }
    }
  }
  aA0 += __shfl_xor(aA0, 32, 64);
  aA1 += __shfl_xor(aA1, 32, 64);
  dA  += __shfl_xor(dA, 32, 64);
  aB0 += __shfl_xor(aB0, 32, 64);
  aB1 += __shfl_xor(aB1, 32, 64);
  dB  += __shfl_xor(dB, 32, 64);
  if (lane < 32) {
    int fB = flags[15];
    int ch = un * 2;
    float b0 = loadF(bias, fB, ch), b1 = loadF(bias, fB, ch + 1);
    float invA = 1.f / (dA + 1e-16f);
    float oA0 = fin(fmaf(aA0, invA, b0));
    float oA1 = fin(fmaf(aA1, invA, b1));
    float invB = 1.f / (dB + 1e-16f);
    float oB0 = fin(fmaf(aB0, invB, b0));
    float oB1 = fin(fmaf(aB1, invB, b1));
    if (flags[0]) {
      *(float2*)((float*)out + (size_t)i0 * 64 + ch) = make_float2(oA0, oA1);
      *(float2*)((float*)out + (size_t)i1 * 64 + ch) = make_float2(oB0, oB1);
    } else {
      unsigned int uA = (unsigned)f2bf(oA0) | ((unsigned)f2bf(oA1) << 16);
      unsigned int uB = (unsigned)f2bf(oB0) | ((unsigned)f2bf(oB1) << 16);
      *(unsigned int*)((unsigned short*)out + (size_t)i0 * 64 + ch) = uA;
      *(unsigned int*)((unsigned short*)out + (size_t)i1 * 64 + ch) = uB;
    }
  }
}

extern "C" void kernel_launch(void* const* d_in, const int* in_sizes, int n_in,
                              void* d_out, int out_size, void* d_ws, size_t ws_size,
                              hipStream_t stream)
{
  (void)n_in; (void)out_size; (void)ws_size;
  const void* x    = d_in[0];
  const int*  ei   = (const int*)d_in[1];
  const void* ea   = d_in[2];
  const void* Wl1  = d_in[3];
  const void* bl1  = d_in[4];
  const void* Wr1  = d_in[5];
  const void* br1  = d_in[6];
  const void* We1  = d_in[7];
  const void* att1 = d_in[8];
  const void* bias1= d_in[9];
  const void* Wl2  = d_in[10];
  const void* bl2  = d_in[11];
  const void* Wr2  = d_in[12];
  const void* br2  = d_in[13];
  const void* We2  = d_in[14];
  const void* att2 = d_in[15];
  const void* bias2= d_in[16];

  char* ws = (char*)d_ws;
  size_t off = 0;
  auto take = [&](size_t bytes) -> char* {
    char* p = ws + off;
    off += (bytes + 255) & ~(size_t)255;
    return p;
  };
  unsigned int* xl1p = (unsigned int*)take((size_t)N_NODES * 64 * 4);   // 12.8 MB
  unsigned int* xr1p = (unsigned int*)take((size_t)N_NODES * 64 * 4);   // 12.8 MB
  float* hbuf   = (float*)take((size_t)N_NODES * 128 * 4);              // 25.6 MB
  unsigned short* eap = (unsigned short*)take((size_t)(N_EDGES + 16) * 32 * 2); // 51.2 MB
  int*   counts = (int*)  take((size_t)N_NODES * 4);
  int*   row_ptr= (int*)  take((size_t)(N_NODES + 1) * 4);
  int*   cursor = (int*)  take((size_t)N_NODES * 4);
  int*   srcs   = (int*)  take((size_t)(N_EDGES + 16) * 4);
  int*   bsum   = (int*)  take(64 * 4);
  int*   flags  = (int*)  take(64 * 4);
  unsigned int* xl2p = xl1p;      // layer-2 reuses ([N,32] <= [N,64])
  unsigned int* xr2p = xr1p;

  Ptrs tl;
  const int map[16] = {0, 2, 3, 4, 5, 6, 7, 8, 9, 10, 11, 12, 13, 14, 15, 16};
  for (int j = 0; j < 16; j++) { tl.p[j] = d_in[map[j]]; tl.n[j] = in_sizes[map[j]]; }

  int nb = (N_NODES + 1023) / 1024;
  k_detect<<<16, 256, 0, stream>>>(tl, flags);
  k_zero<<<(N_NODES + 255) / 256, 256, 0, stream>>>(counts, N_NODES, srcs + N_EDGES);
  k_gemm1<<<dim3((N_NODES + 31) / 32, 2), 256, 0, stream>>>(x, Wl1, bl1, Wr1, br1, flags, xl1p, xr1p);
  k_hist<<<(N_EDGES + 255) / 256, 256, 0, stream>>>(ei, counts);
  k_scan1<<<nb, 256, 0, stream>>>(counts, row_ptr, bsum);
  k_scan2<<<1, 64, 0, stream>>>(bsum, nb);
  k_scan3<<<nb, 256, 0, stream>>>(row_ptr, cursor, bsum);
  k_scatter<<<(N_EDGES + 255) / 256, 256, 0, stream>>>(ei, cursor, srcs, ea, flags, eap);
  k_fuse1<<<N_NODES / 8, 256, 0, stream>>>(eap, srcs, row_ptr, xl1p, xr1p, We1, att1, bias1, flags, hbuf);
  k_gemm2<<<dim3((N_NODES + 31) / 32, 2), 256, 0, stream>>>(hbuf, Wl2, bl2, Wr2, br2, flags, xl2p, xr2p);
  k_fuse2<<<N_NODES / 8, 256, 0, stream>>>(eap, srcs, row_ptr, xl2p, xr2p, We2, att2, bias2, flags, d_out);
}

// Round 8
// 657.709 us; speedup vs baseline: 1.5873x; 1.0622x over previous
//
#include <hip/hip_runtime.h>
#include <stdint.h>

#define N_NODES 50000
#define N_EDGES 800000

// flag indices: 0:x 1:ea 2:Wl1 3:bl1 4:Wr1 5:br1 6:We1 7:att1 8:bias1
//               9:Wl2 10:bl2 11:Wr2 12:br2 13:We2 14:att2 15:bias2
struct Ptrs { const void* p[16]; int n[16]; };

typedef __attribute__((ext_vector_type(8))) short bf16x8;
typedef __attribute__((ext_vector_type(4))) float f32x4;

__device__ __forceinline__ float bf2f(unsigned short u){
  union { unsigned int i; float f; } v; v.i = ((unsigned int)u) << 16; return v.f;
}
__device__ __forceinline__ float lo16(unsigned int u){ union { unsigned int i; float f; } v; v.i = u << 16; return v.f; }
__device__ __forceinline__ float hi16(unsigned int u){ union { unsigned int i; float f; } v; v.i = u & 0xffff0000u; return v.f; }
__device__ __forceinline__ unsigned short f2bf(float f){
  if (!(f == f)) return 0;
  unsigned int x = __float_as_uint(f);
  unsigned int r = (x + 0x7fffu + ((x >> 16) & 1u)) >> 16;
  return (unsigned short)r;
}
__device__ __forceinline__ float fin(float v){
  if (!(v == v)) return 0.f;
  return fminf(fmaxf(v, -1e30f), 1e30f);
}
__device__ __forceinline__ float loadF(const void* p, int f32, size_t idx){
  return f32 ? ((const float*)p)[idx] : bf2f(((const unsigned short*)p)[idx]);
}

// ---------- dtype detect + zero (merged) ----------
__global__ __launch_bounds__(256) void k_detect(Ptrs tl, int* __restrict__ flags,
                                                int* __restrict__ counts, int* __restrict__ pad16)
{
  if (blockIdx.x >= 16) {
    int i = (blockIdx.x - 16) * 256 + threadIdx.x;
    if (i < N_NODES) counts[i] = 0;
    if (blockIdx.x == 16 && threadIdx.x < 16) pad16[threadIdx.x] = 0;
    return;
  }
  __shared__ int red[256];
  int b = blockIdx.x, t = threadIdx.x;
  const unsigned short* p = (const unsigned short*)tl.p[b];
  int n = tl.n[b]; if (n > 16384) n = 16384;
  int crazy = 0;
  for (int i = t; i < n; i += 256) {
    unsigned short u = p[i];
    if (u) {
      int ex = (u >> 7) & 0xFF;
      if (ex == 0xFF || ex < 0x60) crazy++;
    }
  }
  red[t] = crazy; __syncthreads();
  for (int off = 128; off; off >>= 1) { if (t < off) red[t] += red[t + off]; __syncthreads(); }
  if (t == 0) flags[b] = (red[0] * 10 > n) ? 1 : 0;
}

// ---------- layer-1 GEMM (MFMA, hi/lo bf16 split): xlp/xrp fragment-order bf16 [N,64] uints ----------
// A = x rows (hi+lo bf16 from LDS), B = W cols in REGISTERS (W is L2-resident, no LDS stage).
// MFMA convention identical to k_score1 (verified): A m-dim = af idx16, B n-dim = bfrag idx16,
// D lane(i16,q) holds rows q*4+r, col i16. Out via LDS f32 staging -> existing epilogue.
__global__ __launch_bounds__(256) void k_gemm1(
    const void* __restrict__ x,
    const void* __restrict__ Wl, const void* __restrict__ bl,
    const void* __restrict__ Wr, const void* __restrict__ br,
    const int* __restrict__ flags,
    unsigned int* __restrict__ xlp, unsigned int* __restrict__ xrp)
{
  __shared__ __align__(16) char smem[17408];
  unsigned short* xh  = (unsigned short*)smem;            // [32][136] bf16 hi
  unsigned short* xlo = (unsigned short*)(smem + 8704);   // [32][136] bf16 lo residual
  float* outb = (float*)smem;                             // [32][132] f32 (alias, after sync)
  const void* W  = blockIdx.y ? Wr : Wl;
  const void* bb = blockIdx.y ? br : bl;
  int fW = blockIdx.y ? flags[4] : flags[2];
  int fB = blockIdx.y ? flags[5] : flags[3];
  int fX = flags[0];
  unsigned int* outp = blockIdx.y ? xrp : xlp;
  int tid = threadIdx.x;
  int row0 = blockIdx.x * 32;
  // stage x rows as hi/lo bf16
  for (int i = tid * 4; i < 32 * 128; i += 1024) {
    int r = i >> 7, k = i & 127;
    int row = row0 + r;
    float4 v = make_float4(0.f, 0.f, 0.f, 0.f);
    if (row < N_NODES) {
      if (fX) v = *(const float4*)((const float*)x + (size_t)row * 128 + k);
      else {
        uint2 u = *(const uint2*)((const unsigned short*)x + (size_t)row * 128 + k);
        v.x = lo16(u.x); v.y = hi16(u.x); v.z = lo16(u.y); v.w = hi16(u.y);
      }
    }
    unsigned short h0 = f2bf(v.x), h1 = f2bf(v.y), h2 = f2bf(v.z), h3 = f2bf(v.w);
    *(ushort4*)(xh + r * 136 + k) = make_ushort4(h0, h1, h2, h3);
    ushort4 lv;
    lv.x = f2bf(v.x - bf2f(h0)); lv.y = f2bf(v.y - bf2f(h1));
    lv.z = f2bf(v.z - bf2f(h2)); lv.w = f2bf(v.w - bf2f(h3));
    *(ushort4*)(xlo + r * 136 + k) = lv;
  }
  // B fragments in registers: wave wv covers cols wv*32 .. wv*32+31
  int lane = tid & 63, wv = tid >> 6;
  int idx16 = lane & 15, quad = lane >> 4;
  bf16x8 bfr[2][4];
#pragma unroll
  for (int ct = 0; ct < 2; ct++) {
#pragma unroll
    for (int kc = 0; kc < 4; kc++) {
      int col = wv * 32 + ct * 16 + idx16;
      unsigned short tmp[8];
#pragma unroll
      for (int j = 0; j < 8; j++) {
        int kk = kc * 32 + quad * 8 + j;
        tmp[j] = fW ? f2bf(((const float*)W)[(size_t)kk * 128 + col])
                    : ((const unsigned short*)W)[(size_t)kk * 128 + col];
      }
      bfr[ct][kc] = *(const bf16x8*)tmp;
    }
  }
  __syncthreads();
  f32x4 acc[2][2];
#pragma unroll
  for (int rt = 0; rt < 2; rt++)
#pragma unroll
    for (int ct = 0; ct < 2; ct++)
      acc[rt][ct] = (f32x4){0.f, 0.f, 0.f, 0.f};
#pragma unroll
  for (int kc = 0; kc < 4; kc++) {
#pragma unroll
    for (int rt = 0; rt < 2; rt++) {
      bf16x8 ah = *(const bf16x8*)(xh  + (rt * 16 + idx16) * 136 + kc * 32 + quad * 8);
      bf16x8 al = *(const bf16x8*)(xlo + (rt * 16 + idx16) * 136 + kc * 32 + quad * 8);
#pragma unroll
      for (int ct = 0; ct < 2; ct++) {
        acc[rt][ct] = __builtin_amdgcn_mfma_f32_16x16x32_bf16(ah, bfr[ct][kc], acc[rt][ct], 0, 0, 0);
        acc[rt][ct] = __builtin_amdgcn_mfma_f32_16x16x32_bf16(al, bfr[ct][kc], acc[rt][ct], 0, 0, 0);
      }
    }
  }
  __syncthreads();   // all LDS reads done before aliasing outb over xh/xlo
#pragma unroll
  for (int rt = 0; rt < 2; rt++)
#pragma unroll
    for (int ct = 0; ct < 2; ct++)
#pragma unroll
      for (int r = 0; r < 4; r++)
        outb[(rt * 16 + quad * 4 + r) * 132 + wv * 32 + ct * 16 + idx16] = acc[rt][ct][r];
  __syncthreads();
  // existing fragment-order epilogue, fed from outb
  int r = tid >> 3, cg = tid & 7;
  float a2[16];
#pragma unroll
  for (int j = 0; j < 8; j++) {
    a2[j]     = outb[r * 132 + cg * 8 + j];
    a2[8 + j] = outb[r * 132 + 64 + cg * 8 + j];
  }
  int row = row0 + r;
  if (row < N_NODES) {
    unsigned int* op = outp + (size_t)row * 64;
    int tt = cg >> 1, qb = (cg & 1) * 2;
    unsigned int ou[4];
#pragma unroll
    for (int t = 0; t < 4; t++) {
      float f0 = fin(a2[2 * t]     + loadF(bb, fB, cg * 8 + 2 * t));
      float f1 = fin(a2[2 * t + 1] + loadF(bb, fB, cg * 8 + 2 * t + 1));
      ou[t] = (unsigned)f2bf(f0) | ((unsigned)f2bf(f1) << 16);
    }
    *(uint2*)(op + qb * 16 + tt * 2)       = make_uint2(ou[0], ou[1]);
    *(uint2*)(op + (qb + 1) * 16 + tt * 2) = make_uint2(ou[2], ou[3]);
#pragma unroll
    for (int t = 0; t < 4; t++) {
      float f0 = fin(a2[8 + 2 * t]     + loadF(bb, fB, 64 + cg * 8 + 2 * t));
      float f1 = fin(a2[8 + 2 * t + 1] + loadF(bb, fB, 64 + cg * 8 + 2 * t + 1));
      ou[t] = (unsigned)f2bf(f0) | ((unsigned)f2bf(f1) << 16);
    }
    *(uint2*)(op + qb * 16 + 8 + tt * 2)       = make_uint2(ou[0], ou[1]);
    *(uint2*)(op + (qb + 1) * 16 + 8 + tt * 2) = make_uint2(ou[2], ou[3]);
  }
}

// ---------- layer-2 GEMM (MFMA, hi/lo): xl2p/xr2p fragment-order bf16 [N,32] uints ----------
__global__ __launch_bounds__(256) void k_gemm2(
    const float* __restrict__ h,
    const void* __restrict__ Wl, const void* __restrict__ bl,
    const void* __restrict__ Wr, const void* __restrict__ br,
    const int* __restrict__ flags,
    unsigned int* __restrict__ xlp, unsigned int* __restrict__ xrp)
{
  __shared__ __align__(16) char smem[17408];
  unsigned short* hh  = (unsigned short*)smem;            // [32][136]
  unsigned short* hlo = (unsigned short*)(smem + 8704);   // [32][136]
  float* outb = (float*)smem;                             // [32][68] f32 (alias)
  const void* W  = blockIdx.y ? Wr : Wl;
  const void* bb = blockIdx.y ? br : bl;
  int fW = blockIdx.y ? flags[11] : flags[9];
  int fB = blockIdx.y ? flags[12] : flags[10];
  unsigned int* outp = blockIdx.y ? xrp : xlp;
  int tid = threadIdx.x;
  int row0 = blockIdx.x * 32;
  for (int i = tid * 4; i < 32 * 128; i += 1024) {
    int r = i >> 7, k = i & 127;
    int row = row0 + r;
    float4 v = make_float4(0.f, 0.f, 0.f, 0.f);
    if (row < N_NODES) v = *(const float4*)(h + (size_t)row * 128 + k);
    unsigned short h0 = f2bf(v.x), h1 = f2bf(v.y), h2 = f2bf(v.z), h3 = f2bf(v.w);
    *(ushort4*)(hh + r * 136 + k) = make_ushort4(h0, h1, h2, h3);
    ushort4 lv;
    lv.x = f2bf(v.x - bf2f(h0)); lv.y = f2bf(v.y - bf2f(h1));
    lv.z = f2bf(v.z - bf2f(h2)); lv.w = f2bf(v.w - bf2f(h3));
    *(ushort4*)(hlo + r * 136 + k) = lv;
  }
  int lane = tid & 63, wv = tid >> 6;
  int idx16 = lane & 15, quad = lane >> 4;
  bf16x8 bfr[4];
#pragma unroll
  for (int kc = 0; kc < 4; kc++) {
    int col = wv * 16 + idx16;
    unsigned short tmp[8];
#pragma unroll
    for (int j = 0; j < 8; j++) {
      int kk = kc * 32 + quad * 8 + j;
      tmp[j] = fW ? f2bf(((const float*)W)[(size_t)kk * 64 + col])
                  : ((const unsigned short*)W)[(size_t)kk * 64 + col];
    }
    bfr[kc] = *(const bf16x8*)tmp;
  }
  __syncthreads();
  f32x4 acc[2];
  acc[0] = (f32x4){0.f, 0.f, 0.f, 0.f};
  acc[1] = (f32x4){0.f, 0.f, 0.f, 0.f};
#pragma unroll
  for (int kc = 0; kc < 4; kc++) {
#pragma unroll
    for (int rt = 0; rt < 2; rt++) {
      bf16x8 ah = *(const bf16x8*)(hh  + (rt * 16 + idx16) * 136 + kc * 32 + quad * 8);
      bf16x8 al = *(const bf16x8*)(hlo + (rt * 16 + idx16) * 136 + kc * 32 + quad * 8);
      acc[rt] = __builtin_amdgcn_mfma_f32_16x16x32_bf16(ah, bfr[kc], acc[rt], 0, 0, 0);
      acc[rt] = __builtin_amdgcn_mfma_f32_16x16x32_bf16(al, bfr[kc], acc[rt], 0, 0, 0);
    }
  }
  __syncthreads();
#pragma unroll
  for (int rt = 0; rt < 2; rt++)
#pragma unroll
    for (int r = 0; r < 4; r++)
      outb[(rt * 16 + quad * 4 + r) * 68 + wv * 16 + idx16] = acc[rt][r];
  __syncthreads();
  int r = tid >> 3, cg = tid & 7;
  float a2[8];
#pragma unroll
  for (int j = 0; j < 8; j++) a2[j] = outb[r * 68 + cg * 8 + j];
  int row = row0 + r;
  if (row < N_NODES) {
    unsigned int* op = outp + (size_t)row * 32;
    int tt = cg >> 1, qb = (cg & 1) * 2;
    unsigned int ou[4];
#pragma unroll
    for (int t = 0; t < 4; t++) {
      float f0 = fin(a2[2 * t]     + loadF(bb, fB, cg * 8 + 2 * t));
      float f1 = fin(a2[2 * t + 1] + loadF(bb, fB, cg * 8 + 2 * t + 1));
      ou[t] = (unsigned)f2bf(f0) | ((unsigned)f2bf(f1) << 16);
    }
    *(uint2*)(op + qb * 8 + tt * 2)       = make_uint2(ou[0], ou[1]);
    *(uint2*)(op + (qb + 1) * 8 + tt * 2) = make_uint2(ou[2], ou[3]);
  }
}

// ---------- CSR build ----------
__global__ __launch_bounds__(256) void k_hist(const int* __restrict__ ei, int* __restrict__ counts)
{
  int e = blockIdx.x * 256 + threadIdx.x;
  if (e < N_EDGES) {
    int d = ei[N_EDGES + e]; if ((unsigned)d >= N_NODES) d = 0;
    atomicAdd(&counts[d], 1);
  }
}

__global__ __launch_bounds__(256) void k_scan1(const int* __restrict__ counts,
                                               int* __restrict__ row_ptr, int* __restrict__ bsum)
{
  __shared__ int lds[256];
  int t = threadIdx.x;
  int base = blockIdx.x * 1024 + t * 4;
  int c0 = (base + 0) < N_NODES ? counts[base + 0] : 0;
  int c1 = (base + 1) < N_NODES ? counts[base + 1] : 0;
  int c2 = (base + 2) < N_NODES ? counts[base + 2] : 0;
  int c3 = (base + 3) < N_NODES ? counts[base + 3] : 0;
  int s = c0 + c1 + c2 + c3;
  lds[t] = s; __syncthreads();
  for (int off = 1; off < 256; off <<= 1) {
    int v = (t >= off) ? lds[t - off] : 0;
    __syncthreads();
    lds[t] += v;
    __syncthreads();
  }
  int incl = lds[t];
  int excl = incl - s;
  if (base + 0 < N_NODES) row_ptr[base + 0] = excl;
  if (base + 1 < N_NODES) row_ptr[base + 1] = excl + c0;
  if (base + 2 < N_NODES) row_ptr[base + 2] = excl + c0 + c1;
  if (base + 3 < N_NODES) row_ptr[base + 3] = excl + c0 + c1 + c2;
  if (t == 255) bsum[blockIdx.x] = incl;
}

__global__ __launch_bounds__(64) void k_scan2(int* __restrict__ bsum, int nb)
{
  __shared__ int l[64];
  int t = threadIdx.x;
  if (t < nb) l[t] = bsum[t];
  __syncthreads();
  if (t == 0) { int run = 0; for (int i = 0; i < nb; i++) { int v = l[i]; l[i] = run; run += v; } }
  __syncthreads();
  if (t < nb) bsum[t] = l[t];
}

__global__ __launch_bounds__(256) void k_scan3(int* __restrict__ row_ptr, int* __restrict__ cursor,
                                               const int* __restrict__ bsum)
{
  int t = threadIdx.x;
  int base = blockIdx.x * 1024 + t * 4;
  int add = bsum[blockIdx.x];
#pragma unroll
  for (int j = 0; j < 4; j++) {
    int i = base + j;
    if (i < N_NODES) { int v = row_ptr[i] + add; row_ptr[i] = v; cursor[i] = v; }
  }
  if (blockIdx.x == 0 && t == 0) row_ptr[N_NODES] = N_EDGES;
}

// ---------- scatter: CSR perm + pack edge_attr to bf16 CSR order ----------
__global__ __launch_bounds__(256) void k_scatter(const int* __restrict__ ei,
                                                 int* __restrict__ cursor,
                                                 int* __restrict__ srcs,
                                                 const void* __restrict__ ea,
                                                 const int* __restrict__ flags,
                                                 unsigned short* __restrict__ eap)
{
  int e = blockIdx.x * 256 + threadIdx.x;
  if (e >= N_EDGES) return;
  int d = ei[N_EDGES + e]; if ((unsigned)d >= N_NODES) d = 0;
  int s = ei[e];           if ((unsigned)s >= N_NODES) s = 0;
  int p = atomicAdd(&cursor[d], 1);
  if ((unsigned)p >= N_EDGES) return;
  srcs[p] = s;
  unsigned short* op = eap + (size_t)p * 32;
  if (flags[1]) {
    const float* ip = (const float*)ea + (size_t)e * 32;
#pragma unroll
    for (int q = 0; q < 2; q++) {
      float4 a = *(const float4*)(ip + q * 16);
      float4 b = *(const float4*)(ip + q * 16 + 4);
      float4 c = *(const float4*)(ip + q * 16 + 8);
      float4 dd = *(const float4*)(ip + q * 16 + 12);
      uint4 u0, u1;
      u0.x = (unsigned)f2bf(a.x) | ((unsigned)f2bf(a.y) << 16);
      u0.y = (unsigned)f2bf(a.z) | ((unsigned)f2bf(a.w) << 16);
      u0.z = (unsigned)f2bf(b.x) | ((unsigned)f2bf(b.y) << 16);
      u0.w = (unsigned)f2bf(b.z) | ((unsigned)f2bf(b.w) << 16);
      u1.x = (unsigned)f2bf(c.x) | ((unsigned)f2bf(c.y) << 16);
      u1.y = (unsigned)f2bf(c.z) | ((unsigned)f2bf(c.w) << 16);
      u1.z = (unsigned)f2bf(dd.x) | ((unsigned)f2bf(dd.y) << 16);
      u1.w = (unsigned)f2bf(dd.z) | ((unsigned)f2bf(dd.w) << 16);
      *(uint4*)(op + q * 16) = u0;
      *(uint4*)(op + q * 16 + 8) = u1;
    }
  } else {
    const uint4* ip = (const uint4*)((const unsigned short*)ea + (size_t)e * 32);
#pragma unroll
    for (int q = 0; q < 4; q++) *(uint4*)(op + q * 8) = ip[q];
  }
}

// ---------- layer-1 fused score+aggregate, channel-owner epilogue (r6-best) ----------
__global__ __launch_bounds__(256) void k_fuse1(
    const unsigned short* __restrict__ eap, const int* __restrict__ srcs,
    const int* __restrict__ row_ptr,
    const unsigned int* __restrict__ xlp, const unsigned int* __restrict__ xrp,
    const void* __restrict__ We, const void* __restrict__ att,
    const void* __restrict__ bias, const int* __restrict__ flags,
    float* __restrict__ hout)
{
  __shared__ unsigned short wt[128 * 34];   // WeT[ch][k], stride 34
  __shared__ float at[128];
  int tid = threadIdx.x;
  {
    int f = flags[6];
    for (int i2 = tid; i2 < 4096; i2 += 256) {   // We[k][c] -> wt[c*34+k]
      int k = i2 >> 7, c = i2 & 127;
      wt[c * 34 + k] = f ? f2bf(((const float*)We)[i2]) : ((const unsigned short*)We)[i2];
    }
  }
  if (tid < 128) at[tid] = loadF(att, flags[7], tid);
  __syncthreads();
  int lane = tid & 63;
  int idx16 = lane & 15, quad = lane >> 4;
  int t_s = (lane & 15) >> 1, b_s = lane & 1;
  int un = t_s * 8 + quad * 2 + b_s;     // owned natural uint index in [0,64)
  int hd = un >> 4;                       // head of owned channels
  bf16x8 af[8];
#pragma unroll
  for (int t = 0; t < 8; t++)
    af[t] = *(const bf16x8*)(wt + (t * 16 + idx16) * 34 + quad * 8);
  int wv = tid >> 6;
#pragma unroll 1
  for (int rep = 0; rep < 2; rep++) {
    int i = blockIdx.x * 8 + rep * 4 + wv;
    int p0 = row_ptr[i], p1 = row_ptr[i + 1];
    uint2 rv[8];
#pragma unroll
    for (int t4 = 0; t4 < 4; t4++) {
      uint4 u = *(const uint4*)(xrp + (size_t)i * 64 + quad * 16 + t4 * 4);
      rv[2 * t4]     = make_uint2(u.x, u.y);
      rv[2 * t4 + 1] = make_uint2(u.z, u.w);
    }
    float acc0 = 0.f, acc1 = 0.f, den = 0.f;
    for (int jb = p0; jb < p1; jb += 16) {
      int j = jb + idx16;
      int act = j < p1;
      int jc = act ? j : p0;
      int s = srcs[jc];
      bf16x8 bfrag = *(const bf16x8*)(eap + (size_t)jc * 32 + quad * 8);
      uint2 xv[8];
#pragma unroll
      for (int t4 = 0; t4 < 4; t4++) {
        uint4 u = *(const uint4*)(xlp + (size_t)s * 64 + quad * 16 + t4 * 4);
        xv[2 * t4]     = make_uint2(u.x, u.y);
        xv[2 * t4 + 1] = make_uint2(u.z, u.w);
      }
      float ph0 = 0.f, ph1 = 0.f, ph2 = 0.f, ph3 = 0.f;
#pragma unroll
      for (int t = 0; t < 8; t++) {
        float4 av = *(const float4*)(at + t * 16 + quad * 4);
        uint2 r = rv[t];
        f32x4 c = {0.f, 0.f, 0.f, 0.f};
        c = __builtin_amdgcn_mfma_f32_16x16x32_bf16(af[t], bfrag, c, 0, 0, 0);
        float z0 = c[0] + lo16(xv[t].x) + lo16(r.x);
        float z1 = c[1] + hi16(xv[t].x) + hi16(r.x);
        float z2 = c[2] + lo16(xv[t].y) + lo16(r.y);
        float z3 = c[3] + hi16(xv[t].y) + hi16(r.y);
        z0 = z0 > 0.f ? z0 : 0.2f * z0;
        z1 = z1 > 0.f ? z1 : 0.2f * z1;
        z2 = z2 > 0.f ? z2 : 0.2f * z2;
        z3 = z3 > 0.f ? z3 : 0.2f * z3;
        float pp = fmaf(av.x, z0, fmaf(av.y, z1, fmaf(av.z, z2, av.w * z3)));
        if (t < 2)      ph0 += pp;
        else if (t < 4) ph1 += pp;
        else if (t < 6) ph2 += pp;
        else            ph3 += pp;
      }
      ph0 += __shfl_xor(ph0, 16, 64); ph0 += __shfl_xor(ph0, 32, 64);
      ph1 += __shfl_xor(ph1, 16, 64); ph1 += __shfl_xor(ph1, 32, 64);
      ph2 += __shfl_xor(ph2, 16, 64); ph2 += __shfl_xor(ph2, 32, 64);
      ph3 += __shfl_xor(ph3, 16, 64); ph3 += __shfl_xor(ph3, 32, 64);
      float w0 = act ? __expf(fminf(fin(ph0), 25.f)) : 0.f;
      float w1 = act ? __expf(fminf(fin(ph1), 25.f)) : 0.f;
      float w2 = act ? __expf(fminf(fin(ph2), 25.f)) : 0.f;
      float w3 = act ? __expf(fminf(fin(ph3), 25.f)) : 0.f;
      float wsel = quad == 0 ? w0 : quad == 1 ? w1 : quad == 2 ? w2 : w3;
      int sjl[16];
      float wjv[16];
#pragma unroll
      for (int q = 0; q < 16; q++) sjl[q] = __shfl(s, q, 64);
#pragma unroll
      for (int q = 0; q < 16; q++) wjv[q] = __shfl(wsel, hd * 16 + q, 64);
#pragma unroll
      for (int q = 0; q < 16; q++) {
        unsigned int v = xlp[(size_t)sjl[q] * 64 + lane];   // L1-hot coalesced row
        acc0 = fmaf(wjv[q], lo16(v), acc0);
        acc1 = fmaf(wjv[q], hi16(v), acc1);
        den += wjv[q];
      }
    }
    float inv = 1.f / (den + 1e-16f);
    int fB = flags[8];
    int ch = un * 2;
    float o0 = fin(fmaf(acc0, inv, loadF(bias, fB, ch)));
    float o1 = fin(fmaf(acc1, inv, loadF(bias, fB, ch + 1)));
    o0 = o0 > 0.f ? o0 : __expf(o0) - 1.f;
    o1 = o1 > 0.f ? o1 : __expf(o1) - 1.f;
    *(float2*)(hout + (size_t)i * 128 + ch) = make_float2(o0, o1);
  }
}

// ---------- layer-2 fused score+aggregate (H=1, C=64), channel-owner epilogue (r6-best) ----------
__global__ __launch_bounds__(256) void k_fuse2(
    const unsigned short* __restrict__ eap, const int* __restrict__ srcs,
    const int* __restrict__ row_ptr,
    const unsigned int* __restrict__ xlp, const unsigned int* __restrict__ xrp,
    const void* __restrict__ We, const void* __restrict__ att,
    const void* __restrict__ bias, const int* __restrict__ flags,
    void* __restrict__ out)
{
  __shared__ unsigned short wt[64 * 34];
  __shared__ float at[64];
  int tid = threadIdx.x;
  {
    int f = flags[13];
    for (int i2 = tid; i2 < 2048; i2 += 256) {   // We[k][c] -> wt[c*34+k]
      int k = i2 >> 6, c = i2 & 63;
      wt[c * 34 + k] = f ? f2bf(((const float*)We)[i2]) : ((const unsigned short*)We)[i2];
    }
  }
  if (tid < 64) at[tid] = loadF(att, flags[14], tid);
  __syncthreads();
  int lane = tid & 63;
  int idx16 = lane & 15, quad = lane >> 4;
  int l5 = lane & 31;
  int q_s = l5 >> 3, t2 = (l5 & 7) >> 1, b2 = l5 & 1;
  int un = t2 * 8 + q_s * 2 + b2;        // owned natural uint index in [0,32)
  int halfe = lane >> 5;
  bf16x8 af[4];
#pragma unroll
  for (int t = 0; t < 4; t++)
    af[t] = *(const bf16x8*)(wt + (t * 16 + idx16) * 34 + quad * 8);
  int wv = tid >> 6;
#pragma unroll 1
  for (int rep = 0; rep < 2; rep++) {
    int i = blockIdx.x * 8 + rep * 4 + wv;
    int p0 = row_ptr[i], p1 = row_ptr[i + 1];
    uint2 rv[4];
#pragma unroll
    for (int k = 0; k < 2; k++) {
      uint4 u = *(const uint4*)(xrp + (size_t)i * 32 + quad * 8 + k * 4);
      rv[2 * k]     = make_uint2(u.x, u.y);
      rv[2 * k + 1] = make_uint2(u.z, u.w);
    }
    float acc0 = 0.f, acc1 = 0.f, den = 0.f;
    for (int jb = p0; jb < p1; jb += 16) {
      int j = jb + idx16;
      int act = j < p1;
      int jc = act ? j : p0;
      int s = srcs[jc];
      bf16x8 bfrag = *(const bf16x8*)(eap + (size_t)jc * 32 + quad * 8);
      uint2 xv[4];
#pragma unroll
      for (int k = 0; k < 2; k++) {
        uint4 u = *(const uint4*)(xlp + (size_t)s * 32 + quad * 8 + k * 4);
        xv[2 * k]     = make_uint2(u.x, u.y);
        xv[2 * k + 1] = make_uint2(u.z, u.w);
      }
      float ph = 0.f;
#pragma unroll
      for (int t = 0; t < 4; t++) {
        float4 av = *(const float4*)(at + t * 16 + quad * 4);
        uint2 r = rv[t];
        f32x4 c = {0.f, 0.f, 0.f, 0.f};
        c = __builtin_amdgcn_mfma_f32_16x16x32_bf16(af[t], bfrag, c, 0, 0, 0);
        float z0 = c[0] + lo16(xv[t].x) + lo16(r.x);
        float z1 = c[1] + hi16(xv[t].x) + hi16(r.x);
        float z2 = c[2] + lo16(xv[t].y) + lo16(r.y);
        float z3 = c[3] + hi16(xv[t].y) + hi16(r.y);
        z0 = z0 > 0.f ? z0 : 0.2f * z0;
        z1 = z1 > 0.f ? z1 : 0.2f * z1;
        z2 = z2 > 0.f ? z2 : 0.2f * z2;
        z3 = z3 > 0.f ? z3 : 0.2f * z3;
        ph += fmaf(av.x, z0, fmaf(av.y, z1, fmaf(av.z, z2, av.w * z3)));
      }
      ph += __shfl_xor(ph, 16, 64);
      ph += __shfl_xor(ph, 32, 64);
      float wsel = act ? __expf(fminf(fin(ph), 25.f)) : 0.f;
      int sjl[8];
      float wjv[8];
#pragma unroll
      for (int q = 0; q < 8; q++) {
        int qq = 2 * q + halfe;
        sjl[q] = __shfl(s, qq, 64);
        wjv[q] = __shfl(wsel, qq, 64);
      }
#pragma unroll
      for (int q = 0; q < 8; q++) {
        unsigned int v = xlp[(size_t)sjl[q] * 32 + l5];   // L1-hot coalesced row
        acc0 = fmaf(wjv[q], lo16(v), acc0);
        acc1 = fmaf(wjv[q], hi16(v), acc1);
        den += wjv[q];
      }
    }
    acc0 += __shfl_xor(acc0, 32, 64);
    acc1 += __shfl_xor(acc1, 32, 64);
    den  += __shfl_xor(den, 32, 64);
    if (lane < 32) {
      float inv = 1.f / (den + 1e-16f);
      int fB = flags[15];
      int ch = un * 2;
      float o0 = fin(fmaf(acc0, inv, loadF(bias, fB, ch)));
      float o1 = fin(fmaf(acc1, inv, loadF(bias, fB, ch + 1)));
      if (flags[0]) {
        *(float2*)((float*)out + (size_t)i * 64 + ch) = make_float2(o0, o1);
      } else {
        unsigned int u = (unsigned)f2bf(o0) | ((unsigned)f2bf(o1) << 16);
        *(unsigned int*)((unsigned short*)out + (size_t)i * 64 + ch) = u;
      }
    }
  }
}

extern "C" void kernel_launch(void* const* d_in, const int* in_sizes, int n_in,
                              void* d_out, int out_size, void* d_ws, size_t ws_size,
                              hipStream_t stream)
{
  (void)n_in; (void)out_size; (void)ws_size;
  const void* x    = d_in[0];
  const int*  ei   = (const int*)d_in[1];
  const void* ea   = d_in[2];
  const void* Wl1  = d_in[3];
  const void* bl1  = d_in[4];
  const void* Wr1  = d_in[5];
  const void* br1  = d_in[6];
  const void* We1  = d_in[7];
  const void* att1 = d_in[8];
  const void* bias1= d_in[9];
  const void* Wl2  = d_in[10];
  const void* bl2  = d_in[11];
  const void* Wr2  = d_in[12];
  const void* br2  = d_in[13];
  const void* We2  = d_in[14];
  const void* att2 = d_in[15];
  const void* bias2= d_in[16];

  char* ws = (char*)d_ws;
  size_t off = 0;
  auto take = [&](size_t bytes) -> char* {
    char* p = ws + off;
    off += (bytes + 255) & ~(size_t)255;
    return p;
  };
  unsigned int* xl1p = (unsigned int*)take((size_t)N_NODES * 64 * 4);   // 12.8 MB
  unsigned int* xr1p = (unsigned int*)take((size_t)N_NODES * 64 * 4);   // 12.8 MB
  float* hbuf   = (float*)take((size_t)N_NODES * 128 * 4);              // 25.6 MB
  unsigned short* eap = (unsigned short*)take((size_t)(N_EDGES + 16) * 32 * 2); // 51.2 MB
  int*   counts = (int*)  take((size_t)N_NODES * 4);
  int*   row_ptr= (int*)  take((size_t)(N_NODES + 1) * 4);
  int*   cursor = (int*)  take((size_t)N_NODES * 4);
  int*   srcs   = (int*)  take((size_t)(N_EDGES + 16) * 4);
  int*   bsum   = (int*)  take(64 * 4);
  int*   flags  = (int*)  take(64 * 4);
  unsigned int* xl2p = xl1p;      // layer-2 reuses ([N,32] <= [N,64])
  unsigned int* xr2p = xr1p;

  Ptrs tl;
  const int map[16] = {0, 2, 3, 4, 5, 6, 7, 8, 9, 10, 11, 12, 13, 14, 15, 16};
  for (int j = 0; j < 16; j++) { tl.p[j] = d_in[map[j]]; tl.n[j] = in_sizes[map[j]]; }

  int nb = (N_NODES + 1023) / 1024;
  int zblocks = (N_NODES + 255) / 256;
  k_detect<<<16 + zblocks, 256, 0, stream>>>(tl, flags, counts, srcs + N_EDGES);
  k_gemm1<<<dim3((N_NODES + 31) / 32, 2), 256, 0, stream>>>(x, Wl1, bl1, Wr1, br1, flags, xl1p, xr1p);
  k_hist<<<(N_EDGES + 255) / 256, 256, 0, stream>>>(ei, counts);
  k_scan1<<<nb, 256, 0, stream>>>(counts, row_ptr, bsum);
  k_scan2<<<1, 64, 0, stream>>>(bsum, nb);
  k_scan3<<<nb, 256, 0, stream>>>(row_ptr, cursor, bsum);
  k_scatter<<<(N_EDGES + 255) / 256, 256, 0, stream>>>(ei, cursor, srcs, ea, flags, eap);
  k_fuse1<<<N_NODES / 8, 256, 0, stream>>>(eap, srcs, row_ptr, xl1p, xr1p, We1, att1, bias1, flags, hbuf);
  k_gemm2<<<dim3((N_NODES + 31) / 32, 2), 256, 0, stream>>>(hbuf, Wl2, bl2, Wr2, br2, flags, xl2p, xr2p);
  k_fuse2<<<N_NODES / 8, 256, 0, stream>>>(eap, srcs, row_ptr, xl2p, xr2p, We2, att2, bias2, flags, d_out);
}

// Round 9
// 640.727 us; speedup vs baseline: 1.6293x; 1.0265x over previous
//
#include <hip/hip_runtime.h>
#include <stdint.h>

#define N_NODES 50000
#define N_EDGES 800000

// flag indices: 0:x 1:ea 2:Wl1 3:bl1 4:Wr1 5:br1 6:We1 7:att1 8:bias1
//               9:Wl2 10:bl2 11:Wr2 12:br2 13:We2 14:att2 15:bias2
struct Ptrs { const void* p[16]; int n[16]; };

typedef __attribute__((ext_vector_type(8))) short bf16x8;
typedef __attribute__((ext_vector_type(4))) float f32x4;

__device__ __forceinline__ float bf2f(unsigned short u){
  union { unsigned int i; float f; } v; v.i = ((unsigned int)u) << 16; return v.f;
}
__device__ __forceinline__ float lo16(unsigned int u){ union { unsigned int i; float f; } v; v.i = u << 16; return v.f; }
__device__ __forceinline__ float hi16(unsigned int u){ union { unsigned int i; float f; } v; v.i = u & 0xffff0000u; return v.f; }
__device__ __forceinline__ unsigned short f2bf(float f){
  if (!(f == f)) return 0;
  unsigned int x = __float_as_uint(f);
  unsigned int r = (x + 0x7fffu + ((x >> 16) & 1u)) >> 16;
  return (unsigned short)r;
}
__device__ __forceinline__ float fin(float v){
  if (!(v == v)) return 0.f;
  return fminf(fmaxf(v, -1e30f), 1e30f);
}
__device__ __forceinline__ float loadF(const void* p, int f32, size_t idx){
  return f32 ? ((const float*)p)[idx] : bf2f(((const unsigned short*)p)[idx]);
}

// ---------- dtype detect + zero (merged) ----------
__global__ __launch_bounds__(256) void k_detect(Ptrs tl, int* __restrict__ flags,
                                                int* __restrict__ counts, int* __restrict__ pad16)
{
  if (blockIdx.x >= 16) {
    int i = (blockIdx.x - 16) * 256 + threadIdx.x;
    if (i < N_NODES) counts[i] = 0;
    if (blockIdx.x == 16 && threadIdx.x < 16) pad16[threadIdx.x] = 0;
    return;
  }
  __shared__ int red[256];
  int b = blockIdx.x, t = threadIdx.x;
  const unsigned short* p = (const unsigned short*)tl.p[b];
  int n = tl.n[b]; if (n > 16384) n = 16384;
  int crazy = 0;
  for (int i = t; i < n; i += 256) {
    unsigned short u = p[i];
    if (u) {
      int ex = (u >> 7) & 0xFF;
      if (ex == 0xFF || ex < 0x60) crazy++;
    }
  }
  red[t] = crazy; __syncthreads();
  for (int off = 128; off; off >>= 1) { if (t < off) red[t] += red[t + off]; __syncthreads(); }
  if (t == 0) flags[b] = (red[0] * 10 > n) ? 1 : 0;
}

// ---------- layer-1 GEMM (MFMA, hi/lo bf16 split) ----------
__global__ __launch_bounds__(256) void k_gemm1(
    const void* __restrict__ x,
    const void* __restrict__ Wl, const void* __restrict__ bl,
    const void* __restrict__ Wr, const void* __restrict__ br,
    const int* __restrict__ flags,
    unsigned int* __restrict__ xlp, unsigned int* __restrict__ xrp)
{
  __shared__ __align__(16) char smem[17408];
  unsigned short* xh  = (unsigned short*)smem;            // [32][136] bf16 hi
  unsigned short* xlo = (unsigned short*)(smem + 8704);   // [32][136] bf16 lo residual
  float* outb = (float*)smem;                             // [32][132] f32 (alias, after sync)
  const void* W  = blockIdx.y ? Wr : Wl;
  const void* bb = blockIdx.y ? br : bl;
  int fW = blockIdx.y ? flags[4] : flags[2];
  int fB = blockIdx.y ? flags[5] : flags[3];
  int fX = flags[0];
  unsigned int* outp = blockIdx.y ? xrp : xlp;
  int tid = threadIdx.x;
  int row0 = blockIdx.x * 32;
  for (int i = tid * 4; i < 32 * 128; i += 1024) {
    int r = i >> 7, k = i & 127;
    int row = row0 + r;
    float4 v = make_float4(0.f, 0.f, 0.f, 0.f);
    if (row < N_NODES) {
      if (fX) v = *(const float4*)((const float*)x + (size_t)row * 128 + k);
      else {
        uint2 u = *(const uint2*)((const unsigned short*)x + (size_t)row * 128 + k);
        v.x = lo16(u.x); v.y = hi16(u.x); v.z = lo16(u.y); v.w = hi16(u.y);
      }
    }
    unsigned short h0 = f2bf(v.x), h1 = f2bf(v.y), h2 = f2bf(v.z), h3 = f2bf(v.w);
    *(ushort4*)(xh + r * 136 + k) = make_ushort4(h0, h1, h2, h3);
    ushort4 lv;
    lv.x = f2bf(v.x - bf2f(h0)); lv.y = f2bf(v.y - bf2f(h1));
    lv.z = f2bf(v.z - bf2f(h2)); lv.w = f2bf(v.w - bf2f(h3));
    *(ushort4*)(xlo + r * 136 + k) = lv;
  }
  int lane = tid & 63, wv = tid >> 6;
  int idx16 = lane & 15, quad = lane >> 4;
  bf16x8 bfr[2][4];
#pragma unroll
  for (int ct = 0; ct < 2; ct++) {
#pragma unroll
    for (int kc = 0; kc < 4; kc++) {
      int col = wv * 32 + ct * 16 + idx16;
      unsigned short tmp[8];
#pragma unroll
      for (int j = 0; j < 8; j++) {
        int kk = kc * 32 + quad * 8 + j;
        tmp[j] = fW ? f2bf(((const float*)W)[(size_t)kk * 128 + col])
                    : ((const unsigned short*)W)[(size_t)kk * 128 + col];
      }
      bfr[ct][kc] = *(const bf16x8*)tmp;
    }
  }
  __syncthreads();
  f32x4 acc[2][2];
#pragma unroll
  for (int rt = 0; rt < 2; rt++)
#pragma unroll
    for (int ct = 0; ct < 2; ct++)
      acc[rt][ct] = (f32x4){0.f, 0.f, 0.f, 0.f};
#pragma unroll
  for (int kc = 0; kc < 4; kc++) {
#pragma unroll
    for (int rt = 0; rt < 2; rt++) {
      bf16x8 ah = *(const bf16x8*)(xh  + (rt * 16 + idx16) * 136 + kc * 32 + quad * 8);
      bf16x8 al = *(const bf16x8*)(xlo + (rt * 16 + idx16) * 136 + kc * 32 + quad * 8);
#pragma unroll
      for (int ct = 0; ct < 2; ct++) {
        acc[rt][ct] = __builtin_amdgcn_mfma_f32_16x16x32_bf16(ah, bfr[ct][kc], acc[rt][ct], 0, 0, 0);
        acc[rt][ct] = __builtin_amdgcn_mfma_f32_16x16x32_bf16(al, bfr[ct][kc], acc[rt][ct], 0, 0, 0);
      }
    }
  }
  __syncthreads();
#pragma unroll
  for (int rt = 0; rt < 2; rt++)
#pragma unroll
    for (int ct = 0; ct < 2; ct++)
#pragma unroll
      for (int r = 0; r < 4; r++)
        outb[(rt * 16 + quad * 4 + r) * 132 + wv * 32 + ct * 16 + idx16] = acc[rt][ct][r];
  __syncthreads();
  int r = tid >> 3, cg = tid & 7;
  float a2[16];
#pragma unroll
  for (int j = 0; j < 8; j++) {
    a2[j]     = outb[r * 132 + cg * 8 + j];
    a2[8 + j] = outb[r * 132 + 64 + cg * 8 + j];
  }
  int row = row0 + r;
  if (row < N_NODES) {
    unsigned int* op = outp + (size_t)row * 64;
    int tt = cg >> 1, qb = (cg & 1) * 2;
    unsigned int ou[4];
#pragma unroll
    for (int t = 0; t < 4; t++) {
      float f0 = fin(a2[2 * t]     + loadF(bb, fB, cg * 8 + 2 * t));
      float f1 = fin(a2[2 * t + 1] + loadF(bb, fB, cg * 8 + 2 * t + 1));
      ou[t] = (unsigned)f2bf(f0) | ((unsigned)f2bf(f1) << 16);
    }
    *(uint2*)(op + qb * 16 + tt * 2)       = make_uint2(ou[0], ou[1]);
    *(uint2*)(op + (qb + 1) * 16 + tt * 2) = make_uint2(ou[2], ou[3]);
#pragma unroll
    for (int t = 0; t < 4; t++) {
      float f0 = fin(a2[8 + 2 * t]     + loadF(bb, fB, 64 + cg * 8 + 2 * t));
      float f1 = fin(a2[8 + 2 * t + 1] + loadF(bb, fB, 64 + cg * 8 + 2 * t + 1));
      ou[t] = (unsigned)f2bf(f0) | ((unsigned)f2bf(f1) << 16);
    }
    *(uint2*)(op + qb * 16 + 8 + tt * 2)       = make_uint2(ou[0], ou[1]);
    *(uint2*)(op + (qb + 1) * 16 + 8 + tt * 2) = make_uint2(ou[2], ou[3]);
  }
}

// ---------- layer-2 GEMM (MFMA, hi/lo) ----------
__global__ __launch_bounds__(256) void k_gemm2(
    const float* __restrict__ h,
    const void* __restrict__ Wl, const void* __restrict__ bl,
    const void* __restrict__ Wr, const void* __restrict__ br,
    const int* __restrict__ flags,
    unsigned int* __restrict__ xlp, unsigned int* __restrict__ xrp)
{
  __shared__ __align__(16) char smem[17408];
  unsigned short* hh  = (unsigned short*)smem;            // [32][136]
  unsigned short* hlo = (unsigned short*)(smem + 8704);   // [32][136]
  float* outb = (float*)smem;                             // [32][68] f32 (alias)
  const void* W  = blockIdx.y ? Wr : Wl;
  const void* bb = blockIdx.y ? br : bl;
  int fW = blockIdx.y ? flags[11] : flags[9];
  int fB = blockIdx.y ? flags[12] : flags[10];
  unsigned int* outp = blockIdx.y ? xrp : xlp;
  int tid = threadIdx.x;
  int row0 = blockIdx.x * 32;
  for (int i = tid * 4; i < 32 * 128; i += 1024) {
    int r = i >> 7, k = i & 127;
    int row = row0 + r;
    float4 v = make_float4(0.f, 0.f, 0.f, 0.f);
    if (row < N_NODES) v = *(const float4*)(h + (size_t)row * 128 + k);
    unsigned short h0 = f2bf(v.x), h1 = f2bf(v.y), h2 = f2bf(v.z), h3 = f2bf(v.w);
    *(ushort4*)(hh + r * 136 + k) = make_ushort4(h0, h1, h2, h3);
    ushort4 lv;
    lv.x = f2bf(v.x - bf2f(h0)); lv.y = f2bf(v.y - bf2f(h1));
    lv.z = f2bf(v.z - bf2f(h2)); lv.w = f2bf(v.w - bf2f(h3));
    *(ushort4*)(hlo + r * 136 + k) = lv;
  }
  int lane = tid & 63, wv = tid >> 6;
  int idx16 = lane & 15, quad = lane >> 4;
  bf16x8 bfr[4];
#pragma unroll
  for (int kc = 0; kc < 4; kc++) {
    int col = wv * 16 + idx16;
    unsigned short tmp[8];
#pragma unroll
    for (int j = 0; j < 8; j++) {
      int kk = kc * 32 + quad * 8 + j;
      tmp[j] = fW ? f2bf(((const float*)W)[(size_t)kk * 64 + col])
                  : ((const unsigned short*)W)[(size_t)kk * 64 + col];
    }
    bfr[kc] = *(const bf16x8*)tmp;
  }
  __syncthreads();
  f32x4 acc[2];
  acc[0] = (f32x4){0.f, 0.f, 0.f, 0.f};
  acc[1] = (f32x4){0.f, 0.f, 0.f, 0.f};
#pragma unroll
  for (int kc = 0; kc < 4; kc++) {
#pragma unroll
    for (int rt = 0; rt < 2; rt++) {
      bf16x8 ah = *(const bf16x8*)(hh  + (rt * 16 + idx16) * 136 + kc * 32 + quad * 8);
      bf16x8 al = *(const bf16x8*)(hlo + (rt * 16 + idx16) * 136 + kc * 32 + quad * 8);
      acc[rt] = __builtin_amdgcn_mfma_f32_16x16x32_bf16(ah, bfr[kc], acc[rt], 0, 0, 0);
      acc[rt] = __builtin_amdgcn_mfma_f32_16x16x32_bf16(al, bfr[kc], acc[rt], 0, 0, 0);
    }
  }
  __syncthreads();
#pragma unroll
  for (int rt = 0; rt < 2; rt++)
#pragma unroll
    for (int r = 0; r < 4; r++)
      outb[(rt * 16 + quad * 4 + r) * 68 + wv * 16 + idx16] = acc[rt][r];
  __syncthreads();
  int r = tid >> 3, cg = tid & 7;
  float a2[8];
#pragma unroll
  for (int j = 0; j < 8; j++) a2[j] = outb[r * 68 + cg * 8 + j];
  int row = row0 + r;
  if (row < N_NODES) {
    unsigned int* op = outp + (size_t)row * 32;
    int tt = cg >> 1, qb = (cg & 1) * 2;
    unsigned int ou[4];
#pragma unroll
    for (int t = 0; t < 4; t++) {
      float f0 = fin(a2[2 * t]     + loadF(bb, fB, cg * 8 + 2 * t));
      float f1 = fin(a2[2 * t + 1] + loadF(bb, fB, cg * 8 + 2 * t + 1));
      ou[t] = (unsigned)f2bf(f0) | ((unsigned)f2bf(f1) << 16);
    }
    *(uint2*)(op + qb * 8 + tt * 2)       = make_uint2(ou[0], ou[1]);
    *(uint2*)(op + (qb + 1) * 8 + tt * 2) = make_uint2(ou[2], ou[3]);
  }
}

// ---------- CSR build ----------
__global__ __launch_bounds__(256) void k_hist(const int* __restrict__ ei, int* __restrict__ counts)
{
  int e = blockIdx.x * 256 + threadIdx.x;
  if (e < N_EDGES) {
    int d = ei[N_EDGES + e]; if ((unsigned)d >= N_NODES) d = 0;
    atomicAdd(&counts[d], 1);
  }
}

__global__ __launch_bounds__(256) void k_scan1(const int* __restrict__ counts,
                                               int* __restrict__ row_ptr, int* __restrict__ bsum)
{
  __shared__ int lds[256];
  int t = threadIdx.x;
  int base = blockIdx.x * 1024 + t * 4;
  int c0 = (base + 0) < N_NODES ? counts[base + 0] : 0;
  int c1 = (base + 1) < N_NODES ? counts[base + 1] : 0;
  int c2 = (base + 2) < N_NODES ? counts[base + 2] : 0;
  int c3 = (base + 3) < N_NODES ? counts[base + 3] : 0;
  int s = c0 + c1 + c2 + c3;
  lds[t] = s; __syncthreads();
  for (int off = 1; off < 256; off <<= 1) {
    int v = (t >= off) ? lds[t - off] : 0;
    __syncthreads();
    lds[t] += v;
    __syncthreads();
  }
  int incl = lds[t];
  int excl = incl - s;
  if (base + 0 < N_NODES) row_ptr[base + 0] = excl;
  if (base + 1 < N_NODES) row_ptr[base + 1] = excl + c0;
  if (base + 2 < N_NODES) row_ptr[base + 2] = excl + c0 + c1;
  if (base + 3 < N_NODES) row_ptr[base + 3] = excl + c0 + c1 + c2;
  if (t == 255) bsum[blockIdx.x] = incl;
}

// scan2+scan3 merged: each block wave-reduces its bsum prefix (nb<=64)
__global__ __launch_bounds__(256) void k_scan23(int* __restrict__ row_ptr, int* __restrict__ cursor,
                                                const int* __restrict__ bsum, int nb)
{
  __shared__ int sadd;
  int t = threadIdx.x;
  if (t < 64) {
    int v = (t < nb && t < (int)blockIdx.x) ? bsum[t] : 0;
    v += __shfl_xor(v, 1, 64);  v += __shfl_xor(v, 2, 64);
    v += __shfl_xor(v, 4, 64);  v += __shfl_xor(v, 8, 64);
    v += __shfl_xor(v, 16, 64); v += __shfl_xor(v, 32, 64);
    if (t == 0) sadd = v;
  }
  __syncthreads();
  int add = sadd;
  int base = blockIdx.x * 1024 + t * 4;
#pragma unroll
  for (int j = 0; j < 4; j++) {
    int i = base + j;
    if (i < N_NODES) { int v = row_ptr[i] + add; row_ptr[i] = v; cursor[i] = v; }
  }
  if (blockIdx.x == 0 && t == 0) row_ptr[N_NODES] = N_EDGES;
}

// ---------- scatter: CSR perm + pack edge_attr to bf16 CSR order ----------
__global__ __launch_bounds__(256) void k_scatter(const int* __restrict__ ei,
                                                 int* __restrict__ cursor,
                                                 int* __restrict__ srcs,
                                                 const void* __restrict__ ea,
                                                 const int* __restrict__ flags,
                                                 unsigned short* __restrict__ eap)
{
  int e = blockIdx.x * 256 + threadIdx.x;
  if (e >= N_EDGES) return;
  int d = ei[N_EDGES + e]; if ((unsigned)d >= N_NODES) d = 0;
  int s = ei[e];           if ((unsigned)s >= N_NODES) s = 0;
  int p = atomicAdd(&cursor[d], 1);
  if ((unsigned)p >= N_EDGES) return;
  srcs[p] = s;
  unsigned short* op = eap + (size_t)p * 32;
  if (flags[1]) {
    const float* ip = (const float*)ea + (size_t)e * 32;
#pragma unroll
    for (int q = 0; q < 2; q++) {
      float4 a = *(const float4*)(ip + q * 16);
      float4 b = *(const float4*)(ip + q * 16 + 4);
      float4 c = *(const float4*)(ip + q * 16 + 8);
      float4 dd = *(const float4*)(ip + q * 16 + 12);
      uint4 u0, u1;
      u0.x = (unsigned)f2bf(a.x) | ((unsigned)f2bf(a.y) << 16);
      u0.y = (unsigned)f2bf(a.z) | ((unsigned)f2bf(a.w) << 16);
      u0.z = (unsigned)f2bf(b.x) | ((unsigned)f2bf(b.y) << 16);
      u0.w = (unsigned)f2bf(b.z) | ((unsigned)f2bf(b.w) << 16);
      u1.x = (unsigned)f2bf(c.x) | ((unsigned)f2bf(c.y) << 16);
      u1.y = (unsigned)f2bf(c.z) | ((unsigned)f2bf(c.w) << 16);
      u1.z = (unsigned)f2bf(dd.x) | ((unsigned)f2bf(dd.y) << 16);
      u1.w = (unsigned)f2bf(dd.z) | ((unsigned)f2bf(dd.w) << 16);
      *(uint4*)(op + q * 16) = u0;
      *(uint4*)(op + q * 16 + 8) = u1;
    }
  } else {
    const uint4* ip = (const uint4*)((const unsigned short*)ea + (size_t)e * 32);
#pragma unroll
    for (int q = 0; q < 4; q++) *(uint4*)(op + q * 8) = ip[q];
  }
}

// ---------- layer-1 fused score+aggregate: prefetched agg rows ----------
// Per chunk: sjl shfls + ALL 16 agg row loads issue BEFORE the MFMA/logit
// phase (they depend only on srcs) -> HBM/L2 latency hides under compute.
// xr rows staged in LDS (frees rv's 16 VGPRs to pay for vq[16]).
__global__ __launch_bounds__(256) void k_fuse1(
    const unsigned short* __restrict__ eap, const int* __restrict__ srcs,
    const int* __restrict__ row_ptr,
    const unsigned int* __restrict__ xlp, const unsigned int* __restrict__ xrp,
    const void* __restrict__ We, const void* __restrict__ att,
    const void* __restrict__ bias, const int* __restrict__ flags,
    float* __restrict__ hout)
{
  __shared__ unsigned short wt[128 * 34];   // WeT[ch][k], stride 34
  __shared__ float at[128];
  __shared__ __align__(16) unsigned int xr_s[8 * 64];   // block's 8 xr rows
  int tid = threadIdx.x;
  {
    int f = flags[6];
    for (int i2 = tid; i2 < 4096; i2 += 256) {   // We[k][c] -> wt[c*34+k]
      int k = i2 >> 7, c = i2 & 127;
      wt[c * 34 + k] = f ? f2bf(((const float*)We)[i2]) : ((const unsigned short*)We)[i2];
    }
  }
  if (tid < 128) at[tid] = loadF(att, flags[7], tid);
  for (int i2 = tid; i2 < 512; i2 += 256)
    xr_s[i2] = xrp[(size_t)(blockIdx.x * 8 + (i2 >> 6)) * 64 + (i2 & 63)];
  __syncthreads();
  int lane = tid & 63;
  int idx16 = lane & 15, quad = lane >> 4;
  int t_s = (lane & 15) >> 1, b_s = lane & 1;
  int un = t_s * 8 + quad * 2 + b_s;     // owned natural uint index in [0,64)
  int hd = un >> 4;                       // head of owned channels
  bf16x8 af[8];
#pragma unroll
  for (int t = 0; t < 8; t++)
    af[t] = *(const bf16x8*)(wt + (t * 16 + idx16) * 34 + quad * 8);
  int wv = tid >> 6;
#pragma unroll 1
  for (int rep = 0; rep < 2; rep++) {
    int loc = rep * 4 + wv;
    int i = blockIdx.x * 8 + loc;
    int p0 = row_ptr[i], p1 = row_ptr[i + 1];
    const unsigned int* xr_row = xr_s + loc * 64;
    float acc0 = 0.f, acc1 = 0.f, den = 0.f;
    for (int jb = p0; jb < p1; jb += 16) {
      int j = jb + idx16;
      int act = j < p1;
      int jc = act ? j : p0;
      int s = srcs[jc];
      // --- w-independent loads first: frag gather + agg row prefetch ---
      bf16x8 bfrag = *(const bf16x8*)(eap + (size_t)jc * 32 + quad * 8);
      uint2 xv[8];
#pragma unroll
      for (int t4 = 0; t4 < 4; t4++) {
        uint4 u = *(const uint4*)(xlp + (size_t)s * 64 + quad * 16 + t4 * 4);
        xv[2 * t4]     = make_uint2(u.x, u.y);
        xv[2 * t4 + 1] = make_uint2(u.z, u.w);
      }
      int sjl[16];
#pragma unroll
      for (int q = 0; q < 16; q++) sjl[q] = __shfl(s, q, 64);
      unsigned int vq[16];
#pragma unroll
      for (int q = 0; q < 16; q++) vq[q] = xlp[(size_t)sjl[q] * 64 + lane];
      // --- logits (MFMA + leaky + dot) ---
      float ph0 = 0.f, ph1 = 0.f, ph2 = 0.f, ph3 = 0.f;
#pragma unroll
      for (int t = 0; t < 8; t++) {
        float4 av = *(const float4*)(at + t * 16 + quad * 4);
        uint2 r = *(const uint2*)(xr_row + quad * 16 + t * 2);
        f32x4 c = {0.f, 0.f, 0.f, 0.f};
        c = __builtin_amdgcn_mfma_f32_16x16x32_bf16(af[t], bfrag, c, 0, 0, 0);
        float z0 = c[0] + lo16(xv[t].x) + lo16(r.x);
        float z1 = c[1] + hi16(xv[t].x) + hi16(r.x);
        float z2 = c[2] + lo16(xv[t].y) + lo16(r.y);
        float z3 = c[3] + hi16(xv[t].y) + hi16(r.y);
        z0 = z0 > 0.f ? z0 : 0.2f * z0;
        z1 = z1 > 0.f ? z1 : 0.2f * z1;
        z2 = z2 > 0.f ? z2 : 0.2f * z2;
        z3 = z3 > 0.f ? z3 : 0.2f * z3;
        float pp = fmaf(av.x, z0, fmaf(av.y, z1, fmaf(av.z, z2, av.w * z3)));
        if (t < 2)      ph0 += pp;
        else if (t < 4) ph1 += pp;
        else if (t < 6) ph2 += pp;
        else            ph3 += pp;
      }
      ph0 += __shfl_xor(ph0, 16, 64); ph0 += __shfl_xor(ph0, 32, 64);
      ph1 += __shfl_xor(ph1, 16, 64); ph1 += __shfl_xor(ph1, 32, 64);
      ph2 += __shfl_xor(ph2, 16, 64); ph2 += __shfl_xor(ph2, 32, 64);
      ph3 += __shfl_xor(ph3, 16, 64); ph3 += __shfl_xor(ph3, 32, 64);
      float w0 = act ? __expf(fminf(fin(ph0), 25.f)) : 0.f;
      float w1 = act ? __expf(fminf(fin(ph1), 25.f)) : 0.f;
      float w2 = act ? __expf(fminf(fin(ph2), 25.f)) : 0.f;
      float w3 = act ? __expf(fminf(fin(ph3), 25.f)) : 0.f;
      float wsel = quad == 0 ? w0 : quad == 1 ? w1 : quad == 2 ? w2 : w3;
#pragma unroll
      for (int q = 0; q < 16; q++) {
        float wq = __shfl(wsel, hd * 16 + q, 64);
        acc0 = fmaf(wq, lo16(vq[q]), acc0);
        acc1 = fmaf(wq, hi16(vq[q]), acc1);
        den += wq;
      }
    }
    float inv = 1.f / (den + 1e-16f);
    int fB = flags[8];
    int ch = un * 2;
    float o0 = fin(fmaf(acc0, inv, loadF(bias, fB, ch)));
    float o1 = fin(fmaf(acc1, inv, loadF(bias, fB, ch + 1)));
    o0 = o0 > 0.f ? o0 : __expf(o0) - 1.f;
    o1 = o1 > 0.f ? o1 : __expf(o1) - 1.f;
    *(float2*)(hout + (size_t)i * 128 + ch) = make_float2(o0, o1);
  }
}

// ---------- layer-2 fused score+aggregate (H=1, C=64): prefetched agg rows ----------
__global__ __launch_bounds__(256) void k_fuse2(
    const unsigned short* __restrict__ eap, const int* __restrict__ srcs,
    const int* __restrict__ row_ptr,
    const unsigned int* __restrict__ xlp, const unsigned int* __restrict__ xrp,
    const void* __restrict__ We, const void* __restrict__ att,
    const void* __restrict__ bias, const int* __restrict__ flags,
    void* __restrict__ out)
{
  __shared__ unsigned short wt[64 * 34];
  __shared__ float at[64];
  __shared__ __align__(16) unsigned int xr_s[8 * 32];
  int tid = threadIdx.x;
  {
    int f = flags[13];
    for (int i2 = tid; i2 < 2048; i2 += 256) {   // We[k][c] -> wt[c*34+k]
      int k = i2 >> 6, c = i2 & 63;
      wt[c * 34 + k] = f ? f2bf(((const float*)We)[i2]) : ((const unsigned short*)We)[i2];
    }
  }
  if (tid < 64) at[tid] = loadF(att, flags[14], tid);
  if (tid < 256) {
    int i2 = tid;
    if (i2 < 256) xr_s[i2] = xrp[(size_t)(blockIdx.x * 8 + (i2 >> 5)) * 32 + (i2 & 31)];
  }
  __syncthreads();
  int lane = tid & 63;
  int idx16 = lane & 15, quad = lane >> 4;
  int l5 = lane & 31;
  int q_s = l5 >> 3, t2 = (l5 & 7) >> 1, b2 = l5 & 1;
  int un = t2 * 8 + q_s * 2 + b2;        // owned natural uint index in [0,32)
  int halfe = lane >> 5;
  bf16x8 af[4];
#pragma unroll
  for (int t = 0; t < 4; t++)
    af[t] = *(const bf16x8*)(wt + (t * 16 + idx16) * 34 + quad * 8);
  int wv = tid >> 6;
#pragma unroll 1
  for (int rep = 0; rep < 2; rep++) {
    int loc = rep * 4 + wv;
    int i = blockIdx.x * 8 + loc;
    int p0 = row_ptr[i], p1 = row_ptr[i + 1];
    const unsigned int* xr_row = xr_s + loc * 32;
    float acc0 = 0.f, acc1 = 0.f, den = 0.f;
    for (int jb = p0; jb < p1; jb += 16) {
      int j = jb + idx16;
      int act = j < p1;
      int jc = act ? j : p0;
      int s = srcs[jc];
      bf16x8 bfrag = *(const bf16x8*)(eap + (size_t)jc * 32 + quad * 8);
      uint2 xv[4];
#pragma unroll
      for (int k = 0; k < 2; k++) {
        uint4 u = *(const uint4*)(xlp + (size_t)s * 32 + quad * 8 + k * 4);
        xv[2 * k]     = make_uint2(u.x, u.y);
        xv[2 * k + 1] = make_uint2(u.z, u.w);
      }
      int sjl[8];
#pragma unroll
      for (int q = 0; q < 8; q++) sjl[q] = __shfl(s, 2 * q + halfe, 64);
      unsigned int vq[8];
#pragma unroll
      for (int q = 0; q < 8; q++) vq[q] = xlp[(size_t)sjl[q] * 32 + l5];
      float ph = 0.f;
#pragma unroll
      for (int t = 0; t < 4; t++) {
        float4 av = *(const float4*)(at + t * 16 + quad * 4);
        uint2 r = *(const uint2*)(xr_row + quad * 8 + t * 2);
        f32x4 c = {0.f, 0.f, 0.f, 0.f};
        c = __builtin_amdgcn_mfma_f32_16x16x32_bf16(af[t], bfrag, c, 0, 0, 0);
        float z0 = c[0] + lo16(xv[t].x) + lo16(r.x);
        float z1 = c[1] + hi16(xv[t].x) + hi16(r.x);
        float z2 = c[2] + lo16(xv[t].y) + lo16(r.y);
        float z3 = c[3] + hi16(xv[t].y) + hi16(r.y);
        z0 = z0 > 0.f ? z0 : 0.2f * z0;
        z1 = z1 > 0.f ? z1 : 0.2f * z1;
        z2 = z2 > 0.f ? z2 : 0.2f * z2;
        z3 = z3 > 0.f ? z3 : 0.2f * z3;
        ph += fmaf(av.x, z0, fmaf(av.y, z1, fmaf(av.z, z2, av.w * z3)));
      }
      ph += __shfl_xor(ph, 16, 64);
      ph += __shfl_xor(ph, 32, 64);
      float wsel = act ? __expf(fminf(fin(ph), 25.f)) : 0.f;
#pragma unroll
      for (int q = 0; q < 8; q++) {
        float wq = __shfl(wsel, 2 * q + halfe, 64);
        acc0 = fmaf(wq, lo16(vq[q]), acc0);
        acc1 = fmaf(wq, hi16(vq[q]), acc1);
        den += wq;
      }
    }
    acc0 += __shfl_xor(acc0, 32, 64);
    acc1 += __shfl_xor(acc1, 32, 64);
    den  += __shfl_xor(den, 32, 64);
    if (lane < 32) {
      float inv = 1.f / (den + 1e-16f);
      int fB = flags[15];
      int ch = un * 2;
      float o0 = fin(fmaf(acc0, inv, loadF(bias, fB, ch)));
      float o1 = fin(fmaf(acc1, inv, loadF(bias, fB, ch + 1)));
      if (flags[0]) {
        *(float2*)((float*)out + (size_t)i * 64 + ch) = make_float2(o0, o1);
      } else {
        unsigned int u = (unsigned)f2bf(o0) | ((unsigned)f2bf(o1) << 16);
        *(unsigned int*)((unsigned short*)out + (size_t)i * 64 + ch) = u;
      }
    }
  }
}

extern "C" void kernel_launch(void* const* d_in, const int* in_sizes, int n_in,
                              void* d_out, int out_size, void* d_ws, size_t ws_size,
                              hipStream_t stream)
{
  (void)n_in; (void)out_size; (void)ws_size;
  const void* x    = d_in[0];
  const int*  ei   = (const int*)d_in[1];
  const void* ea   = d_in[2];
  const void* Wl1  = d_in[3];
  const void* bl1  = d_in[4];
  const void* Wr1  = d_in[5];
  const void* br1  = d_in[6];
  const void* We1  = d_in[7];
  const void* att1 = d_in[8];
  const void* bias1= d_in[9];
  const void* Wl2  = d_in[10];
  const void* bl2  = d_in[11];
  const void* Wr2  = d_in[12];
  const void* br2  = d_in[13];
  const void* We2  = d_in[14];
  const void* att2 = d_in[15];
  const void* bias2= d_in[16];

  char* ws = (char*)d_ws;
  size_t off = 0;
  auto take = [&](size_t bytes) -> char* {
    char* p = ws + off;
    off += (bytes + 255) & ~(size_t)255;
    return p;
  };
  unsigned int* xl1p = (unsigned int*)take((size_t)N_NODES * 64 * 4);   // 12.8 MB
  unsigned int* xr1p = (unsigned int*)take((size_t)N_NODES * 64 * 4);   // 12.8 MB
  float* hbuf   = (float*)take((size_t)N_NODES * 128 * 4);              // 25.6 MB
  unsigned short* eap = (unsigned short*)take((size_t)(N_EDGES + 16) * 32 * 2); // 51.2 MB
  int*   counts = (int*)  take((size_t)N_NODES * 4);
  int*   row_ptr= (int*)  take((size_t)(N_NODES + 1) * 4);
  int*   cursor = (int*)  take((size_t)N_NODES * 4);
  int*   srcs   = (int*)  take((size_t)(N_EDGES + 16) * 4);
  int*   bsum   = (int*)  take(64 * 4);
  int*   flags  = (int*)  take(64 * 4);
  unsigned int* xl2p = xl1p;      // layer-2 reuses ([N,32] <= [N,64])
  unsigned int* xr2p = xr1p;

  Ptrs tl;
  const int map[16] = {0, 2, 3, 4, 5, 6, 7, 8, 9, 10, 11, 12, 13, 14, 15, 16};
  for (int j = 0; j < 16; j++) { tl.p[j] = d_in[map[j]]; tl.n[j] = in_sizes[map[j]]; }

  int nb = (N_NODES + 1023) / 1024;
  int zblocks = (N_NODES + 255) / 256;
  k_detect<<<16 + zblocks, 256, 0, stream>>>(tl, flags, counts, srcs + N_EDGES);
  k_gemm1<<<dim3((N_NODES + 31) / 32, 2), 256, 0, stream>>>(x, Wl1, bl1, Wr1, br1, flags, xl1p, xr1p);
  k_hist<<<(N_EDGES + 255) / 256, 256, 0, stream>>>(ei, counts);
  k_scan1<<<nb, 256, 0, stream>>>(counts, row_ptr, bsum);
  k_scan23<<<nb, 256, 0, stream>>>(row_ptr, cursor, bsum, nb);
  k_scatter<<<(N_EDGES + 255) / 256, 256, 0, stream>>>(ei, cursor, srcs, ea, flags, eap);
  k_fuse1<<<N_NODES / 8, 256, 0, stream>>>(eap, srcs, row_ptr, xl1p, xr1p, We1, att1, bias1, flags, hbuf);
  k_gemm2<<<dim3((N_NODES + 31) / 32, 2), 256, 0, stream>>>(hbuf, Wl2, bl2, Wr2, br2, flags, xl2p, xr2p);
  k_fuse2<<<N_NODES / 8, 256, 0, stream>>>(eap, srcs, row_ptr, xl2p, xr2p, We2, att2, bias2, flags, d_out);
}